// Round 2
// baseline (19750.636 us; speedup 1.0000x reference)
//
#include <hip/hip_runtime.h>

// ---------------------------------------------------------------------------
// Seq2Seq LSTM + attention, persistent cooperative kernel for MI355X (gfx950)
// B=256, T=512, I=64, H=512, HORIZON=30, NQ=3
// All scratch lives in a static __device__ global (g_ws) so we never depend
// on the harness ws_size. Cooperative launch with plain-launch fallback.
// ---------------------------------------------------------------------------

typedef _Float16 half_t;
typedef __attribute__((ext_vector_type(8)))  _Float16 f16x8;
typedef __attribute__((ext_vector_type(2)))  _Float16 f16x2;
typedef __attribute__((ext_vector_type(16))) float    f32x16;

#define MFMA(a,b,c) __builtin_amdgcn_mfma_f32_32x32x16_f16((a),(b),(c),0,0,0)
#define WAITV2()   asm volatile("s_waitcnt vmcnt(2)" ::: "memory")
#define WAITV0()   asm volatile("s_waitcnt vmcnt(0)" ::: "memory")
#define WAITLGKM() asm volatile("s_waitcnt lgkmcnt(0)" ::: "memory")
#define CBAR()     asm volatile("" ::: "memory")

__device__ __forceinline__ float fsig(float x)  { return 1.0f / (1.0f + __expf(-x)); }
__device__ __forceinline__ float ftanh(float x) { return 1.0f - 2.0f / (1.0f + __expf(2.0f * x)); }

// ---------------- workspace layout (bytes, inside g_ws) ----------------
static constexpr size_t O_X16 = 0;                            // (T,B,64) f16 transposed x
static constexpr size_t O_WL0 = O_X16 + (size_t)512*256*64*2; // 2048x576  f16 [Wih0|Whh0] gate-perm
static constexpr size_t O_WL1 = O_WL0 + (size_t)2048*576*2;   // 2048x1024 f16 [Wih1|Whh1]
static constexpr size_t O_WP1 = O_WL1 + (size_t)2048*1024*2;  // 4672x512  f16 [attnW|dWhh0|dWhh1|outW|pad]
static constexpr size_t O_WD0 = O_WP1 + (size_t)4672*512*2;   // 2048x512  f16 dec_Wih0[:,1:]
static constexpr size_t O_WD1 = O_WD0 + (size_t)2048*512*2;   // 2048x512  f16 dec_Wih1
static constexpr size_t O_BL0 = O_WD1 + (size_t)2048*512*2;   // 2048 f32 biases (gate-permuted)
static constexpr size_t O_BL1 = O_BL0 + 8192;
static constexpr size_t O_BD0 = O_BL1 + 8192;
static constexpr size_t O_BD1 = O_BD0 + 8192;
static constexpr size_t O_W0C = O_BD1 + 8192;                 // 2048 f32 dec_Wih0[:,0] permuted
static constexpr size_t O_H0B = O_W0C + 8192;                 // 2 x (256,512) f16 L0 h ping-pong
static constexpr size_t O_H1B = O_H0B + (size_t)2*256*512*2;  // 2 x (256,512) f16 L1 h ping-pong
static constexpr size_t O_HD1 = O_H1B + (size_t)2*256*512*2;  // (256,512) f16 decoder h1
static constexpr size_t O_H0D = O_HD1 + (size_t)256*512*2;    // (256,512) f16 decoder h0
static constexpr size_t O_CTX = O_H0D + (size_t)256*512*2;    // (256,512) f16 context
static constexpr size_t O_C0  = O_CTX + (size_t)256*512*2;    // (256,512) f32
static constexpr size_t O_C1  = O_C0  + (size_t)256*512*4;    // (256,512) f32
static constexpr size_t O_INP = O_C1  + (size_t)256*512*4;    // 256 f32
static constexpr size_t O_GAT = O_INP + 1024;                 // (256,4672) f32 decoder gate partials
static constexpr size_t O_EO  = O_GAT + (size_t)256*4672*4;   // (B*T,H) f16 encoder outputs
static constexpr size_t O_EP  = O_EO  + (size_t)256*512*512*2;// (B*T,512) f16 enc_proj
static constexpr size_t WS_NEED = O_EP + (size_t)256*512*512*2;

__device__ __align__(4096) unsigned char g_ws[WS_NEED];
__device__ int g_bar[256];

#define WSH(o) ((half_t*)(g_ws + (o)))
#define WSCH(o) ((const half_t*)(g_ws + (o)))
#define WSF(o) ((float*)(g_ws + (o)))
#define WSCF(o) ((const float*)(g_ws + (o)))

// ---------------- grid barrier (8 groups of 32, gen counter) ----------------
__device__ __forceinline__ void gbar() {
  __syncthreads();
  if (threadIdx.x == 0) {
    int* cnt = g_bar + ((blockIdx.x & 7) << 4);
    int* mst = g_bar + 128;
    int* gen = g_bar + 132;
    int g = __hip_atomic_load(gen, __ATOMIC_RELAXED, __HIP_MEMORY_SCOPE_AGENT);
    int a = __hip_atomic_fetch_add(cnt, 1, __ATOMIC_ACQ_REL, __HIP_MEMORY_SCOPE_AGENT);
    if (a == 31) {
      __hip_atomic_store(cnt, 0, __ATOMIC_RELAXED, __HIP_MEMORY_SCOPE_AGENT);
      int m = __hip_atomic_fetch_add(mst, 1, __ATOMIC_ACQ_REL, __HIP_MEMORY_SCOPE_AGENT);
      if (m == 7) {
        __hip_atomic_store(mst, 0, __ATOMIC_RELAXED, __HIP_MEMORY_SCOPE_AGENT);
        __hip_atomic_fetch_add(gen, 1, __ATOMIC_RELEASE, __HIP_MEMORY_SCOPE_AGENT);
      }
    }
    while (__hip_atomic_load(gen, __ATOMIC_RELAXED, __HIP_MEMORY_SCOPE_AGENT) == g)
      __builtin_amdgcn_s_sleep(2);
    (void)__hip_atomic_load(gen, __ATOMIC_ACQUIRE, __HIP_MEMORY_SCOPE_AGENT);
  }
  __syncthreads();
}

// ---------------- GEMM core: 64x64 tile, K-split over 4 waves ----------------
struct Seg { const half_t* p; int stride; int row0; };

// stage one 64-row x 16-k fragment-ordered slab (this wave's k16 slice) into LDS
__device__ __forceinline__ void stage_c(Seg sa, Seg sb, int cSplit, int c,
                                        int lane, int wid, char* dst) {
  Seg s = (c < cSplit) ? sa : sb;
  int kb = ((c < cSplit) ? c : (c - cSplit)) * 64;
  const half_t* g = s.p + (size_t)(s.row0 + (lane & 31)) * s.stride
                        + kb + (wid << 4) + ((lane >> 5) << 3);
  __builtin_amdgcn_global_load_lds(
      (const __attribute__((address_space(1))) unsigned int*)g,
      (__attribute__((address_space(3))) unsigned int*)dst, 16, 0, 0);
  g += (size_t)32 * s.stride;
  __builtin_amdgcn_global_load_lds(
      (const __attribute__((address_space(1))) unsigned int*)g,
      (__attribute__((address_space(3))) unsigned int*)(dst + 1024), 16, 0, 0);
}

__device__ __forceinline__ void gemm_ks(Seg sa, Seg sb, int cSplit, int NC,
                                        const half_t* W, int ws, int n0,
                                        int lane, int wid, char* asg,
                                        f32x16 acc[2][2]) {
  // wave-private LDS slots: make sure our prior ds_reads of this slot retired
  WAITLGKM();
  int hi8 = (lane >> 5) << 3;
  stage_c(sa, sb, cSplit, 0, lane, wid, asg + (size_t)(wid * 2) * 1024);
  for (int c = 0; c < NC; c++) {
    int kg = c * 64 + (wid << 4) + hi8;
    const half_t* wp = W + (size_t)(n0 + (lane & 31)) * ws + kg;
    f16x8 b0 = *(const f16x8*)wp;
    f16x8 b1 = *(const f16x8*)(wp + (size_t)32 * ws);
    CBAR();
    if (c + 1 < NC) {
      stage_c(sa, sb, cSplit, c + 1, lane, wid,
              asg + (size_t)((((c + 1) & 1) * 4 + wid) * 2) * 1024);
      WAITV2();
    } else {
      WAITV0();
    }
    char* ab = asg + (size_t)(((c & 1) * 4 + wid) * 2) * 1024 + lane * 16;
    f16x8 a0 = *(const f16x8*)ab;
    f16x8 a1 = *(const f16x8*)(ab + 1024);
    acc[0][0] = MFMA(a0, b0, acc[0][0]);
    acc[0][1] = MFMA(a0, b1, acc[0][1]);
    acc[1][0] = MFMA(a1, b0, acc[1][0]);
    acc[1][1] = MFMA(a1, b1, acc[1][1]);
  }
}

__device__ __forceinline__ void acc_wr(float* dst, int lane, f32x16 acc[2][2]) {
  #pragma unroll
  for (int t = 0; t < 4; t++) {
    float* p = dst + t * 1024 + lane * 16;
    f32x16 a = acc[t >> 1][t & 1];
    #pragma unroll
    for (int r4 = 0; r4 < 4; r4++)
      *(float4*)(p + r4 * 4) = make_float4(a[r4*4], a[r4*4+1], a[r4*4+2], a[r4*4+3]);
  }
}
__device__ __forceinline__ void acc_add(const float* src, int lane, f32x16 acc[2][2]) {
  #pragma unroll
  for (int t = 0; t < 4; t++) {
    const float* p = src + t * 1024 + lane * 16;
    #pragma unroll
    for (int r4 = 0; r4 < 4; r4++) {
      float4 v = *(const float4*)(p + r4 * 4);
      acc[t>>1][t&1][r4*4]   += v.x;
      acc[t>>1][t&1][r4*4+1] += v.y;
      acc[t>>1][t&1][r4*4+2] += v.z;
      acc[t>>1][t&1][r4*4+3] += v.w;
    }
  }
}

// reduce the 4 waves' K-split partials; leave final 64x64 tile in red[0..4095]
// laid out row*64+col
__device__ __forceinline__ void reduce_scatter(f32x16 acc[2][2], float* red,
                                               int lane, int wid) {
  if (wid >= 2) acc_wr(red + (wid - 2) * 4096, lane, acc);
  __syncthreads();
  if (wid < 2) acc_add(red + wid * 4096, lane, acc);
  __syncthreads();
  if (wid == 1) acc_wr(red, lane, acc);
  __syncthreads();
  if (wid == 0) {
    acc_add(red, lane, acc);
    #pragma unroll
    for (int ms = 0; ms < 2; ms++)
      #pragma unroll
      for (int ns = 0; ns < 2; ns++)
        #pragma unroll
        for (int r = 0; r < 16; r++) {
          int row = ms * 32 + (r & 3) + ((r >> 2) << 3) + ((lane >> 5) << 2);
          red[row * 64 + ns * 32 + (lane & 31)] = acc[ms][ns][r];
        }
  }
  __syncthreads();
}

// ---------------- main persistent cooperative kernel ----------------
__global__ void __launch_bounds__(256, 1) kmain(const float* __restrict__ attn_v,
                                                const float* __restrict__ out_b,
                                                float* __restrict__ out) {
  __shared__ __align__(16) char asg[16384];  // A staging: 2 bufs x 4 k16 x 2 msub x 1KB
  __shared__ float red[8192];                // 32KB reduction / scratch

  const half_t* x16 = WSCH(O_X16);
  const half_t* wL0 = WSCH(O_WL0);
  const half_t* wL1 = WSCH(O_WL1);
  const half_t* wP1 = WSCH(O_WP1);
  const half_t* wD0 = WSCH(O_WD0);
  const half_t* wD1 = WSCH(O_WD1);
  half_t* h0bB = WSH(O_H0B);
  half_t* h1bB = WSH(O_H1B);
  half_t* hd1  = WSH(O_HD1);
  half_t* h0d  = WSH(O_H0D);
  half_t* ctx  = WSH(O_CTX);
  half_t* eo   = WSH(O_EO);
  half_t* ep   = WSH(O_EP);
  float* c0 = WSF(O_C0);
  float* c1 = WSF(O_C1);
  float* inp = WSF(O_INP);
  float* gates = WSF(O_GAT);

  const int tid = threadIdx.x;
  const int wid = tid >> 6;
  const int lane = tid & 63;
  const f32x16 zv = {0,0,0,0,0,0,0,0,0,0,0,0,0,0,0,0};

  // ================= encoder: 513 wavefront-pipelined steps =================
  for (int s = 0; s <= 512; s++) {
    const bool isL1 = blockIdx.x >= 128;
    const int bi = blockIdx.x & 127;
    const int m0 = (bi >> 5) << 6;
    const int n0 = (bi & 31) << 6;
    const bool active = isL1 ? (s > 0) : (s < 512);
    if (active) {
      const half_t* h0r = h0bB + (size_t)((s + 1) & 1) * (256 * 512);
      f32x16 acc[2][2] = {{zv, zv}, {zv, zv}};
      int t;
      if (!isL1) {
        t = s;
        gemm_ks(Seg{x16, 64, t * 256 + m0}, Seg{h0r, 512, m0}, 1, 9,
                wL0, 576, n0, lane, wid, asg, acc);
      } else {
        t = s - 1;
        const half_t* h1r = h1bB + (size_t)(s & 1) * (256 * 512);
        gemm_ks(Seg{h0r, 512, m0}, Seg{h1r, 512, m0}, 8, 16,
                wL1, 1024, n0, lane, wid, asg, acc);
      }
      reduce_scatter(acc, red, lane, wid);
      const float* bias = isL1 ? WSCF(O_BL1) : WSCF(O_BL0);
      float* cb = isL1 ? c1 : c0;
      half_t* hb = isL1 ? (h1bB + (size_t)((s - 1) & 1) * (256 * 512))
                        : (h0bB + (size_t)(s & 1) * (256 * 512));
      #pragma unroll
      for (int it = 0; it < 4; it++) {
        int p = it * 256 + tid;
        int u = p & 15, bl = p >> 4;
        int nl = n0 + u * 4;
        float4 g4 = *(float4*)&red[bl * 64 + u * 4];
        float4 b4 = *(const float4*)&bias[nl];
        float gi = g4.x + b4.x, gf = g4.y + b4.y, gz = g4.z + b4.z, go = g4.w + b4.w;
        int bg = m0 + bl, ug = (n0 >> 2) + u;
        float cold = cb[bg * 512 + ug];
        float cn = fsig(gf) * cold + fsig(gi) * ftanh(gz);
        float hn = fsig(go) * ftanh(cn);
        cb[bg * 512 + ug] = cn;
        hb[bg * 512 + ug] = (half_t)hn;
        if (isL1) eo[((size_t)bg * 512 + t) * 512 + ug] = (half_t)hn;
      }
    }
    gbar();
  }

  // ================= enc_proj = enc_out @ attn_W^T (f16 out) =================
  for (int j = 0; j < 8; j++) {
    const int m0r = (blockIdx.x * 8 + j) * 64;
    for (int np = 0; np < 2; np++) {
      f32x16 acc[2][2] = {{zv, zv}, {zv, zv}};
      const int n0w = np * 256 + wid * 64;
      Seg se{eo, 512, m0r};
      WAITV0();
      __syncthreads();
      stage_c(se, se, 8, 0, lane, wid, asg + (size_t)(wid * 2) * 1024);
      for (int c = 0; c < 8; c++) {
        WAITV0();
        __syncthreads();
        if (c + 1 < 8)
          stage_c(se, se, 8, c + 1, lane, wid,
                  asg + (size_t)((((c + 1) & 1) * 4 + wid) * 2) * 1024);
        #pragma unroll
        for (int kk = 0; kk < 4; kk++) {
          char* ab = asg + (size_t)(((c & 1) * 4 + kk) * 2) * 1024 + lane * 16;
          f16x8 a0 = *(const f16x8*)ab;
          f16x8 a1 = *(const f16x8*)(ab + 1024);
          int kg = c * 64 + kk * 16 + ((lane >> 5) << 3);
          const half_t* wp = wP1 + (size_t)(n0w + (lane & 31)) * 512 + kg;
          f16x8 b0 = *(const f16x8*)wp;
          f16x8 b1 = *(const f16x8*)(wp + 32 * 512);
          acc[0][0] = MFMA(a0, b0, acc[0][0]);
          acc[0][1] = MFMA(a0, b1, acc[0][1]);
          acc[1][0] = MFMA(a1, b0, acc[1][0]);
          acc[1][1] = MFMA(a1, b1, acc[1][1]);
        }
      }
      #pragma unroll
      for (int ms = 0; ms < 2; ms++)
        #pragma unroll
        for (int ns = 0; ns < 2; ns++)
          #pragma unroll
          for (int r = 0; r < 16; r++) {
            int row = m0r + ms * 32 + (r & 3) + ((r >> 2) << 3) + ((lane >> 5) << 2);
            ep[(size_t)row * 512 + n0w + ns * 32 + (lane & 31)] = (half_t)acc[ms][ns][r];
          }
    }
  }
  gbar();

  // ================= decoder: 30 steps (d=30 = final output-only pass) ======
  for (int d = 0; d <= 30; d++) {
    // ---- P1: h1 @ [attn_W | dWhh0 | dWhh1 | out_W]  (N = 4672, 292 tiles) ----
    const half_t* hs = (d == 0) ? (h1bB + 256 * 512) : hd1;
    for (int jj = blockIdx.x; jj < 292; jj += 256) {
      const int m0 = (jj / 73) * 64;
      const int n0 = (jj % 73) * 64;
      f32x16 acc[2][2] = {{zv, zv}, {zv, zv}};
      gemm_ks(Seg{hs, 512, m0}, Seg{hs, 512, m0}, 8, 8,
              wP1, 512, n0, lane, wid, asg, acc);
      reduce_scatter(acc, red, lane, wid);
      if (n0 < 4608) {
        #pragma unroll
        for (int it = 0; it < 4; it++) {
          int p4 = (it * 256 + tid) * 4;
          int row = p4 >> 6, col = p4 & 63;
          *(float4*)&gates[(size_t)(m0 + row) * 4672 + n0 + col] = *(float4*)&red[p4];
        }
      } else if (d > 0) {
        if (tid < 64) {
          int bg = m0 + tid;
          float v0 = red[tid * 64 + 0] + out_b[0];
          float v1 = red[tid * 64 + 1] + out_b[1];
          float v2 = red[tid * 64 + 2] + out_b[2];
          out[(size_t)bg * 90 + (d - 1) * 3 + 0] = v0;
          out[(size_t)bg * 90 + (d - 1) * 3 + 1] = v1;
          out[(size_t)bg * 90 + (d - 1) * 3 + 2] = v2;
          inp[bg] = v1;
        }
      }
      __syncthreads();   // protect red[] from next tile's reduce_scatter pre-write
    }
    gbar();
    if (d == 30) break;

    // ---- P2: attention for batch row b = blockIdx.x ----
    {
      const int b = blockIdx.x;
      float* dpb = red;
      float* vb  = red + 512;
      float* eb  = red + 1024;
      float* ab2 = red + 1536;
      float* sc  = red + 2048;
      dpb[tid]       = gates[(size_t)b * 4672 + tid];
      dpb[tid + 256] = gates[(size_t)b * 4672 + tid + 256];
      vb[tid]        = attn_v[tid];
      vb[tid + 256]  = attn_v[tid + 256];
      __syncthreads();
      const half_t* eprow = ep + ((size_t)b << 18) + (size_t)(wid * 128) * 512 + lane * 8;
      for (int tt = 0; tt < 128; tt++) {
        f16x8 e8 = *(const f16x8*)(eprow + (size_t)tt * 512);
        float sum = 0.f;
        #pragma unroll
        for (int j = 0; j < 8; j++)
          sum += vb[lane * 8 + j] * ftanh((float)e8[j] + dpb[lane * 8 + j]);
        #pragma unroll
        for (int off = 32; off > 0; off >>= 1) sum += __shfl_down(sum, off, 64);
        if (lane == 0) eb[wid * 128 + tt] = sum;
      }
      __syncthreads();
      float e0 = eb[tid], e1 = eb[tid + 256];
      float mx = fmaxf(e0, e1);
      #pragma unroll
      for (int off = 32; off > 0; off >>= 1) mx = fmaxf(mx, __shfl_xor(mx, off, 64));
      if (lane == 0) sc[wid] = mx;
      __syncthreads();
      mx = fmaxf(fmaxf(sc[0], sc[1]), fmaxf(sc[2], sc[3]));
      float x0 = __expf(e0 - mx), x1 = __expf(e1 - mx);
      float ssum = x0 + x1;
      #pragma unroll
      for (int off = 32; off > 0; off >>= 1) ssum += __shfl_xor(ssum, off, 64);
      __syncthreads();
      if (lane == 0) sc[wid] = ssum;
      __syncthreads();
      float inv = 1.f / (sc[0] + sc[1] + sc[2] + sc[3]);
      ab2[tid] = x0 * inv;
      ab2[tid + 256] = x1 * inv;
      __syncthreads();
      const int h0i = tid * 2;
      const half_t* eor = eo + ((size_t)b << 18) + h0i;
      float a0 = 0.f, a1 = 0.f;
      #pragma unroll 4
      for (int t = 0; t < 512; t++) {
        f16x2 hv = *(const f16x2*)(eor + (size_t)t * 512);
        float at = ab2[t];
        a0 += at * (float)hv[0];
        a1 += at * (float)hv[1];
      }
      ctx[(b << 9) + h0i]     = (half_t)a0;
      ctx[(b << 9) + h0i + 1] = (half_t)a1;
    }
    gbar();

    // ---- P3: gates0 = ctx @ dWih0[:,1:] + inp*w0col + partial + bias -> h0d ----
    if (blockIdx.x < 128) {
      const int m0 = (blockIdx.x >> 5) << 6;
      const int n0 = (blockIdx.x & 31) << 6;
      f32x16 acc[2][2] = {{zv, zv}, {zv, zv}};
      gemm_ks(Seg{ctx, 512, m0}, Seg{ctx, 512, m0}, 8, 8,
              wD0, 512, n0, lane, wid, asg, acc);
      reduce_scatter(acc, red, lane, wid);
      const float* bD0 = WSCF(O_BD0);
      const float* w0c = WSCF(O_W0C);
      #pragma unroll
      for (int it = 0; it < 4; it++) {
        int p = it * 256 + tid;
        int u = p & 15, bl = p >> 4;
        int bg = m0 + bl, ug = (n0 >> 2) + u, nl = n0 + u * 4;
        float4 g4 = *(float4*)&red[bl * 64 + u * 4];
        float4 p4 = *(const float4*)&gates[(size_t)bg * 4672 + 512 + nl];
        float4 b4 = *(const float4*)&bD0[nl];
        float4 w4 = *(const float4*)&w0c[nl];
        float iv = inp[bg];
        float gi = g4.x + p4.x + b4.x + iv * w4.x;
        float gf = g4.y + p4.y + b4.y + iv * w4.y;
        float gz = g4.z + p4.z + b4.z + iv * w4.z;
        float go = g4.w + p4.w + b4.w + iv * w4.w;
        float cold = c1[bg * 512 + ug];
        float cn = fsig(gf) * cold + fsig(gi) * ftanh(gz);
        h0d[bg * 512 + ug] = (half_t)(fsig(go) * ftanh(cn));
      }
    }
    gbar();

    // ---- P4: gates1 = h0d @ dWih1 + partial + bias -> c1, hd1 ----
    if (blockIdx.x < 128) {
      const int m0 = (blockIdx.x >> 5) << 6;
      const int n0 = (blockIdx.x & 31) << 6;
      f32x16 acc[2][2] = {{zv, zv}, {zv, zv}};
      gemm_ks(Seg{h0d, 512, m0}, Seg{h0d, 512, m0}, 8, 8,
              wD1, 512, n0, lane, wid, asg, acc);
      reduce_scatter(acc, red, lane, wid);
      const float* bD1 = WSCF(O_BD1);
      #pragma unroll
      for (int it = 0; it < 4; it++) {
        int p = it * 256 + tid;
        int u = p & 15, bl = p >> 4;
        int bg = m0 + bl, ug = (n0 >> 2) + u, nl = n0 + u * 4;
        float4 g4 = *(float4*)&red[bl * 64 + u * 4];
        float4 p4 = *(const float4*)&gates[(size_t)bg * 4672 + 2560 + nl];
        float4 b4 = *(const float4*)&bD1[nl];
        float gi = g4.x + p4.x + b4.x;
        float gf = g4.y + p4.y + b4.y;
        float gz = g4.z + p4.z + b4.z;
        float go = g4.w + p4.w + b4.w;
        float cold = c1[bg * 512 + ug];
        float cn = fsig(gf) * cold + fsig(gi) * ftanh(gz);
        float hn = fsig(go) * ftanh(cn);
        c1[bg * 512 + ug] = cn;
        hd1[bg * 512 + ug] = (half_t)hn;
      }
    }
    gbar();
  }
}

// ---------------- prep kernels ----------------
__global__ void kpack(size_t dstOff, const float* srcA, int strideA, int offA, int Ka,
                      const float* srcB, int strideB, int Ktot, int N) {
  half_t* dst = (half_t*)(g_ws + dstOff);
  int i = blockIdx.x * 256 + threadIdx.x, stride = gridDim.x * 256;
  int total = N * Ktot;
  for (int idx = i; idx < total; idx += stride) {
    int n = idx / Ktot, k = idx - n * Ktot;
    int pn = (n & 3) * 512 + (n >> 2);   // gate-interleaved permutation
    float v = (k < Ka) ? srcA[(size_t)pn * strideA + offA + k]
                       : srcB[(size_t)pn * strideB + (k - Ka)];
    dst[idx] = (half_t)v;
  }
}

__global__ void kpackP1(const float* attnW, const float* dWhh0,
                        const float* dWhh1, const float* outW) {
  half_t* dst = WSH(O_WP1);
  int i = blockIdx.x * 256 + threadIdx.x, stride = gridDim.x * 256;
  for (int idx = i; idx < 4672 * 512; idx += stride) {
    int n = idx >> 9, k = idx & 511;
    float v = 0.f;
    if (n < 512) v = attnW[(n << 9) + k];
    else if (n < 2560) { int nn = n - 512;  int pn = (nn & 3) * 512 + (nn >> 2); v = dWhh0[(pn << 9) + k]; }
    else if (n < 4608) { int nn = n - 2560; int pn = (nn & 3) * 512 + (nn >> 2); v = dWhh1[(pn << 9) + k]; }
    else if (n < 4611) v = outW[((n - 4608) << 9) + k];
    dst[idx] = (half_t)v;
  }
}

__global__ void kmisc(const float* ebih0, const float* ebhh0, const float* ebih1, const float* ebhh1,
                      const float* dbih0, const float* dbhh0, const float* dbih1, const float* dbhh1,
                      const float* dWih0, const float* x) {
  float* bL0 = WSF(O_BL0);
  float* bL1 = WSF(O_BL1);
  float* bD0 = WSF(O_BD0);
  float* bD1 = WSF(O_BD1);
  float* w0c = WSF(O_W0C);
  half_t* h0b = WSH(O_H0B);
  half_t* h1b = WSH(O_H1B);
  float* c0 = WSF(O_C0);
  float* c1 = WSF(O_C1);
  float* inp = WSF(O_INP);
  int i = blockIdx.x * 256 + threadIdx.x, stride = gridDim.x * 256;
  for (int idx = i; idx < 262144; idx += stride) {
    if (idx < 2048) {
      int pn = (idx & 3) * 512 + (idx >> 2);
      bL0[idx] = ebih0[pn] + ebhh0[pn];
      bL1[idx] = ebih1[pn] + ebhh1[pn];
      bD0[idx] = dbih0[pn] + dbhh0[pn];
      bD1[idx] = dbih1[pn] + dbhh1[pn];
      w0c[idx] = dWih0[(size_t)pn * 513];
    }
    if (idx < 256) { inp[idx] = x[((size_t)idx * 512 + 511) * 64]; g_bar[idx] = 0; }
    h0b[idx] = (half_t)0.f;
    h1b[idx] = (half_t)0.f;
    if (idx < 131072) { c0[idx] = 0.f; c1[idx] = 0.f; }
  }
}

__global__ void kx16(const float* x) {
  half_t* dst = WSH(O_X16);
  int i = blockIdx.x * 256 + threadIdx.x, stride = gridDim.x * 256;
  for (int idx = i; idx < 256 * 512 * 64; idx += stride) {
    int b = idx >> 15;
    int t = (idx >> 6) & 511;
    int ii = idx & 63;
    dst[((size_t)(t << 8) + b) * 64 + ii] = (half_t)x[idx];
  }
}

// ---------------- launch ----------------
extern "C" void kernel_launch(void* const* d_in, const int* in_sizes, int n_in,
                              void* d_out, int out_size, void* d_ws, size_t ws_size,
                              hipStream_t stream) {
  const float* x     = (const float*)d_in[0];
  const float* eWih0 = (const float*)d_in[1];
  const float* eWhh0 = (const float*)d_in[2];
  const float* ebih0 = (const float*)d_in[3];
  const float* ebhh0 = (const float*)d_in[4];
  const float* eWih1 = (const float*)d_in[5];
  const float* eWhh1 = (const float*)d_in[6];
  const float* ebih1 = (const float*)d_in[7];
  const float* ebhh1 = (const float*)d_in[8];
  const float* dWih0 = (const float*)d_in[9];
  const float* dWhh0 = (const float*)d_in[10];
  const float* dbih0 = (const float*)d_in[11];
  const float* dbhh0 = (const float*)d_in[12];
  const float* dWih1 = (const float*)d_in[13];
  const float* dWhh1 = (const float*)d_in[14];
  const float* dbih1 = (const float*)d_in[15];
  const float* dbhh1 = (const float*)d_in[16];
  const float* attnW = (const float*)d_in[17];
  const float* attnv = (const float*)d_in[18];
  const float* outW  = (const float*)d_in[19];
  const float* outb  = (const float*)d_in[20];
  (void)in_sizes; (void)n_in; (void)out_size; (void)d_ws; (void)ws_size;

  kpack<<<1024, 256, 0, stream>>>(O_WL0, eWih0, 64, 0, 64, eWhh0, 512, 576, 2048);
  kpack<<<1024, 256, 0, stream>>>(O_WL1, eWih1, 512, 0, 512, eWhh1, 512, 1024, 2048);
  kpack<<<1024, 256, 0, stream>>>(O_WD0, dWih0, 513, 1, 512, nullptr, 0, 512, 2048);
  kpack<<<1024, 256, 0, stream>>>(O_WD1, dWih1, 512, 0, 512, nullptr, 0, 512, 2048);
  kpackP1<<<1024, 256, 0, stream>>>(attnW, dWhh0, dWhh1, outW);
  kmisc<<<1024, 256, 0, stream>>>(ebih0, ebhh0, ebih1, ebhh1,
                                  dbih0, dbhh0, dbih1, dbhh1, dWih0, x);
  kx16<<<2048, 256, 0, stream>>>(x);

  float* outp = (float*)d_out;
  void* args[] = {(void*)&attnv, (void*)&outb, (void*)&outp};
  hipError_t e = hipLaunchCooperativeKernel((void*)kmain, dim3(256), dim3(256),
                                            args, 0, stream);
  if (e != hipSuccess) {
    // fallback: plain launch — barrier is a custom atomic barrier and 256
    // blocks x 256 threads (launch_bounds 256,1) are co-resident on 256 CUs
    kmain<<<dim3(256), dim3(256), 0, stream>>>(attnv, outb, outp);
  }
}

// Round 3
// 16077.866 us; speedup vs baseline: 1.2284x; 1.2284x over previous
//
#include <hip/hip_runtime.h>

// ---------------------------------------------------------------------------
// Seq2Seq LSTM + attention, persistent cooperative kernel for MI355X (gfx950)
// B=256, T=512, I=64, H=512, HORIZON=30, NQ=3
// R3: 512-thread blocks (8 waves, K-split 128), fragment-order packed B
// (coalesced 1KB loads), depth-2 B prefetch w/ vmcnt(4) pipeline,
// conflict-free LDS reduction layout.
// ---------------------------------------------------------------------------

typedef _Float16 half_t;
typedef __attribute__((ext_vector_type(8)))  _Float16 f16x8;
typedef __attribute__((ext_vector_type(16))) float    f32x16;

#define MFMA(a,b,c) __builtin_amdgcn_mfma_f32_32x32x16_f16((a),(b),(c),0,0,0)
#define WAITV4()   asm volatile("s_waitcnt vmcnt(4)" ::: "memory")
#define WAITV0()   asm volatile("s_waitcnt vmcnt(0)" ::: "memory")
#define WAITLGKM() asm volatile("s_waitcnt lgkmcnt(0)" ::: "memory")
#define CBAR()     asm volatile("" ::: "memory")

__device__ __forceinline__ float fsig(float x)  { return 1.0f / (1.0f + __expf(-x)); }
__device__ __forceinline__ float ftanh(float x) { return 1.0f - 2.0f / (1.0f + __expf(2.0f * x)); }

// ---------------- workspace layout (bytes, inside g_ws) ----------------
static constexpr size_t O_X16 = 0;                             // (T,B,128) f16 x zero-padded
static constexpr size_t O_WL0 = O_X16 + (size_t)512*256*128*2; // 32t x 5c packed  (2048x640)
static constexpr size_t O_WL1 = O_WL0 + (size_t)2048*640*2;    // 32t x 8c packed  (2048x1024)
static constexpr size_t O_WP1 = O_WL1 + (size_t)2048*1024*2;   // 73t x 4c packed  (4672x512)
static constexpr size_t O_WD0 = O_WP1 + (size_t)4672*512*2;    // 32t x 4c packed
static constexpr size_t O_WD1 = O_WD0 + (size_t)2048*512*2;    // 32t x 4c packed
static constexpr size_t O_BL0 = O_WD1 + (size_t)2048*512*2;    // 2048 f32 biases (gate-permuted)
static constexpr size_t O_BL1 = O_BL0 + 8192;
static constexpr size_t O_BD0 = O_BL1 + 8192;
static constexpr size_t O_BD1 = O_BD0 + 8192;
static constexpr size_t O_W0C = O_BD1 + 8192;                  // 2048 f32 dec_Wih0[:,0] permuted
static constexpr size_t O_H0B = O_W0C + 8192;                  // 2 x (256,512) f16 L0 h ping-pong
static constexpr size_t O_H1B = O_H0B + (size_t)2*256*512*2;   // 2 x (256,512) f16 L1 h ping-pong
static constexpr size_t O_HD1 = O_H1B + (size_t)2*256*512*2;   // (256,512) f16 decoder h1
static constexpr size_t O_H0D = O_HD1 + (size_t)256*512*2;     // (256,512) f16 decoder h0
static constexpr size_t O_CTX = O_H0D + (size_t)256*512*2;     // (256,512) f16 context
static constexpr size_t O_C0  = O_CTX + (size_t)256*512*2;     // (256,512) f32
static constexpr size_t O_C1  = O_C0  + (size_t)256*512*4;     // (256,512) f32
static constexpr size_t O_INP = O_C1  + (size_t)256*512*4;     // 256 f32
static constexpr size_t O_GAT = O_INP + 1024;                  // (256,4672) f32 gate partials
static constexpr size_t O_EO  = O_GAT + (size_t)256*4672*4;    // (B*T,H) f16 encoder outputs
static constexpr size_t O_EP  = O_EO  + (size_t)256*512*512*2; // (B*T,512) f16 enc_proj
static constexpr size_t WS_NEED = O_EP + (size_t)256*512*512*2;

__device__ __align__(4096) unsigned char g_ws[WS_NEED];
__device__ int g_bar[256];

#define WSH(o) ((half_t*)(g_ws + (o)))
#define WSCH(o) ((const half_t*)(g_ws + (o)))
#define WSF(o) ((float*)(g_ws + (o)))
#define WSCF(o) ((const float*)(g_ws + (o)))

__device__ __forceinline__ int gperm(int n) { return (n & 3) * 512 + (n >> 2); }

// ---------------- grid barrier (8 groups of 32, gen counter) ----------------
__device__ __forceinline__ void gbar() {
  __syncthreads();
  if (threadIdx.x == 0) {
    int* cnt = g_bar + ((blockIdx.x & 7) << 4);
    int* mst = g_bar + 128;
    int* gen = g_bar + 132;
    int g = __hip_atomic_load(gen, __ATOMIC_RELAXED, __HIP_MEMORY_SCOPE_AGENT);
    int a = __hip_atomic_fetch_add(cnt, 1, __ATOMIC_ACQ_REL, __HIP_MEMORY_SCOPE_AGENT);
    if (a == 31) {
      __hip_atomic_store(cnt, 0, __ATOMIC_RELAXED, __HIP_MEMORY_SCOPE_AGENT);
      int m = __hip_atomic_fetch_add(mst, 1, __ATOMIC_ACQ_REL, __HIP_MEMORY_SCOPE_AGENT);
      if (m == 7) {
        __hip_atomic_store(mst, 0, __ATOMIC_RELAXED, __HIP_MEMORY_SCOPE_AGENT);
        __hip_atomic_fetch_add(gen, 1, __ATOMIC_RELEASE, __HIP_MEMORY_SCOPE_AGENT);
      }
    }
    while (__hip_atomic_load(gen, __ATOMIC_RELAXED, __HIP_MEMORY_SCOPE_AGENT) == g)
      __builtin_amdgcn_s_sleep(2);
    (void)__hip_atomic_load(gen, __ATOMIC_ACQUIRE, __HIP_MEMORY_SCOPE_AGENT);
  }
  __syncthreads();
}

// ---------------- GEMM core: 64x64 tile, K-split over 8 waves (chunk=128) ----
struct Seg { const half_t* p; int stride; int row0; };

// stage this wave's 64-row x 16-k fragment-ordered slice of chunk c into LDS
__device__ __forceinline__ void stageA(Seg sa, Seg sb, int cSplit, int c,
                                       int lane, int wid, char* dst) {
  Seg s = (c < cSplit) ? sa : sb;
  int kb = ((c < cSplit) ? c : (c - cSplit)) * 128;
  const half_t* g = s.p + (size_t)(s.row0 + (lane & 31)) * s.stride
                        + kb + (wid << 4) + ((lane >> 5) << 3);
  __builtin_amdgcn_global_load_lds(
      (const __attribute__((address_space(1))) unsigned int*)g,
      (__attribute__((address_space(3))) unsigned int*)dst, 16, 0, 0);
  g += (size_t)32 * s.stride;
  __builtin_amdgcn_global_load_lds(
      (const __attribute__((address_space(1))) unsigned int*)g,
      (__attribute__((address_space(3))) unsigned int*)(dst + 1024), 16, 0, 0);
}

// Wt: packed B for this n-tile. Layout (halves): (c*16 + wid*2 + bh)*512 + lane*8
__device__ __forceinline__ void gemm_ks(Seg sa, Seg sb, int cSplit, int NC,
                                        const half_t* Wt,
                                        int lane, int wid, char* asg,
                                        f32x16 acc[2][2]) {
  WAITV0(); WAITLGKM();   // drain: vmcnt arithmetic below assumes empty queue
  const half_t* wb = Wt + (wid << 1) * 512 + lane * 8;
  f16x8 b0[2], b1[2];
  // preamble: group(c) = { B(c) x2, A-stage(c) x2 }; CBAR keeps groups ordered
  b0[0] = *(const f16x8*)wb;
  b1[0] = *(const f16x8*)(wb + 512);
  stageA(sa, sb, cSplit, 0, lane, wid, asg + (size_t)wid * 2048);
  CBAR();
  b0[1] = *(const f16x8*)(wb + 8192);
  b1[1] = *(const f16x8*)(wb + 8192 + 512);
  stageA(sa, sb, cSplit, 1, lane, wid, asg + (size_t)(8 + wid) * 2048);
  CBAR();
  for (int c = 0; c < NC; c++) {
    if (c + 1 < NC) { WAITV4(); } else { WAITV0(); }
    char* ab = asg + (size_t)(((c & 1) * 8 + wid)) * 2048 + lane * 16;
    f16x8 a0 = *(const f16x8*)ab;
    f16x8 a1 = *(const f16x8*)(ab + 1024);
    WAITLGKM();
    acc[0][0] = MFMA(a0, b0[c & 1], acc[0][0]);
    acc[0][1] = MFMA(a0, b1[c & 1], acc[0][1]);
    acc[1][0] = MFMA(a1, b0[c & 1], acc[1][0]);
    acc[1][1] = MFMA(a1, b1[c & 1], acc[1][1]);
    if (c + 2 < NC) {
      b0[c & 1] = *(const f16x8*)(wb + (size_t)(c + 2) * 8192);
      b1[c & 1] = *(const f16x8*)(wb + (size_t)(c + 2) * 8192 + 512);
      stageA(sa, sb, cSplit, c + 2, lane, wid,
             asg + (size_t)(((c & 1) * 8 + wid)) * 2048);
    }
    CBAR();
  }
}

// conflict-free partial-tile store: float4 per (t,r4), consecutive lanes
__device__ __forceinline__ void acc_wr(float* dst, int lane, f32x16 acc[2][2]) {
  #pragma unroll
  for (int t = 0; t < 4; t++) {
    f32x16 a = acc[t >> 1][t & 1];
    #pragma unroll
    for (int r4 = 0; r4 < 4; r4++)
      *(float4*)(dst + ((t * 4 + r4) * 64 + lane) * 4) =
          make_float4(a[r4*4], a[r4*4+1], a[r4*4+2], a[r4*4+3]);
  }
}
__device__ __forceinline__ void acc_add(const float* src, int lane, f32x16 acc[2][2]) {
  #pragma unroll
  for (int t = 0; t < 4; t++) {
    #pragma unroll
    for (int r4 = 0; r4 < 4; r4++) {
      float4 v = *(const float4*)(src + ((t * 4 + r4) * 64 + lane) * 4);
      acc[t>>1][t&1][r4*4]   += v.x;
      acc[t>>1][t&1][r4*4+1] += v.y;
      acc[t>>1][t&1][r4*4+2] += v.z;
      acc[t>>1][t&1][r4*4+3] += v.w;
    }
  }
}

// reduce the 8 waves' K-split partials; final 64x64 tile in red[row*64+col]
__device__ __forceinline__ void reduce_scatter(f32x16 acc[2][2], float* red,
                                               int lane, int wid) {
  if (wid >= 4) acc_wr(red + (size_t)(wid - 4) * 4096, lane, acc);
  __syncthreads();
  if (wid < 4) acc_add(red + (size_t)wid * 4096, lane, acc);
  __syncthreads();
  if (wid == 2 || wid == 3) acc_wr(red + (size_t)(wid - 2) * 4096, lane, acc);
  __syncthreads();
  if (wid < 2) acc_add(red + (size_t)wid * 4096, lane, acc);
  __syncthreads();
  if (wid == 1) acc_wr(red, lane, acc);
  __syncthreads();
  if (wid == 0) {
    acc_add(red, lane, acc);
    #pragma unroll
    for (int ms = 0; ms < 2; ms++)
      #pragma unroll
      for (int ns = 0; ns < 2; ns++)
        #pragma unroll
        for (int r = 0; r < 16; r++) {
          int row = ms * 32 + (r & 3) + ((r >> 2) << 3) + ((lane >> 5) << 2);
          red[row * 64 + ns * 32 + (lane & 31)] = acc[ms][ns][r];
        }
  }
  __syncthreads();
}

// ---------------- main persistent cooperative kernel ----------------
__global__ void __launch_bounds__(512, 2) kmain(const float* __restrict__ attn_v,
                                                const float* __restrict__ out_b,
                                                float* __restrict__ out) {
  __shared__ __align__(16) char asg[32768];  // A staging: 2 bufs x 8 waves x 2KB
  __shared__ float red[16384];               // 64KB reduction / scratch

  const half_t* x16 = WSCH(O_X16);
  const half_t* wL0 = WSCH(O_WL0);
  const half_t* wL1 = WSCH(O_WL1);
  const half_t* wP1 = WSCH(O_WP1);
  const half_t* wD0 = WSCH(O_WD0);
  const half_t* wD1 = WSCH(O_WD1);
  half_t* h0bB = WSH(O_H0B);
  half_t* h1bB = WSH(O_H1B);
  half_t* hd1  = WSH(O_HD1);
  half_t* h0d  = WSH(O_H0D);
  half_t* ctx  = WSH(O_CTX);
  half_t* eo   = WSH(O_EO);
  half_t* ep   = WSH(O_EP);
  float* c0 = WSF(O_C0);
  float* c1 = WSF(O_C1);
  float* inp = WSF(O_INP);
  float* gates = WSF(O_GAT);

  const int tid = threadIdx.x;
  const int wid = tid >> 6;
  const int lane = tid & 63;
  const f32x16 zv = {0,0,0,0,0,0,0,0,0,0,0,0,0,0,0,0};

  // ================= encoder: 513 wavefront-pipelined steps =================
  for (int s = 0; s <= 512; s++) {
    const bool isL1 = blockIdx.x >= 128;
    const int bi = blockIdx.x & 127;
    const int m0 = (bi >> 5) << 6;
    const int n0 = (bi & 31) << 6;
    const bool active = isL1 ? (s > 0) : (s < 512);
    if (active) {
      const half_t* h0r = h0bB + (size_t)((s + 1) & 1) * (256 * 512);
      f32x16 acc[2][2] = {{zv, zv}, {zv, zv}};
      int t;
      if (!isL1) {
        t = s;
        gemm_ks(Seg{x16, 128, t * 256 + m0}, Seg{h0r, 512, m0}, 1, 5,
                wL0 + (size_t)(n0 >> 6) * (5 * 8192), lane, wid, asg, acc);
      } else {
        t = s - 1;
        const half_t* h1r = h1bB + (size_t)(s & 1) * (256 * 512);
        gemm_ks(Seg{h0r, 512, m0}, Seg{h1r, 512, m0}, 4, 8,
                wL1 + (size_t)(n0 >> 6) * (8 * 8192), lane, wid, asg, acc);
      }
      reduce_scatter(acc, red, lane, wid);
      const float* bias = isL1 ? WSCF(O_BL1) : WSCF(O_BL0);
      float* cb = isL1 ? c1 : c0;
      half_t* hb = isL1 ? (h1bB + (size_t)((s - 1) & 1) * (256 * 512))
                        : (h0bB + (size_t)(s & 1) * (256 * 512));
      #pragma unroll
      for (int it = 0; it < 2; it++) {
        int p = it * 512 + tid;
        int u = p & 15, bl = p >> 4;
        int nl = n0 + u * 4;
        float4 g4 = *(float4*)&red[bl * 64 + u * 4];
        float4 b4 = *(const float4*)&bias[nl];
        float gi = g4.x + b4.x, gf = g4.y + b4.y, gz = g4.z + b4.z, go = g4.w + b4.w;
        int bg = m0 + bl, ug = (n0 >> 2) + u;
        float cold = cb[bg * 512 + ug];
        float cn = fsig(gf) * cold + fsig(gi) * ftanh(gz);
        float hn = fsig(go) * ftanh(cn);
        cb[bg * 512 + ug] = cn;
        hb[bg * 512 + ug] = (half_t)hn;
        if (isL1) eo[((size_t)bg * 512 + t) * 512 + ug] = (half_t)hn;
      }
    }
    gbar();
  }

  // ================= enc_proj = enc_out @ attn_W^T (f16 out) =================
  for (int j = 0; j < 64; j++) {
    const int tile = blockIdx.x * 64 + j;
    const int m0r = (tile >> 3) * 64;
    const int nt = tile & 7;
    f32x16 acc[2][2] = {{zv, zv}, {zv, zv}};
    gemm_ks(Seg{eo, 512, m0r}, Seg{eo, 512, m0r}, 4, 4,
            wP1 + (size_t)nt * (4 * 8192), lane, wid, asg, acc);
    reduce_scatter(acc, red, lane, wid);
    {
      int base = tid * 8;
      int row = base >> 6, col = base & 63;
      f16x8 h8;
      #pragma unroll
      for (int q = 0; q < 8; q++) h8[q] = (half_t)red[row * 64 + col + q];
      *(f16x8*)&ep[(size_t)(m0r + row) * 512 + nt * 64 + col] = h8;
    }
    __syncthreads();   // protect red[] from next tile's reduce pre-write
  }
  gbar();

  // ================= decoder: 30 steps (d=30 = final output-only pass) ======
  for (int d = 0; d <= 30; d++) {
    // ---- P1: h1 @ [attn_W | dWhh0 | dWhh1 | out_W]  (N=4672, 292 tiles) ----
    const half_t* hs = (d == 0) ? (h1bB + 256 * 512) : hd1;
    for (int jj = blockIdx.x; jj < 292; jj += 256) {
      const int m0 = (jj / 73) * 64;
      const int ntile = jj % 73;
      const int n0 = ntile * 64;
      f32x16 acc[2][2] = {{zv, zv}, {zv, zv}};
      gemm_ks(Seg{hs, 512, m0}, Seg{hs, 512, m0}, 4, 4,
              wP1 + (size_t)ntile * (4 * 8192), lane, wid, asg, acc);
      reduce_scatter(acc, red, lane, wid);
      if (n0 < 4608) {
        #pragma unroll
        for (int it = 0; it < 2; it++) {
          int p4 = (it * 512 + tid) * 4;
          int row = p4 >> 6, col = p4 & 63;
          *(float4*)&gates[(size_t)(m0 + row) * 4672 + n0 + col] = *(float4*)&red[p4];
        }
      } else if (d > 0) {
        if (tid < 64) {
          int bg = m0 + tid;
          float v0 = red[tid * 64 + 0] + out_b[0];
          float v1 = red[tid * 64 + 1] + out_b[1];
          float v2 = red[tid * 64 + 2] + out_b[2];
          out[(size_t)bg * 90 + (d - 1) * 3 + 0] = v0;
          out[(size_t)bg * 90 + (d - 1) * 3 + 1] = v1;
          out[(size_t)bg * 90 + (d - 1) * 3 + 2] = v2;
          inp[bg] = v1;
        }
      }
      __syncthreads();   // protect red[] across jj iterations
    }
    gbar();
    if (d == 30) break;

    // ---- P2: attention for batch row b = blockIdx.x ----
    {
      const int b = blockIdx.x;
      float* dpb = red;          // 512
      float* vb  = red + 512;    // 512
      float* eb  = red + 1024;   // 512
      float* ab2 = red + 2048;   // 512
      float* sc  = red + 2560;   // 16
      dpb[tid] = gates[(size_t)b * 4672 + tid];
      vb[tid]  = attn_v[tid];
      __syncthreads();
      const half_t* eprow = ep + ((size_t)b << 18) + (size_t)(wid * 64) * 512 + lane * 8;
      for (int tt = 0; tt < 64; tt++) {
        f16x8 e8 = *(const f16x8*)(eprow + (size_t)tt * 512);
        float sum = 0.f;
        #pragma unroll
        for (int j = 0; j < 8; j++)
          sum += vb[lane * 8 + j] * ftanh((float)e8[j] + dpb[lane * 8 + j]);
        #pragma unroll
        for (int off = 32; off > 0; off >>= 1) sum += __shfl_down(sum, off, 64);
        if (lane == 0) eb[wid * 64 + tt] = sum;
      }
      __syncthreads();
      float e0 = eb[tid];
      float mx = e0;
      #pragma unroll
      for (int off = 32; off > 0; off >>= 1) mx = fmaxf(mx, __shfl_xor(mx, off, 64));
      if (lane == 0) sc[wid] = mx;
      __syncthreads();
      mx = sc[0];
      #pragma unroll
      for (int q = 1; q < 8; q++) mx = fmaxf(mx, sc[q]);
      float x0 = __expf(e0 - mx);
      float ssum = x0;
      #pragma unroll
      for (int off = 32; off > 0; off >>= 1) ssum += __shfl_xor(ssum, off, 64);
      __syncthreads();
      if (lane == 0) sc[8 + wid] = ssum;
      __syncthreads();
      float tot = sc[8];
      #pragma unroll
      for (int q = 1; q < 8; q++) tot += sc[8 + q];
      float inv = 1.f / tot;
      ab2[tid] = x0 * inv;
      __syncthreads();
      const half_t* eor = eo + ((size_t)b << 18) + tid;
      float a0 = 0.f;
      #pragma unroll 8
      for (int t = 0; t < 512; t++)
        a0 += ab2[t] * (float)eor[(size_t)t * 512];
      ctx[(b << 9) + tid] = (half_t)a0;
    }
    gbar();

    // ---- P3: gates0 = ctx @ dWih0[:,1:] + inp*w0col + partial + bias -> h0d ----
    if (blockIdx.x < 128) {
      const int m0 = (blockIdx.x >> 5) << 6;
      const int n0 = (blockIdx.x & 31) << 6;
      f32x16 acc[2][2] = {{zv, zv}, {zv, zv}};
      gemm_ks(Seg{ctx, 512, m0}, Seg{ctx, 512, m0}, 4, 4,
              wD0 + (size_t)(n0 >> 6) * (4 * 8192), lane, wid, asg, acc);
      reduce_scatter(acc, red, lane, wid);
      const float* bD0 = WSCF(O_BD0);
      const float* w0c = WSCF(O_W0C);
      #pragma unroll
      for (int it = 0; it < 2; it++) {
        int p = it * 512 + tid;
        int u = p & 15, bl = p >> 4;
        int bg = m0 + bl, ug = (n0 >> 2) + u, nl = n0 + u * 4;
        float4 g4 = *(float4*)&red[bl * 64 + u * 4];
        float4 p4 = *(const float4*)&gates[(size_t)bg * 4672 + 512 + nl];
        float4 b4 = *(const float4*)&bD0[nl];
        float4 w4 = *(const float4*)&w0c[nl];
        float iv = inp[bg];
        float gi = g4.x + p4.x + b4.x + iv * w4.x;
        float gf = g4.y + p4.y + b4.y + iv * w4.y;
        float gz = g4.z + p4.z + b4.z + iv * w4.z;
        float go = g4.w + p4.w + b4.w + iv * w4.w;
        float cold = c1[bg * 512 + ug];
        float cn = fsig(gf) * cold + fsig(gi) * ftanh(gz);
        h0d[bg * 512 + ug] = (half_t)(fsig(go) * ftanh(cn));
      }
    }
    gbar();

    // ---- P4: gates1 = h0d @ dWih1 + partial + bias -> c1, hd1 ----
    if (blockIdx.x < 128) {
      const int m0 = (blockIdx.x >> 5) << 6;
      const int n0 = (blockIdx.x & 31) << 6;
      f32x16 acc[2][2] = {{zv, zv}, {zv, zv}};
      gemm_ks(Seg{h0d, 512, m0}, Seg{h0d, 512, m0}, 4, 4,
              wD1 + (size_t)(n0 >> 6) * (4 * 8192), lane, wid, asg, acc);
      reduce_scatter(acc, red, lane, wid);
      const float* bD1 = WSCF(O_BD1);
      #pragma unroll
      for (int it = 0; it < 2; it++) {
        int p = it * 512 + tid;
        int u = p & 15, bl = p >> 4;
        int bg = m0 + bl, ug = (n0 >> 2) + u, nl = n0 + u * 4;
        float4 g4 = *(float4*)&red[bl * 64 + u * 4];
        float4 p4 = *(const float4*)&gates[(size_t)bg * 4672 + 2560 + nl];
        float4 b4 = *(const float4*)&bD1[nl];
        float gi = g4.x + p4.x + b4.x;
        float gf = g4.y + p4.y + b4.y;
        float gz = g4.z + p4.z + b4.z;
        float go = g4.w + p4.w + b4.w;
        float cold = c1[bg * 512 + ug];
        float cn = fsig(gf) * cold + fsig(gi) * ftanh(gz);
        float hn = fsig(go) * ftanh(cn);
        c1[bg * 512 + ug] = cn;
        hd1[bg * 512 + ug] = (half_t)hn;
      }
    }
    gbar();
  }
}

// ---------------- prep kernels ----------------
// packed-B layout (halves): e = (((tile*NC + c)*8 + w)*2 + bh)*512 + l*8 + j
// -> n = tile*64 + bh*32 + (l&31), k = c*128 + w*16 + (l>>5)*8 + j
__global__ void kpackB(size_t dstOff, int id, int Ntiles, int NC,
                       const float* s0, const float* s1,
                       const float* s2, const float* s3) {
  half_t* dst = (half_t*)(g_ws + dstOff);
  size_t total = (size_t)Ntiles * NC * 8192;
  size_t i = (size_t)blockIdx.x * 256 + threadIdx.x;
  size_t stride = (size_t)gridDim.x * 256;
  for (size_t e = i; e < total; e += stride) {
    int j = e & 7;
    int l = (e >> 3) & 63;
    int bh = (e >> 9) & 1;
    int w = (e >> 10) & 7;
    int tc = (int)(e >> 13);
    int c = tc % NC;
    int tile = tc / NC;
    int n = tile * 64 + bh * 32 + (l & 31);
    int k = c * 128 + w * 16 + ((l >> 5) << 3) + j;
    float v = 0.f;
    if (id == 0) {          // wL0: [Wih0(64) | pad(64) | Whh0(512)]
      int pn = gperm(n);
      if (k < 64) v = s0[(size_t)pn * 64 + k];
      else if (k >= 128) v = s1[(size_t)pn * 512 + (k - 128)];
    } else if (id == 1) {   // wL1: [Wih1(512) | Whh1(512)]
      int pn = gperm(n);
      v = (k < 512) ? s0[(size_t)pn * 512 + k] : s1[(size_t)pn * 512 + (k - 512)];
    } else if (id == 2) {   // wP1: [attnW | dWhh0 | dWhh1 | outW | pad]
      if (n < 512) v = s0[((size_t)n << 9) + k];
      else if (n < 2560) v = s1[((size_t)gperm(n - 512) << 9) + k];
      else if (n < 4608) v = s2[((size_t)gperm(n - 2560) << 9) + k];
      else if (n < 4611) v = s3[((size_t)(n - 4608) << 9) + k];
    } else if (id == 3) {   // wD0: dec_Wih0[:,1:]
      v = s0[(size_t)gperm(n) * 513 + 1 + k];
    } else {                // wD1
      v = s0[((size_t)gperm(n) << 9) + k];
    }
    dst[e] = (half_t)v;
  }
}

__global__ void kmisc(const float* ebih0, const float* ebhh0, const float* ebih1, const float* ebhh1,
                      const float* dbih0, const float* dbhh0, const float* dbih1, const float* dbhh1,
                      const float* dWih0, const float* x) {
  float* bL0 = WSF(O_BL0);
  float* bL1 = WSF(O_BL1);
  float* bD0 = WSF(O_BD0);
  float* bD1 = WSF(O_BD1);
  float* w0c = WSF(O_W0C);
  half_t* h0b = WSH(O_H0B);
  half_t* h1b = WSH(O_H1B);
  float* c0 = WSF(O_C0);
  float* c1 = WSF(O_C1);
  float* inp = WSF(O_INP);
  int i = blockIdx.x * 256 + threadIdx.x, stride = gridDim.x * 256;
  for (int idx = i; idx < 262144; idx += stride) {
    if (idx < 2048) {
      int pn = gperm(idx);
      bL0[idx] = ebih0[pn] + ebhh0[pn];
      bL1[idx] = ebih1[pn] + ebhh1[pn];
      bD0[idx] = dbih0[pn] + dbhh0[pn];
      bD1[idx] = dbih1[pn] + dbhh1[pn];
      w0c[idx] = dWih0[(size_t)pn * 513];
    }
    if (idx < 256) { inp[idx] = x[((size_t)idx * 512 + 511) * 64]; g_bar[idx] = 0; }
    h0b[idx] = (half_t)0.f;
    h1b[idx] = (half_t)0.f;
    if (idx < 131072) { c0[idx] = 0.f; c1[idx] = 0.f; }
  }
}

__global__ void kx16(const float* x) {
  half_t* dst = WSH(O_X16);   // (t, b, 128) zero-padded cols 64..127
  size_t i = (size_t)blockIdx.x * 256 + threadIdx.x;
  size_t stride = (size_t)gridDim.x * 256;
  for (size_t e = i; e < (size_t)512 * 256 * 128; e += stride) {
    int t = (int)(e >> 15);
    int b = (int)((e >> 7) & 255);
    int ii = (int)(e & 127);
    dst[e] = (ii < 64) ? (half_t)x[((size_t)b * 512 + t) * 64 + ii] : (half_t)0.f;
  }
}

// ---------------- launch ----------------
extern "C" void kernel_launch(void* const* d_in, const int* in_sizes, int n_in,
                              void* d_out, int out_size, void* d_ws, size_t ws_size,
                              hipStream_t stream) {
  const float* x     = (const float*)d_in[0];
  const float* eWih0 = (const float*)d_in[1];
  const float* eWhh0 = (const float*)d_in[2];
  const float* ebih0 = (const float*)d_in[3];
  const float* ebhh0 = (const float*)d_in[4];
  const float* eWih1 = (const float*)d_in[5];
  const float* eWhh1 = (const float*)d_in[6];
  const float* ebih1 = (const float*)d_in[7];
  const float* ebhh1 = (const float*)d_in[8];
  const float* dWih0 = (const float*)d_in[9];
  const float* dWhh0 = (const float*)d_in[10];
  const float* dbih0 = (const float*)d_in[11];
  const float* dbhh0 = (const float*)d_in[12];
  const float* dWih1 = (const float*)d_in[13];
  const float* dWhh1 = (const float*)d_in[14];
  const float* dbih1 = (const float*)d_in[15];
  const float* dbhh1 = (const float*)d_in[16];
  const float* attnW = (const float*)d_in[17];
  const float* attnv = (const float*)d_in[18];
  const float* outW  = (const float*)d_in[19];
  const float* outb  = (const float*)d_in[20];
  (void)in_sizes; (void)n_in; (void)out_size; (void)d_ws; (void)ws_size;

  kpackB<<<1024, 256, 0, stream>>>(O_WL0, 0, 32, 5, eWih0, eWhh0, nullptr, nullptr);
  kpackB<<<1024, 256, 0, stream>>>(O_WL1, 1, 32, 8, eWih1, eWhh1, nullptr, nullptr);
  kpackB<<<1024, 256, 0, stream>>>(O_WP1, 2, 73, 4, attnW, dWhh0, dWhh1, outW);
  kpackB<<<1024, 256, 0, stream>>>(O_WD0, 3, 32, 4, dWih0, nullptr, nullptr, nullptr);
  kpackB<<<1024, 256, 0, stream>>>(O_WD1, 4, 32, 4, dWih1, nullptr, nullptr, nullptr);
  kmisc<<<1024, 256, 0, stream>>>(ebih0, ebhh0, ebih1, ebhh1,
                                  dbih0, dbhh0, dbih1, dbhh1, dWih0, x);
  kx16<<<2048, 256, 0, stream>>>(x);

  float* outp = (float*)d_out;
  void* args[] = {(void*)&attnv, (void*)&outb, (void*)&outp};
  hipError_t e = hipLaunchCooperativeKernel((void*)kmain, dim3(256), dim3(512),
                                            args, 0, stream);
  if (e != hipSuccess) {
    // fallback: plain launch — custom atomic barrier; 256 blocks x 512 thr
    // (launch_bounds 512,2) are co-resident on 256 CUs
    kmain<<<dim3(256), dim3(512), 0, stream>>>(attnv, outb, outp);
  }
}

// Round 4
// 15985.625 us; speedup vs baseline: 1.2355x; 1.0058x over previous
//
#include <hip/hip_runtime.h>

// ---------------------------------------------------------------------------
// Seq2Seq LSTM + attention, persistent cooperative kernel for MI355X (gfx950)
// B=256, T=512, I=64, H=512, HORIZON=30, NQ=3
// R4: encoder B-weights held in VGPRs across all 513 steps (K-loop has only
// A-stage LDS-DMA traffic, depth-2 vmcnt(2) pipeline, no compiler-visible
// vm-dependent regs); all GEMM K-loops templated + fully unrolled.
// ---------------------------------------------------------------------------

typedef _Float16 half_t;
typedef __attribute__((ext_vector_type(8)))  _Float16 f16x8;
typedef __attribute__((ext_vector_type(16))) float    f32x16;

#define MFMA(a,b,c) __builtin_amdgcn_mfma_f32_32x32x16_f16((a),(b),(c),0,0,0)
#define WAITV4()   asm volatile("s_waitcnt vmcnt(4)" ::: "memory")
#define WAITV2()   asm volatile("s_waitcnt vmcnt(2)" ::: "memory")
#define WAITV0()   asm volatile("s_waitcnt vmcnt(0)" ::: "memory")
#define WAITLGKM() asm volatile("s_waitcnt lgkmcnt(0)" ::: "memory")
#define CBAR()     asm volatile("" ::: "memory")

__device__ __forceinline__ float fsig(float x)  { return 1.0f / (1.0f + __expf(-x)); }
__device__ __forceinline__ float ftanh(float x) { return 1.0f - 2.0f / (1.0f + __expf(2.0f * x)); }

// ---------------- workspace layout (bytes, inside g_ws) ----------------
static constexpr size_t O_X16 = 0;                             // (T,B,128) f16 x zero-padded
static constexpr size_t O_WL0 = O_X16 + (size_t)512*256*128*2; // 32t x 5c packed  (2048x640)
static constexpr size_t O_WL1 = O_WL0 + (size_t)2048*640*2;    // 32t x 8c packed  (2048x1024)
static constexpr size_t O_WP1 = O_WL1 + (size_t)2048*1024*2;   // 73t x 4c packed  (4672x512)
static constexpr size_t O_WD0 = O_WP1 + (size_t)4672*512*2;    // 32t x 4c packed
static constexpr size_t O_WD1 = O_WD0 + (size_t)2048*512*2;    // 32t x 4c packed
static constexpr size_t O_BL0 = O_WD1 + (size_t)2048*512*2;    // 2048 f32 biases (gate-permuted)
static constexpr size_t O_BL1 = O_BL0 + 8192;
static constexpr size_t O_BD0 = O_BL1 + 8192;
static constexpr size_t O_BD1 = O_BD0 + 8192;
static constexpr size_t O_W0C = O_BD1 + 8192;                  // 2048 f32 dec_Wih0[:,0] permuted
static constexpr size_t O_H0B = O_W0C + 8192;                  // 2 x (256,512) f16 L0 h ping-pong
static constexpr size_t O_H1B = O_H0B + (size_t)2*256*512*2;   // 2 x (256,512) f16 L1 h ping-pong
static constexpr size_t O_HD1 = O_H1B + (size_t)2*256*512*2;   // (256,512) f16 decoder h1
static constexpr size_t O_H0D = O_HD1 + (size_t)256*512*2;     // (256,512) f16 decoder h0
static constexpr size_t O_CTX = O_H0D + (size_t)256*512*2;     // (256,512) f16 context
static constexpr size_t O_C0  = O_CTX + (size_t)256*512*2;     // (256,512) f32
static constexpr size_t O_C1  = O_C0  + (size_t)256*512*4;     // (256,512) f32
static constexpr size_t O_INP = O_C1  + (size_t)256*512*4;     // 256 f32
static constexpr size_t O_GAT = O_INP + 1024;                  // (256,4672) f32 gate partials
static constexpr size_t O_EO  = O_GAT + (size_t)256*4672*4;    // (B*T,H) f16 encoder outputs
static constexpr size_t O_EP  = O_EO  + (size_t)256*512*512*2; // (B*T,512) f16 enc_proj
static constexpr size_t WS_NEED = O_EP + (size_t)256*512*512*2;

__device__ __align__(4096) unsigned char g_ws[WS_NEED];
__device__ int g_bar[256];

#define WSH(o) ((half_t*)(g_ws + (o)))
#define WSCH(o) ((const half_t*)(g_ws + (o)))
#define WSF(o) ((float*)(g_ws + (o)))
#define WSCF(o) ((const float*)(g_ws + (o)))

__device__ __forceinline__ int gperm(int n) { return (n & 3) * 512 + (n >> 2); }

// ---------------- grid barrier (8 groups of 32, gen counter) ----------------
__device__ __forceinline__ void gbar() {
  __syncthreads();
  if (threadIdx.x == 0) {
    int* cnt = g_bar + ((blockIdx.x & 7) << 4);
    int* mst = g_bar + 128;
    int* gen = g_bar + 132;
    int g = __hip_atomic_load(gen, __ATOMIC_RELAXED, __HIP_MEMORY_SCOPE_AGENT);
    int a = __hip_atomic_fetch_add(cnt, 1, __ATOMIC_ACQ_REL, __HIP_MEMORY_SCOPE_AGENT);
    if (a == 31) {
      __hip_atomic_store(cnt, 0, __ATOMIC_RELAXED, __HIP_MEMORY_SCOPE_AGENT);
      int m = __hip_atomic_fetch_add(mst, 1, __ATOMIC_ACQ_REL, __HIP_MEMORY_SCOPE_AGENT);
      if (m == 7) {
        __hip_atomic_store(mst, 0, __ATOMIC_RELAXED, __HIP_MEMORY_SCOPE_AGENT);
        __hip_atomic_fetch_add(gen, 1, __ATOMIC_RELEASE, __HIP_MEMORY_SCOPE_AGENT);
      }
    }
    while (__hip_atomic_load(gen, __ATOMIC_RELAXED, __HIP_MEMORY_SCOPE_AGENT) == g)
      __builtin_amdgcn_s_sleep(1);
    (void)__hip_atomic_load(gen, __ATOMIC_ACQUIRE, __HIP_MEMORY_SCOPE_AGENT);
  }
  __syncthreads();
}

// ---------------- GEMM cores: 64x64 tile, K-split over 8 waves (chunk=128) ---
struct Seg { const half_t* p; int stride; int row0; };

// stage this wave's 64-row x 16-k fragment-ordered slice of chunk c into LDS
__device__ __forceinline__ void stageA(Seg sa, Seg sb, int cSplit, int c,
                                       int lane, int wid, char* dst) {
  Seg s = (c < cSplit) ? sa : sb;
  int kb = ((c < cSplit) ? c : (c - cSplit)) * 128;
  const half_t* g = s.p + (size_t)(s.row0 + (lane & 31)) * s.stride
                        + kb + (wid << 4) + ((lane >> 5) << 3);
  __builtin_amdgcn_global_load_lds(
      (const __attribute__((address_space(1))) unsigned int*)g,
      (__attribute__((address_space(3))) unsigned int*)dst, 16, 0, 0);
  g += (size_t)32 * s.stride;
  __builtin_amdgcn_global_load_lds(
      (const __attribute__((address_space(1))) unsigned int*)g,
      (__attribute__((address_space(3))) unsigned int*)(dst + 1024), 16, 0, 0);
}

// Encoder GEMM: B held in registers (preloaded once); only A-stage VMEM in loop
template<int NC, int CSPLIT>
__device__ __forceinline__ void gemm_regB(Seg sa, Seg sb,
                                          const f16x8 (&B0)[8], const f16x8 (&B1)[8],
                                          int lane, int wid, char* asg,
                                          f32x16 acc[2][2]) {
  WAITV0(); WAITLGKM();
  stageA(sa, sb, CSPLIT, 0, lane, wid, asg + (size_t)wid * 2048);
  if (NC > 1) stageA(sa, sb, CSPLIT, 1, lane, wid, asg + (size_t)(8 + wid) * 2048);
  CBAR();
  #pragma unroll
  for (int c = 0; c < NC; c++) {
    if (c + 1 < NC) { WAITV2(); } else { WAITV0(); }
    char* ab = asg + (size_t)(((c & 1) * 8 + wid)) * 2048 + lane * 16;
    f16x8 a0 = *(const f16x8*)ab;
    f16x8 a1 = *(const f16x8*)(ab + 1024);
    WAITLGKM();
    acc[0][0] = MFMA(a0, B0[c], acc[0][0]);
    acc[0][1] = MFMA(a0, B1[c], acc[0][1]);
    acc[1][0] = MFMA(a1, B0[c], acc[1][0]);
    acc[1][1] = MFMA(a1, B1[c], acc[1][1]);
    if (c + 2 < NC)
      stageA(sa, sb, CSPLIT, c + 2, lane, wid,
             asg + (size_t)(((c & 1) * 8 + wid)) * 2048);
    CBAR();
  }
}

// Decoder GEMM: streamed B (fully unrolled, depth-2 group prefetch)
template<int NC>
__device__ __forceinline__ void gemm_ks(Seg sa, Seg sb, int cSplit,
                                        const half_t* Wt,
                                        int lane, int wid, char* asg,
                                        f32x16 acc[2][2]) {
  WAITV0(); WAITLGKM();
  const half_t* wb = Wt + (wid << 1) * 512 + lane * 8;
  f16x8 b0[2], b1[2];
  b0[0] = *(const f16x8*)wb;
  b1[0] = *(const f16x8*)(wb + 512);
  stageA(sa, sb, cSplit, 0, lane, wid, asg + (size_t)wid * 2048);
  CBAR();
  b0[1] = *(const f16x8*)(wb + 8192);
  b1[1] = *(const f16x8*)(wb + 8192 + 512);
  stageA(sa, sb, cSplit, 1, lane, wid, asg + (size_t)(8 + wid) * 2048);
  CBAR();
  #pragma unroll
  for (int c = 0; c < NC; c++) {
    if (c + 1 < NC) { WAITV4(); } else { WAITV0(); }
    char* ab = asg + (size_t)(((c & 1) * 8 + wid)) * 2048 + lane * 16;
    f16x8 a0 = *(const f16x8*)ab;
    f16x8 a1 = *(const f16x8*)(ab + 1024);
    WAITLGKM();
    acc[0][0] = MFMA(a0, b0[c & 1], acc[0][0]);
    acc[0][1] = MFMA(a0, b1[c & 1], acc[0][1]);
    acc[1][0] = MFMA(a1, b0[c & 1], acc[1][0]);
    acc[1][1] = MFMA(a1, b1[c & 1], acc[1][1]);
    if (c + 2 < NC) {
      b0[c & 1] = *(const f16x8*)(wb + (size_t)(c + 2) * 8192);
      b1[c & 1] = *(const f16x8*)(wb + (size_t)(c + 2) * 8192 + 512);
      stageA(sa, sb, cSplit, c + 2, lane, wid,
             asg + (size_t)(((c & 1) * 8 + wid)) * 2048);
    }
    CBAR();
  }
}

// conflict-free partial-tile store: float4 per (t,r4), consecutive lanes
__device__ __forceinline__ void acc_wr(float* dst, int lane, f32x16 acc[2][2]) {
  #pragma unroll
  for (int t = 0; t < 4; t++) {
    f32x16 a = acc[t >> 1][t & 1];
    #pragma unroll
    for (int r4 = 0; r4 < 4; r4++)
      *(float4*)(dst + ((t * 4 + r4) * 64 + lane) * 4) =
          make_float4(a[r4*4], a[r4*4+1], a[r4*4+2], a[r4*4+3]);
  }
}
__device__ __forceinline__ void acc_add(const float* src, int lane, f32x16 acc[2][2]) {
  #pragma unroll
  for (int t = 0; t < 4; t++) {
    #pragma unroll
    for (int r4 = 0; r4 < 4; r4++) {
      float4 v = *(const float4*)(src + ((t * 4 + r4) * 64 + lane) * 4);
      acc[t>>1][t&1][r4*4]   += v.x;
      acc[t>>1][t&1][r4*4+1] += v.y;
      acc[t>>1][t&1][r4*4+2] += v.z;
      acc[t>>1][t&1][r4*4+3] += v.w;
    }
  }
}

// reduce the 8 waves' K-split partials; final 64x64 tile in red[row*64+col]
__device__ __forceinline__ void reduce_scatter(f32x16 acc[2][2], float* red,
                                               int lane, int wid) {
  if (wid >= 4) acc_wr(red + (size_t)(wid - 4) * 4096, lane, acc);
  __syncthreads();
  if (wid < 4) acc_add(red + (size_t)wid * 4096, lane, acc);
  __syncthreads();
  if (wid == 2 || wid == 3) acc_wr(red + (size_t)(wid - 2) * 4096, lane, acc);
  __syncthreads();
  if (wid < 2) acc_add(red + (size_t)wid * 4096, lane, acc);
  __syncthreads();
  if (wid == 1) acc_wr(red, lane, acc);
  __syncthreads();
  if (wid == 0) {
    acc_add(red, lane, acc);
    #pragma unroll
    for (int ms = 0; ms < 2; ms++)
      #pragma unroll
      for (int ns = 0; ns < 2; ns++)
        #pragma unroll
        for (int r = 0; r < 16; r++) {
          int row = ms * 32 + (r & 3) + ((r >> 2) << 3) + ((lane >> 5) << 2);
          red[row * 64 + ns * 32 + (lane & 31)] = acc[ms][ns][r];
        }
  }
  __syncthreads();
}

// ---------------- main persistent cooperative kernel ----------------
__global__ void __launch_bounds__(512, 2) kmain(const float* __restrict__ attn_v,
                                                const float* __restrict__ out_b,
                                                float* __restrict__ out) {
  __shared__ __align__(16) char asg[32768];  // A staging: 2 bufs x 8 waves x 2KB
  __shared__ float red[16384];               // 64KB reduction / scratch

  const half_t* x16 = WSCH(O_X16);
  const half_t* wL0 = WSCH(O_WL0);
  const half_t* wL1 = WSCH(O_WL1);
  const half_t* wP1 = WSCH(O_WP1);
  const half_t* wD0 = WSCH(O_WD0);
  const half_t* wD1 = WSCH(O_WD1);
  half_t* h0bB = WSH(O_H0B);
  half_t* h1bB = WSH(O_H1B);
  half_t* hd1  = WSH(O_HD1);
  half_t* h0d  = WSH(O_H0D);
  half_t* ctx  = WSH(O_CTX);
  half_t* eo   = WSH(O_EO);
  half_t* ep   = WSH(O_EP);
  float* c0 = WSF(O_C0);
  float* c1 = WSF(O_C1);
  float* inp = WSF(O_INP);
  float* gates = WSF(O_GAT);

  const int tid = threadIdx.x;
  const int wid = tid >> 6;
  const int lane = tid & 63;
  const f32x16 zv = {0,0,0,0,0,0,0,0,0,0,0,0,0,0,0,0};

  // ================= encoder: 513 wavefront-pipelined steps =================
  {
    const bool isL1 = blockIdx.x >= 128;
    const int bi = blockIdx.x & 127;
    const int m0 = (bi >> 5) << 6;
    const int n0 = (bi & 31) << 6;

    // ---- preload this block's B-weight slice into VGPRs (held 513 steps) ----
    const half_t* wbase = isL1 ? (wL1 + (size_t)(n0 >> 6) * (8 * 8192))
                               : (wL0 + (size_t)(n0 >> 6) * (5 * 8192));
    const half_t* wb = wbase + (wid << 1) * 512 + lane * 8;
    const int ncB = isL1 ? 8 : 5;
    f16x8 B0[8], B1[8];
    #pragma unroll
    for (int c = 0; c < 8; c++) {
      if (c < ncB) {
        B0[c] = *(const f16x8*)(wb + (size_t)c * 8192);
        B1[c] = *(const f16x8*)(wb + (size_t)c * 8192 + 512);
      }
    }

    for (int s = 0; s <= 512; s++) {
      const bool active = isL1 ? (s > 0) : (s < 512);
      if (active) {
        const half_t* h0r = h0bB + (size_t)((s + 1) & 1) * (256 * 512);
        f32x16 acc[2][2] = {{zv, zv}, {zv, zv}};
        int t;
        if (!isL1) {
          t = s;
          gemm_regB<5, 1>(Seg{x16, 128, t * 256 + m0}, Seg{h0r, 512, m0},
                          B0, B1, lane, wid, asg, acc);
        } else {
          t = s - 1;
          const half_t* h1r = h1bB + (size_t)(s & 1) * (256 * 512);
          gemm_regB<8, 4>(Seg{h0r, 512, m0}, Seg{h1r, 512, m0},
                          B0, B1, lane, wid, asg, acc);
        }
        reduce_scatter(acc, red, lane, wid);
        const float* bias = isL1 ? WSCF(O_BL1) : WSCF(O_BL0);
        float* cb = isL1 ? c1 : c0;
        half_t* hb = isL1 ? (h1bB + (size_t)((s - 1) & 1) * (256 * 512))
                          : (h0bB + (size_t)(s & 1) * (256 * 512));
        #pragma unroll
        for (int it = 0; it < 2; it++) {
          int p = it * 512 + tid;
          int u = p & 15, bl = p >> 4;
          int nl = n0 + u * 4;
          float4 g4 = *(float4*)&red[bl * 64 + u * 4];
          float4 b4 = *(const float4*)&bias[nl];
          float gi = g4.x + b4.x, gf = g4.y + b4.y, gz = g4.z + b4.z, go = g4.w + b4.w;
          int bg = m0 + bl, ug = (n0 >> 2) + u;
          float cold = cb[bg * 512 + ug];
          float cn = fsig(gf) * cold + fsig(gi) * ftanh(gz);
          float hn = fsig(go) * ftanh(cn);
          cb[bg * 512 + ug] = cn;
          hb[bg * 512 + ug] = (half_t)hn;
          if (isL1) eo[((size_t)bg * 512 + t) * 512 + ug] = (half_t)hn;
        }
      }
      gbar();
    }
  }

  // ================= enc_proj = enc_out @ attn_W^T (f16 out) =================
  for (int j = 0; j < 64; j++) {
    const int tile = blockIdx.x * 64 + j;
    const int m0r = (tile >> 3) * 64;
    const int nt = tile & 7;
    f32x16 acc[2][2] = {{zv, zv}, {zv, zv}};
    gemm_ks<4>(Seg{eo, 512, m0r}, Seg{eo, 512, m0r}, 4,
               wP1 + (size_t)nt * (4 * 8192), lane, wid, asg, acc);
    reduce_scatter(acc, red, lane, wid);
    {
      int base = tid * 8;
      int row = base >> 6, col = base & 63;
      f16x8 h8;
      #pragma unroll
      for (int q = 0; q < 8; q++) h8[q] = (half_t)red[row * 64 + col + q];
      *(f16x8*)&ep[(size_t)(m0r + row) * 512 + nt * 64 + col] = h8;
    }
    __syncthreads();   // protect red[] from next tile's reduce pre-write
  }
  gbar();

  // ================= decoder: 30 steps (d=30 = final output-only pass) ======
  for (int d = 0; d <= 30; d++) {
    // ---- P1: h1 @ [attn_W | dWhh0 | dWhh1 | out_W]  (N=4672, 292 tiles) ----
    const half_t* hs = (d == 0) ? (h1bB + 256 * 512) : hd1;
    for (int jj = blockIdx.x; jj < 292; jj += 256) {
      const int m0 = (jj / 73) * 64;
      const int ntile = jj % 73;
      const int n0 = ntile * 64;
      f32x16 acc[2][2] = {{zv, zv}, {zv, zv}};
      gemm_ks<4>(Seg{hs, 512, m0}, Seg{hs, 512, m0}, 4,
                 wP1 + (size_t)ntile * (4 * 8192), lane, wid, asg, acc);
      reduce_scatter(acc, red, lane, wid);
      if (n0 < 4608) {
        #pragma unroll
        for (int it = 0; it < 2; it++) {
          int p4 = (it * 512 + tid) * 4;
          int row = p4 >> 6, col = p4 & 63;
          *(float4*)&gates[(size_t)(m0 + row) * 4672 + n0 + col] = *(float4*)&red[p4];
        }
      } else if (d > 0) {
        if (tid < 64) {
          int bg = m0 + tid;
          float v0 = red[tid * 64 + 0] + out_b[0];
          float v1 = red[tid * 64 + 1] + out_b[1];
          float v2 = red[tid * 64 + 2] + out_b[2];
          out[(size_t)bg * 90 + (d - 1) * 3 + 0] = v0;
          out[(size_t)bg * 90 + (d - 1) * 3 + 1] = v1;
          out[(size_t)bg * 90 + (d - 1) * 3 + 2] = v2;
          inp[bg] = v1;
        }
      }
      __syncthreads();   // protect red[] across jj iterations
    }
    gbar();
    if (d == 30) break;

    // ---- P2: attention for batch row b = blockIdx.x ----
    {
      const int b = blockIdx.x;
      float* dpb = red;          // 512
      float* vb  = red + 512;    // 512
      float* eb  = red + 1024;   // 512
      float* ab2 = red + 2048;   // 512
      float* sc  = red + 2560;   // 16
      dpb[tid] = gates[(size_t)b * 4672 + tid];
      vb[tid]  = attn_v[tid];
      __syncthreads();
      const half_t* eprow = ep + ((size_t)b << 18) + (size_t)(wid * 64) * 512 + lane * 8;
      for (int tt = 0; tt < 64; tt++) {
        f16x8 e8 = *(const f16x8*)(eprow + (size_t)tt * 512);
        float sum = 0.f;
        #pragma unroll
        for (int j = 0; j < 8; j++)
          sum += vb[lane * 8 + j] * ftanh((float)e8[j] + dpb[lane * 8 + j]);
        #pragma unroll
        for (int off = 32; off > 0; off >>= 1) sum += __shfl_down(sum, off, 64);
        if (lane == 0) eb[wid * 64 + tt] = sum;
      }
      __syncthreads();
      float e0 = eb[tid];
      float mx = e0;
      #pragma unroll
      for (int off = 32; off > 0; off >>= 1) mx = fmaxf(mx, __shfl_xor(mx, off, 64));
      if (lane == 0) sc[wid] = mx;
      __syncthreads();
      mx = sc[0];
      #pragma unroll
      for (int q = 1; q < 8; q++) mx = fmaxf(mx, sc[q]);
      float x0 = __expf(e0 - mx);
      float ssum = x0;
      #pragma unroll
      for (int off = 32; off > 0; off >>= 1) ssum += __shfl_xor(ssum, off, 64);
      __syncthreads();
      if (lane == 0) sc[8 + wid] = ssum;
      __syncthreads();
      float tot = sc[8];
      #pragma unroll
      for (int q = 1; q < 8; q++) tot += sc[8 + q];
      float inv = 1.f / tot;
      ab2[tid] = x0 * inv;
      __syncthreads();
      const half_t* eor = eo + ((size_t)b << 18) + tid;
      float a0 = 0.f;
      #pragma unroll 8
      for (int t = 0; t < 512; t++)
        a0 += ab2[t] * (float)eor[(size_t)t * 512];
      ctx[(b << 9) + tid] = (half_t)a0;
    }
    gbar();

    // ---- P3: gates0 = ctx @ dWih0[:,1:] + inp*w0col + partial + bias -> h0d ----
    if (blockIdx.x < 128) {
      const int m0 = (blockIdx.x >> 5) << 6;
      const int n0 = (blockIdx.x & 31) << 6;
      f32x16 acc[2][2] = {{zv, zv}, {zv, zv}};
      gemm_ks<4>(Seg{ctx, 512, m0}, Seg{ctx, 512, m0}, 4,
                 wD0 + (size_t)(n0 >> 6) * (4 * 8192), lane, wid, asg, acc);
      reduce_scatter(acc, red, lane, wid);
      const float* bD0 = WSCF(O_BD0);
      const float* w0c = WSCF(O_W0C);
      #pragma unroll
      for (int it = 0; it < 2; it++) {
        int p = it * 512 + tid;
        int u = p & 15, bl = p >> 4;
        int bg = m0 + bl, ug = (n0 >> 2) + u, nl = n0 + u * 4;
        float4 g4 = *(float4*)&red[bl * 64 + u * 4];
        float4 p4 = *(const float4*)&gates[(size_t)bg * 4672 + 512 + nl];
        float4 b4 = *(const float4*)&bD0[nl];
        float4 w4 = *(const float4*)&w0c[nl];
        float iv = inp[bg];
        float gi = g4.x + p4.x + b4.x + iv * w4.x;
        float gf = g4.y + p4.y + b4.y + iv * w4.y;
        float gz = g4.z + p4.z + b4.z + iv * w4.z;
        float go = g4.w + p4.w + b4.w + iv * w4.w;
        float cold = c1[bg * 512 + ug];
        float cn = fsig(gf) * cold + fsig(gi) * ftanh(gz);
        h0d[bg * 512 + ug] = (half_t)(fsig(go) * ftanh(cn));
      }
    }
    gbar();

    // ---- P4: gates1 = h0d @ dWih1 + partial + bias -> c1, hd1 ----
    if (blockIdx.x < 128) {
      const int m0 = (blockIdx.x >> 5) << 6;
      const int n0 = (blockIdx.x & 31) << 6;
      f32x16 acc[2][2] = {{zv, zv}, {zv, zv}};
      gemm_ks<4>(Seg{h0d, 512, m0}, Seg{h0d, 512, m0}, 4,
                 wD1 + (size_t)(n0 >> 6) * (4 * 8192), lane, wid, asg, acc);
      reduce_scatter(acc, red, lane, wid);
      const float* bD1 = WSCF(O_BD1);
      #pragma unroll
      for (int it = 0; it < 2; it++) {
        int p = it * 512 + tid;
        int u = p & 15, bl = p >> 4;
        int bg = m0 + bl, ug = (n0 >> 2) + u, nl = n0 + u * 4;
        float4 g4 = *(float4*)&red[bl * 64 + u * 4];
        float4 p4 = *(const float4*)&gates[(size_t)bg * 4672 + 2560 + nl];
        float4 b4 = *(const float4*)&bD1[nl];
        float gi = g4.x + p4.x + b4.x;
        float gf = g4.y + p4.y + b4.y;
        float gz = g4.z + p4.z + b4.z;
        float go = g4.w + p4.w + b4.w;
        float cold = c1[bg * 512 + ug];
        float cn = fsig(gf) * cold + fsig(gi) * ftanh(gz);
        float hn = fsig(go) * ftanh(cn);
        c1[bg * 512 + ug] = cn;
        hd1[bg * 512 + ug] = (half_t)hn;
      }
    }
    gbar();
  }
}

// ---------------- prep kernels ----------------
// packed-B layout (halves): e = (((tile*NC + c)*8 + w)*2 + bh)*512 + l*8 + j
// -> n = tile*64 + bh*32 + (l&31), k = c*128 + w*16 + (l>>5)*8 + j
__global__ void kpackB(size_t dstOff, int id, int Ntiles, int NC,
                       const float* s0, const float* s1,
                       const float* s2, const float* s3) {
  half_t* dst = (half_t*)(g_ws + dstOff);
  size_t total = (size_t)Ntiles * NC * 8192;
  size_t i = (size_t)blockIdx.x * 256 + threadIdx.x;
  size_t stride = (size_t)gridDim.x * 256;
  for (size_t e = i; e < total; e += stride) {
    int j = e & 7;
    int l = (e >> 3) & 63;
    int bh = (e >> 9) & 1;
    int w = (e >> 10) & 7;
    int tc = (int)(e >> 13);
    int c = tc % NC;
    int tile = tc / NC;
    int n = tile * 64 + bh * 32 + (l & 31);
    int k = c * 128 + w * 16 + ((l >> 5) << 3) + j;
    float v = 0.f;
    if (id == 0) {          // wL0: [Wih0(64) | pad(64) | Whh0(512)]
      int pn = gperm(n);
      if (k < 64) v = s0[(size_t)pn * 64 + k];
      else if (k >= 128) v = s1[(size_t)pn * 512 + (k - 128)];
    } else if (id == 1) {   // wL1: [Wih1(512) | Whh1(512)]
      int pn = gperm(n);
      v = (k < 512) ? s0[(size_t)pn * 512 + k] : s1[(size_t)pn * 512 + (k - 512)];
    } else if (id == 2) {   // wP1: [attnW | dWhh0 | dWhh1 | outW | pad]
      if (n < 512) v = s0[((size_t)n << 9) + k];
      else if (n < 2560) v = s1[((size_t)gperm(n - 512) << 9) + k];
      else if (n < 4608) v = s2[((size_t)gperm(n - 2560) << 9) + k];
      else if (n < 4611) v = s3[((size_t)(n - 4608) << 9) + k];
    } else if (id == 3) {   // wD0: dec_Wih0[:,1:]
      v = s0[(size_t)gperm(n) * 513 + 1 + k];
    } else {                // wD1
      v = s0[((size_t)gperm(n) << 9) + k];
    }
    dst[e] = (half_t)v;
  }
}

__global__ void kmisc(const float* ebih0, const float* ebhh0, const float* ebih1, const float* ebhh1,
                      const float* dbih0, const float* dbhh0, const float* dbih1, const float* dbhh1,
                      const float* dWih0, const float* x) {
  float* bL0 = WSF(O_BL0);
  float* bL1 = WSF(O_BL1);
  float* bD0 = WSF(O_BD0);
  float* bD1 = WSF(O_BD1);
  float* w0c = WSF(O_W0C);
  half_t* h0b = WSH(O_H0B);
  half_t* h1b = WSH(O_H1B);
  float* c0 = WSF(O_C0);
  float* c1 = WSF(O_C1);
  float* inp = WSF(O_INP);
  int i = blockIdx.x * 256 + threadIdx.x, stride = gridDim.x * 256;
  for (int idx = i; idx < 262144; idx += stride) {
    if (idx < 2048) {
      int pn = gperm(idx);
      bL0[idx] = ebih0[pn] + ebhh0[pn];
      bL1[idx] = ebih1[pn] + ebhh1[pn];
      bD0[idx] = dbih0[pn] + dbhh0[pn];
      bD1[idx] = dbih1[pn] + dbhh1[pn];
      w0c[idx] = dWih0[(size_t)pn * 513];
    }
    if (idx < 256) { inp[idx] = x[((size_t)idx * 512 + 511) * 64]; g_bar[idx] = 0; }
    h0b[idx] = (half_t)0.f;
    h1b[idx] = (half_t)0.f;
    if (idx < 131072) { c0[idx] = 0.f; c1[idx] = 0.f; }
  }
}

__global__ void kx16(const float* x) {
  half_t* dst = WSH(O_X16);   // (t, b, 128) zero-padded cols 64..127
  size_t i = (size_t)blockIdx.x * 256 + threadIdx.x;
  size_t stride = (size_t)gridDim.x * 256;
  for (size_t e = i; e < (size_t)512 * 256 * 128; e += stride) {
    int t = (int)(e >> 15);
    int b = (int)((e >> 7) & 255);
    int ii = (int)(e & 127);
    dst[e] = (ii < 64) ? (half_t)x[((size_t)b * 512 + t) * 64 + ii] : (half_t)0.f;
  }
}

// ---------------- launch ----------------
extern "C" void kernel_launch(void* const* d_in, const int* in_sizes, int n_in,
                              void* d_out, int out_size, void* d_ws, size_t ws_size,
                              hipStream_t stream) {
  const float* x     = (const float*)d_in[0];
  const float* eWih0 = (const float*)d_in[1];
  const float* eWhh0 = (const float*)d_in[2];
  const float* ebih0 = (const float*)d_in[3];
  const float* ebhh0 = (const float*)d_in[4];
  const float* eWih1 = (const float*)d_in[5];
  const float* eWhh1 = (const float*)d_in[6];
  const float* ebih1 = (const float*)d_in[7];
  const float* ebhh1 = (const float*)d_in[8];
  const float* dWih0 = (const float*)d_in[9];
  const float* dWhh0 = (const float*)d_in[10];
  const float* dbih0 = (const float*)d_in[11];
  const float* dbhh0 = (const float*)d_in[12];
  const float* dWih1 = (const float*)d_in[13];
  const float* dWhh1 = (const float*)d_in[14];
  const float* dbih1 = (const float*)d_in[15];
  const float* dbhh1 = (const float*)d_in[16];
  const float* attnW = (const float*)d_in[17];
  const float* attnv = (const float*)d_in[18];
  const float* outW  = (const float*)d_in[19];
  const float* outb  = (const float*)d_in[20];
  (void)in_sizes; (void)n_in; (void)out_size; (void)d_ws; (void)ws_size;

  kpackB<<<1024, 256, 0, stream>>>(O_WL0, 0, 32, 5, eWih0, eWhh0, nullptr, nullptr);
  kpackB<<<1024, 256, 0, stream>>>(O_WL1, 1, 32, 8, eWih1, eWhh1, nullptr, nullptr);
  kpackB<<<1024, 256, 0, stream>>>(O_WP1, 2, 73, 4, attnW, dWhh0, dWhh1, outW);
  kpackB<<<1024, 256, 0, stream>>>(O_WD0, 3, 32, 4, dWih0, nullptr, nullptr, nullptr);
  kpackB<<<1024, 256, 0, stream>>>(O_WD1, 4, 32, 4, dWih1, nullptr, nullptr, nullptr);
  kmisc<<<1024, 256, 0, stream>>>(ebih0, ebhh0, ebih1, ebhh1,
                                  dbih0, dbhh0, dbih1, dbhh1, dWih0, x);
  kx16<<<2048, 256, 0, stream>>>(x);

  float* outp = (float*)d_out;
  void* args[] = {(void*)&attnv, (void*)&outb, (void*)&outp};
  hipError_t e = hipLaunchCooperativeKernel((void*)kmain, dim3(256), dim3(512),
                                            args, 0, stream);
  if (e != hipSuccess) {
    // fallback: plain launch — custom atomic barrier; 256 blocks x 512 thr
    // (launch_bounds 512,2) are co-resident on 256 CUs
    kmain<<<dim3(256), dim3(512), 0, stream>>>(attnv, outb, outp);
  }
}

// Round 5
// 13801.157 us; speedup vs baseline: 1.4311x; 1.1583x over previous
//
#include <hip/hip_runtime.h>

// ---------------------------------------------------------------------------
// Seq2Seq LSTM + attention, persistent kernel for MI355X (gfx950)
// B=256, T=512, I=64, H=512, HORIZON=30, NQ=3
// R5: NO global barriers. 4 independent 64-block groups (batch-sliced), each
// with a hierarchical 2x32 group barrier (<=32 spinners per gen line).
// Encoder B-weights in VGPRs; P2 ctx via wave-split-t + LDS reduction.
// ---------------------------------------------------------------------------

typedef _Float16 half_t;
typedef __attribute__((ext_vector_type(8)))  _Float16 f16x8;
typedef __attribute__((ext_vector_type(16))) float    f32x16;

#define MFMA(a,b,c) __builtin_amdgcn_mfma_f32_32x32x16_f16((a),(b),(c),0,0,0)
#define WAITV4()   asm volatile("s_waitcnt vmcnt(4)" ::: "memory")
#define WAITV2()   asm volatile("s_waitcnt vmcnt(2)" ::: "memory")
#define WAITV0()   asm volatile("s_waitcnt vmcnt(0)" ::: "memory")
#define WAITLGKM() asm volatile("s_waitcnt lgkmcnt(0)" ::: "memory")
#define CBAR()     asm volatile("" ::: "memory")

__device__ __forceinline__ float fsig(float x)  { return 1.0f / (1.0f + __expf(-x)); }
__device__ __forceinline__ float ftanh(float x) { return 1.0f - 2.0f / (1.0f + __expf(2.0f * x)); }

// ---------------- workspace layout (bytes, inside g_ws) ----------------
static constexpr size_t O_X16 = 0;                             // (T,B,128) f16 x zero-padded
static constexpr size_t O_WL0 = O_X16 + (size_t)512*256*128*2; // 32t x 5c packed  (2048x640)
static constexpr size_t O_WL1 = O_WL0 + (size_t)2048*640*2;    // 32t x 8c packed  (2048x1024)
static constexpr size_t O_WP1 = O_WL1 + (size_t)2048*1024*2;   // 73t x 4c packed  (4672x512)
static constexpr size_t O_WD0 = O_WP1 + (size_t)4672*512*2;    // 32t x 4c packed
static constexpr size_t O_WD1 = O_WD0 + (size_t)2048*512*2;    // 32t x 4c packed
static constexpr size_t O_BL0 = O_WD1 + (size_t)2048*512*2;    // 2048 f32 biases (gate-permuted)
static constexpr size_t O_BL1 = O_BL0 + 8192;
static constexpr size_t O_BD0 = O_BL1 + 8192;
static constexpr size_t O_BD1 = O_BD0 + 8192;
static constexpr size_t O_W0C = O_BD1 + 8192;                  // 2048 f32 dec_Wih0[:,0] permuted
static constexpr size_t O_H0B = O_W0C + 8192;                  // 2 x (256,512) f16 L0 h ping-pong
static constexpr size_t O_H1B = O_H0B + (size_t)2*256*512*2;   // 2 x (256,512) f16 L1 h ping-pong
static constexpr size_t O_HD1 = O_H1B + (size_t)2*256*512*2;   // (256,512) f16 decoder h1
static constexpr size_t O_H0D = O_HD1 + (size_t)256*512*2;     // (256,512) f16 decoder h0
static constexpr size_t O_CTX = O_H0D + (size_t)256*512*2;     // (256,512) f16 context
static constexpr size_t O_C0  = O_CTX + (size_t)256*512*2;     // (256,512) f32
static constexpr size_t O_C1  = O_C0  + (size_t)256*512*4;     // (256,512) f32
static constexpr size_t O_INP = O_C1  + (size_t)256*512*4;     // 256 f32
static constexpr size_t O_GAT = O_INP + 1024;                  // (256,4672) f32 gate partials
static constexpr size_t O_EO  = O_GAT + (size_t)256*4672*4;    // (B*T,H) f16 encoder outputs
static constexpr size_t O_EP  = O_EO  + (size_t)256*512*512*2; // (B*T,512) f16 enc_proj
static constexpr size_t WS_NEED = O_EP + (size_t)256*512*512*2;

__device__ __align__(4096) unsigned char g_ws[WS_NEED];
__device__ int g_bar[2048];   // 128B-line-separated barrier state

#define WSH(o) ((half_t*)(g_ws + (o)))
#define WSCH(o) ((const half_t*)(g_ws + (o)))
#define WSF(o) ((float*)(g_ws + (o)))
#define WSCF(o) ((const float*)(g_ws + (o)))
#define BLINE(i) (g_bar + ((size_t)(i) << 5))

__device__ __forceinline__ int gperm(int n) { return (n & 3) * 512 + (n >> 2); }

// ------- per-group barrier: 64 blocks = 2 subgroups of 32, per-sub gen line --
// lines: cnt g*2+sub (0..7) | mst 8+g (8..11) | gen 12+g*2+sub (12..19)
__device__ __forceinline__ void gbar_g(int g, int sub) {
  __syncthreads();
  if (threadIdx.x == 0) {
    int* cnt = BLINE(g * 2 + sub);
    int* mst = BLINE(8 + g);
    int* gs  = BLINE(12 + g * 2 + sub);
    int old = __hip_atomic_load(gs, __ATOMIC_RELAXED, __HIP_MEMORY_SCOPE_AGENT);
    int a = __hip_atomic_fetch_add(cnt, 1, __ATOMIC_ACQ_REL, __HIP_MEMORY_SCOPE_AGENT);
    if (a == 31) {
      __hip_atomic_store(cnt, 0, __ATOMIC_RELAXED, __HIP_MEMORY_SCOPE_AGENT);
      int m = __hip_atomic_fetch_add(mst, 1, __ATOMIC_ACQ_REL, __HIP_MEMORY_SCOPE_AGENT);
      if (m == 1) {
        __hip_atomic_store(mst, 0, __ATOMIC_RELAXED, __HIP_MEMORY_SCOPE_AGENT);
        __hip_atomic_fetch_add(BLINE(12 + g * 2), 1, __ATOMIC_RELEASE, __HIP_MEMORY_SCOPE_AGENT);
        __hip_atomic_fetch_add(BLINE(12 + g * 2 + 1), 1, __ATOMIC_RELEASE, __HIP_MEMORY_SCOPE_AGENT);
      }
    }
    while (__hip_atomic_load(gs, __ATOMIC_RELAXED, __HIP_MEMORY_SCOPE_AGENT) == old)
      __builtin_amdgcn_s_sleep(4);
    (void)__hip_atomic_load(gs, __ATOMIC_ACQUIRE, __HIP_MEMORY_SCOPE_AGENT);
  }
  __syncthreads();
}

// ---------------- GEMM cores: 64x64 tile, K-split over 8 waves (chunk=128) ---
struct Seg { const half_t* p; int stride; int row0; };

__device__ __forceinline__ void stageA(Seg sa, Seg sb, int cSplit, int c,
                                       int lane, int wid, char* dst) {
  Seg s = (c < cSplit) ? sa : sb;
  int kb = ((c < cSplit) ? c : (c - cSplit)) * 128;
  const half_t* g = s.p + (size_t)(s.row0 + (lane & 31)) * s.stride
                        + kb + (wid << 4) + ((lane >> 5) << 3);
  __builtin_amdgcn_global_load_lds(
      (const __attribute__((address_space(1))) unsigned int*)g,
      (__attribute__((address_space(3))) unsigned int*)dst, 16, 0, 0);
  g += (size_t)32 * s.stride;
  __builtin_amdgcn_global_load_lds(
      (const __attribute__((address_space(1))) unsigned int*)g,
      (__attribute__((address_space(3))) unsigned int*)(dst + 1024), 16, 0, 0);
}

// Encoder GEMM: B held in registers; only A-stage VMEM in loop
template<int NC, int CSPLIT>
__device__ __forceinline__ void gemm_regB(Seg sa, Seg sb,
                                          const f16x8 (&B0)[8], const f16x8 (&B1)[8],
                                          int lane, int wid, char* asg,
                                          f32x16 acc[2][2]) {
  WAITV0(); WAITLGKM();
  stageA(sa, sb, CSPLIT, 0, lane, wid, asg + (size_t)wid * 2048);
  if (NC > 1) stageA(sa, sb, CSPLIT, 1, lane, wid, asg + (size_t)(8 + wid) * 2048);
  CBAR();
  #pragma unroll
  for (int c = 0; c < NC; c++) {
    if (c + 1 < NC) { WAITV2(); } else { WAITV0(); }
    char* ab = asg + (size_t)(((c & 1) * 8 + wid)) * 2048 + lane * 16;
    f16x8 a0 = *(const f16x8*)ab;
    f16x8 a1 = *(const f16x8*)(ab + 1024);
    WAITLGKM();
    acc[0][0] = MFMA(a0, B0[c], acc[0][0]);
    acc[0][1] = MFMA(a0, B1[c], acc[0][1]);
    acc[1][0] = MFMA(a1, B0[c], acc[1][0]);
    acc[1][1] = MFMA(a1, B1[c], acc[1][1]);
    if (c + 2 < NC)
      stageA(sa, sb, CSPLIT, c + 2, lane, wid,
             asg + (size_t)(((c & 1) * 8 + wid)) * 2048);
    CBAR();
  }
}

// Streamed-B GEMM (fully unrolled, depth-2 group prefetch)
template<int NC>
__device__ __forceinline__ void gemm_ks(Seg sa, Seg sb, int cSplit,
                                        const half_t* Wt,
                                        int lane, int wid, char* asg,
                                        f32x16 acc[2][2]) {
  WAITV0(); WAITLGKM();
  const half_t* wb = Wt + (wid << 1) * 512 + lane * 8;
  f16x8 b0[2], b1[2];
  b0[0] = *(const f16x8*)wb;
  b1[0] = *(const f16x8*)(wb + 512);
  stageA(sa, sb, cSplit, 0, lane, wid, asg + (size_t)wid * 2048);
  CBAR();
  b0[1] = *(const f16x8*)(wb + 8192);
  b1[1] = *(const f16x8*)(wb + 8192 + 512);
  stageA(sa, sb, cSplit, 1, lane, wid, asg + (size_t)(8 + wid) * 2048);
  CBAR();
  #pragma unroll
  for (int c = 0; c < NC; c++) {
    if (c + 1 < NC) { WAITV4(); } else { WAITV0(); }
    char* ab = asg + (size_t)(((c & 1) * 8 + wid)) * 2048 + lane * 16;
    f16x8 a0 = *(const f16x8*)ab;
    f16x8 a1 = *(const f16x8*)(ab + 1024);
    WAITLGKM();
    acc[0][0] = MFMA(a0, b0[c & 1], acc[0][0]);
    acc[0][1] = MFMA(a0, b1[c & 1], acc[0][1]);
    acc[1][0] = MFMA(a1, b0[c & 1], acc[1][0]);
    acc[1][1] = MFMA(a1, b1[c & 1], acc[1][1]);
    if (c + 2 < NC) {
      b0[c & 1] = *(const f16x8*)(wb + (size_t)(c + 2) * 8192);
      b1[c & 1] = *(const f16x8*)(wb + (size_t)(c + 2) * 8192 + 512);
      stageA(sa, sb, cSplit, c + 2, lane, wid,
             asg + (size_t)(((c & 1) * 8 + wid)) * 2048);
    }
    CBAR();
  }
}

// conflict-free partial-tile store: float4 per (t,r4), consecutive lanes
__device__ __forceinline__ void acc_wr(float* dst, int lane, f32x16 acc[2][2]) {
  #pragma unroll
  for (int t = 0; t < 4; t++) {
    f32x16 a = acc[t >> 1][t & 1];
    #pragma unroll
    for (int r4 = 0; r4 < 4; r4++)
      *(float4*)(dst + ((t * 4 + r4) * 64 + lane) * 4) =
          make_float4(a[r4*4], a[r4*4+1], a[r4*4+2], a[r4*4+3]);
  }
}
__device__ __forceinline__ void acc_add(const float* src, int lane, f32x16 acc[2][2]) {
  #pragma unroll
  for (int t = 0; t < 4; t++) {
    #pragma unroll
    for (int r4 = 0; r4 < 4; r4++) {
      float4 v = *(const float4*)(src + ((t * 4 + r4) * 64 + lane) * 4);
      acc[t>>1][t&1][r4*4]   += v.x;
      acc[t>>1][t&1][r4*4+1] += v.y;
      acc[t>>1][t&1][r4*4+2] += v.z;
      acc[t>>1][t&1][r4*4+3] += v.w;
    }
  }
}

// reduce the 8 waves' K-split partials; final 64x64 tile in red[row*64+col]
__device__ __forceinline__ void reduce_scatter(f32x16 acc[2][2], float* red,
                                               int lane, int wid) {
  if (wid >= 4) acc_wr(red + (size_t)(wid - 4) * 4096, lane, acc);
  __syncthreads();
  if (wid < 4) acc_add(red + (size_t)wid * 4096, lane, acc);
  __syncthreads();
  if (wid == 2 || wid == 3) acc_wr(red + (size_t)(wid - 2) * 4096, lane, acc);
  __syncthreads();
  if (wid < 2) acc_add(red + (size_t)wid * 4096, lane, acc);
  __syncthreads();
  if (wid == 1) acc_wr(red, lane, acc);
  __syncthreads();
  if (wid == 0) {
    acc_add(red, lane, acc);
    #pragma unroll
    for (int ms = 0; ms < 2; ms++)
      #pragma unroll
      for (int ns = 0; ns < 2; ns++)
        #pragma unroll
        for (int r = 0; r < 16; r++) {
          int row = ms * 32 + (r & 3) + ((r >> 2) << 3) + ((lane >> 5) << 2);
          red[row * 64 + ns * 32 + (lane & 31)] = acc[ms][ns][r];
        }
  }
  __syncthreads();
}

// ---------------- main persistent kernel (4 independent groups) ----------------
__global__ void __launch_bounds__(512, 2) kmain(const float* __restrict__ attn_v,
                                                const float* __restrict__ out_b,
                                                float* __restrict__ out) {
  __shared__ __align__(16) char asg[32768];  // A staging: 2 bufs x 8 waves x 2KB
  __shared__ float red[16384];               // 64KB reduction / scratch

  const half_t* x16 = WSCH(O_X16);
  const half_t* wL0 = WSCH(O_WL0);
  const half_t* wL1 = WSCH(O_WL1);
  const half_t* wP1 = WSCH(O_WP1);
  const half_t* wD0 = WSCH(O_WD0);
  const half_t* wD1 = WSCH(O_WD1);
  half_t* h0bB = WSH(O_H0B);
  half_t* h1bB = WSH(O_H1B);
  half_t* hd1  = WSH(O_HD1);
  half_t* h0d  = WSH(O_H0D);
  half_t* ctx  = WSH(O_CTX);
  half_t* eo   = WSH(O_EO);
  half_t* ep   = WSH(O_EP);
  float* c0 = WSF(O_C0);
  float* c1 = WSF(O_C1);
  float* inp = WSF(O_INP);
  float* gates = WSF(O_GAT);

  const int tid = threadIdx.x;
  const int wid = tid >> 6;
  const int lane = tid & 63;
  const int g = blockIdx.x & 3;        // batch-slice group (2 XCDs under %8)
  const int r = blockIdx.x >> 2;       // rank within group, 0..63
  const int sub = r & 1;               // XCD-aligned subgroup
  const int m0 = g << 6;               // this group's batch-row base
  const f32x16 zv = {0,0,0,0,0,0,0,0,0,0,0,0,0,0,0,0};

  // ================= encoder: 513 wavefront-pipelined steps =================
  {
    const bool isL1 = r >= 32;
    const int n0 = (r & 31) << 6;

    // preload this block's B-weight slice into VGPRs (held 513 steps)
    const half_t* wbase = isL1 ? (wL1 + (size_t)(n0 >> 6) * (8 * 8192))
                               : (wL0 + (size_t)(n0 >> 6) * (5 * 8192));
    const half_t* wb = wbase + (wid << 1) * 512 + lane * 8;
    const int ncB = isL1 ? 8 : 5;
    f16x8 B0[8], B1[8];
    #pragma unroll
    for (int c = 0; c < 8; c++) {
      if (c < ncB) {
        B0[c] = *(const f16x8*)(wb + (size_t)c * 8192);
        B1[c] = *(const f16x8*)(wb + (size_t)c * 8192 + 512);
      }
    }

    for (int s = 0; s <= 512; s++) {
      const bool active = isL1 ? (s > 0) : (s < 512);
      if (active) {
        const half_t* h0r = h0bB + (size_t)((s + 1) & 1) * (256 * 512);
        f32x16 acc[2][2] = {{zv, zv}, {zv, zv}};
        int t;
        if (!isL1) {
          t = s;
          gemm_regB<5, 1>(Seg{x16, 128, t * 256 + m0}, Seg{h0r, 512, m0},
                          B0, B1, lane, wid, asg, acc);
        } else {
          t = s - 1;
          const half_t* h1r = h1bB + (size_t)(s & 1) * (256 * 512);
          gemm_regB<8, 4>(Seg{h0r, 512, m0}, Seg{h1r, 512, m0},
                          B0, B1, lane, wid, asg, acc);
        }
        reduce_scatter(acc, red, lane, wid);
        const float* bias = isL1 ? WSCF(O_BL1) : WSCF(O_BL0);
        float* cb = isL1 ? c1 : c0;
        half_t* hb = isL1 ? (h1bB + (size_t)((s - 1) & 1) * (256 * 512))
                          : (h0bB + (size_t)(s & 1) * (256 * 512));
        #pragma unroll
        for (int it = 0; it < 2; it++) {
          int p = it * 512 + tid;
          int u = p & 15, bl = p >> 4;
          int nl = n0 + u * 4;
          float4 g4 = *(float4*)&red[bl * 64 + u * 4];
          float4 b4 = *(const float4*)&bias[nl];
          float gi = g4.x + b4.x, gf = g4.y + b4.y, gz = g4.z + b4.z, go = g4.w + b4.w;
          int bg = m0 + bl, ug = (n0 >> 2) + u;
          float cold = cb[bg * 512 + ug];
          float cn = fsig(gf) * cold + fsig(gi) * ftanh(gz);
          float hn = fsig(go) * ftanh(cn);
          cb[bg * 512 + ug] = cn;
          hb[bg * 512 + ug] = (half_t)hn;
          if (isL1) eo[((size_t)bg * 512 + t) * 512 + ug] = (half_t)hn;
        }
      }
      gbar_g(g, sub);
    }
  }

  // ====== enc_proj = enc_out @ attn_W^T (f16), group-local rows ======
  for (int j = 0; j < 64; j++) {
    const int jj = r * 64 + j;           // 0..4095 within group
    const int ml = jj >> 3;              // 0..511
    const int nt = jj & 7;
    const int row0 = (g << 15) + ml * 64;   // ep/eo row base (g*32768)
    f32x16 acc[2][2] = {{zv, zv}, {zv, zv}};
    gemm_ks<4>(Seg{eo, 512, row0}, Seg{eo, 512, row0}, 4,
               wP1 + (size_t)nt * (4 * 8192), lane, wid, asg, acc);
    reduce_scatter(acc, red, lane, wid);
    {
      int base = tid * 8;
      int row = base >> 6, col = base & 63;
      f16x8 h8;
      #pragma unroll
      for (int q = 0; q < 8; q++) h8[q] = (half_t)red[row * 64 + col + q];
      *(f16x8*)&ep[(size_t)(row0 + row) * 512 + nt * 64 + col] = h8;
    }
    __syncthreads();   // protect red[] from next tile's reduce pre-write
  }
  gbar_g(g, sub);

  // ================= decoder: 30 steps (d=30 = final output-only pass) ======
  for (int d = 0; d <= 30; d++) {
    // ---- P1: h1 @ [attn_W | dWhh0 | dWhh1 | out_W]  (73 n-tiles / group) ----
    const half_t* hs = (d == 0) ? (h1bB + 256 * 512) : hd1;
    for (int jj = r; jj < 73; jj += 64) {
      const int n0p = jj * 64;
      f32x16 acc[2][2] = {{zv, zv}, {zv, zv}};
      gemm_ks<4>(Seg{hs, 512, m0}, Seg{hs, 512, m0}, 4,
                 wP1 + (size_t)jj * (4 * 8192), lane, wid, asg, acc);
      reduce_scatter(acc, red, lane, wid);
      if (n0p < 4608) {
        #pragma unroll
        for (int it = 0; it < 2; it++) {
          int p4 = (it * 512 + tid) * 4;
          int row = p4 >> 6, col = p4 & 63;
          *(float4*)&gates[(size_t)(m0 + row) * 4672 + n0p + col] = *(float4*)&red[p4];
        }
      } else if (d > 0) {
        if (tid < 64) {
          int bg = m0 + tid;
          float v0 = red[tid * 64 + 0] + out_b[0];
          float v1 = red[tid * 64 + 1] + out_b[1];
          float v2 = red[tid * 64 + 2] + out_b[2];
          out[(size_t)bg * 90 + (d - 1) * 3 + 0] = v0;
          out[(size_t)bg * 90 + (d - 1) * 3 + 1] = v1;
          out[(size_t)bg * 90 + (d - 1) * 3 + 2] = v2;
          inp[bg] = v1;
        }
      }
      __syncthreads();   // protect red[] across jj iterations
    }
    gbar_g(g, sub);
    if (d == 30) break;

    // ---- P2: attention for batch row b = g*64 + r ----
    {
      const int b = m0 + r;
      float* dpb = red;          // 512
      float* vb  = red + 512;    // 512
      float* eb  = red + 1024;   // 512
      float* ab2 = red + 2048;   // 512
      float* sc  = red + 2560;   // 16
      float* pm  = red + 4096;   // 8x512 ctx partials
      dpb[tid] = gates[(size_t)b * 4672 + tid];
      vb[tid]  = attn_v[tid];
      __syncthreads();
      const half_t* eprow = ep + ((size_t)b << 18) + (size_t)(wid * 64) * 512 + lane * 8;
      for (int tt = 0; tt < 64; tt++) {
        f16x8 e8 = *(const f16x8*)(eprow + (size_t)tt * 512);
        float sum = 0.f;
        #pragma unroll
        for (int jq = 0; jq < 8; jq++)
          sum += vb[lane * 8 + jq] * ftanh((float)e8[jq] + dpb[lane * 8 + jq]);
        #pragma unroll
        for (int off = 32; off > 0; off >>= 1) sum += __shfl_down(sum, off, 64);
        if (lane == 0) eb[wid * 64 + tt] = sum;
      }
      __syncthreads();
      float e0 = eb[tid];
      float mx = e0;
      #pragma unroll
      for (int off = 32; off > 0; off >>= 1) mx = fmaxf(mx, __shfl_xor(mx, off, 64));
      if (lane == 0) sc[wid] = mx;
      __syncthreads();
      mx = sc[0];
      #pragma unroll
      for (int q = 1; q < 8; q++) mx = fmaxf(mx, sc[q]);
      float x0 = __expf(e0 - mx);
      float ssum = x0;
      #pragma unroll
      for (int off = 32; off > 0; off >>= 1) ssum += __shfl_xor(ssum, off, 64);
      __syncthreads();
      if (lane == 0) sc[8 + wid] = ssum;
      __syncthreads();
      float tot = sc[8];
      #pragma unroll
      for (int q = 1; q < 8; q++) tot += sc[8 + q];
      float inv = 1.f / tot;
      ab2[tid] = x0 * inv;
      __syncthreads();
      // ctx: wave w handles t in [w*64, w*64+64), 8 cols/lane, LDS reduce
      float pacc[8] = {0,0,0,0,0,0,0,0};
      const half_t* eow = eo + ((size_t)b << 18) + (size_t)(wid * 64) * 512 + lane * 8;
      for (int tt = 0; tt < 64; tt++) {
        f16x8 h8 = *(const f16x8*)(eow + (size_t)tt * 512);
        float at = ab2[wid * 64 + tt];
        #pragma unroll
        for (int jq = 0; jq < 8; jq++) pacc[jq] += at * (float)h8[jq];
      }
      #pragma unroll
      for (int jq = 0; jq < 8; jq++) pm[wid * 512 + lane * 8 + jq] = pacc[jq];
      __syncthreads();
      float sctx = 0.f;
      #pragma unroll
      for (int w = 0; w < 8; w++) sctx += pm[w * 512 + tid];
      ctx[(b << 9) + tid] = (half_t)sctx;
    }
    gbar_g(g, sub);

    // ---- P3: gates0 = ctx @ dWih0[:,1:] + inp*w0col + partial + bias -> h0d ----
    if (r < 32) {
      const int n0 = r << 6;
      f32x16 acc[2][2] = {{zv, zv}, {zv, zv}};
      gemm_ks<4>(Seg{ctx, 512, m0}, Seg{ctx, 512, m0}, 4,
                 wD0 + (size_t)(n0 >> 6) * (4 * 8192), lane, wid, asg, acc);
      reduce_scatter(acc, red, lane, wid);
      const float* bD0 = WSCF(O_BD0);
      const float* w0c = WSCF(O_W0C);
      #pragma unroll
      for (int it = 0; it < 2; it++) {
        int p = it * 512 + tid;
        int u = p & 15, bl = p >> 4;
        int bg = m0 + bl, ug = (n0 >> 2) + u, nl = n0 + u * 4;
        float4 g4 = *(float4*)&red[bl * 64 + u * 4];
        float4 p4 = *(const float4*)&gates[(size_t)bg * 4672 + 512 + nl];
        float4 b4 = *(const float4*)&bD0[nl];
        float4 w4 = *(const float4*)&w0c[nl];
        float iv = inp[bg];
        float gi = g4.x + p4.x + b4.x + iv * w4.x;
        float gf = g4.y + p4.y + b4.y + iv * w4.y;
        float gz = g4.z + p4.z + b4.z + iv * w4.z;
        float go = g4.w + p4.w + b4.w + iv * w4.w;
        float cold = c1[bg * 512 + ug];
        float cn = fsig(gf) * cold + fsig(gi) * ftanh(gz);
        h0d[bg * 512 + ug] = (half_t)(fsig(go) * ftanh(cn));
      }
    }
    gbar_g(g, sub);

    // ---- P4: gates1 = h0d @ dWih1 + partial + bias -> c1, hd1 ----
    if (r < 32) {
      const int n0 = r << 6;
      f32x16 acc[2][2] = {{zv, zv}, {zv, zv}};
      gemm_ks<4>(Seg{h0d, 512, m0}, Seg{h0d, 512, m0}, 4,
                 wD1 + (size_t)(n0 >> 6) * (4 * 8192), lane, wid, asg, acc);
      reduce_scatter(acc, red, lane, wid);
      const float* bD1 = WSCF(O_BD1);
      #pragma unroll
      for (int it = 0; it < 2; it++) {
        int p = it * 512 + tid;
        int u = p & 15, bl = p >> 4;
        int bg = m0 + bl, ug = (n0 >> 2) + u, nl = n0 + u * 4;
        float4 g4 = *(float4*)&red[bl * 64 + u * 4];
        float4 p4 = *(const float4*)&gates[(size_t)bg * 4672 + 2560 + nl];
        float4 b4 = *(const float4*)&bD1[nl];
        float gi = g4.x + p4.x + b4.x;
        float gf = g4.y + p4.y + b4.y;
        float gz = g4.z + p4.z + b4.z;
        float go = g4.w + p4.w + b4.w;
        float cold = c1[bg * 512 + ug];
        float cn = fsig(gf) * cold + fsig(gi) * ftanh(gz);
        float hn = fsig(go) * ftanh(cn);
        c1[bg * 512 + ug] = cn;
        hd1[bg * 512 + ug] = (half_t)hn;
      }
    }
    gbar_g(g, sub);
  }
}

// ---------------- prep kernels ----------------
// packed-B layout (halves): e = (((tile*NC + c)*8 + w)*2 + bh)*512 + l*8 + j
// -> n = tile*64 + bh*32 + (l&31), k = c*128 + w*16 + (l>>5)*8 + j
__global__ void kpackB(size_t dstOff, int id, int Ntiles, int NC,
                       const float* s0, const float* s1,
                       const float* s2, const float* s3) {
  half_t* dst = (half_t*)(g_ws + dstOff);
  size_t total = (size_t)Ntiles * NC * 8192;
  size_t i = (size_t)blockIdx.x * 256 + threadIdx.x;
  size_t stride = (size_t)gridDim.x * 256;
  for (size_t e = i; e < total; e += stride) {
    int j = e & 7;
    int l = (e >> 3) & 63;
    int bh = (e >> 9) & 1;
    int w = (e >> 10) & 7;
    int tc = (int)(e >> 13);
    int c = tc % NC;
    int tile = tc / NC;
    int n = tile * 64 + bh * 32 + (l & 31);
    int k = c * 128 + w * 16 + ((l >> 5) << 3) + j;
    float v = 0.f;
    if (id == 0) {          // wL0: [Wih0(64) | pad(64) | Whh0(512)]
      int pn = gperm(n);
      if (k < 64) v = s0[(size_t)pn * 64 + k];
      else if (k >= 128) v = s1[(size_t)pn * 512 + (k - 128)];
    } else if (id == 1) {   // wL1: [Wih1(512) | Whh1(512)]
      int pn = gperm(n);
      v = (k < 512) ? s0[(size_t)pn * 512 + k] : s1[(size_t)pn * 512 + (k - 512)];
    } else if (id == 2) {   // wP1: [attnW | dWhh0 | dWhh1 | outW | pad]
      if (n < 512) v = s0[((size_t)n << 9) + k];
      else if (n < 2560) v = s1[((size_t)gperm(n - 512) << 9) + k];
      else if (n < 4608) v = s2[((size_t)gperm(n - 2560) << 9) + k];
      else if (n < 4611) v = s3[((size_t)(n - 4608) << 9) + k];
    } else if (id == 3) {   // wD0: dec_Wih0[:,1:]
      v = s0[(size_t)gperm(n) * 513 + 1 + k];
    } else {                // wD1
      v = s0[((size_t)gperm(n) << 9) + k];
    }
    dst[e] = (half_t)v;
  }
}

__global__ void kmisc(const float* ebih0, const float* ebhh0, const float* ebih1, const float* ebhh1,
                      const float* dbih0, const float* dbhh0, const float* dbih1, const float* dbhh1,
                      const float* dWih0, const float* x) {
  float* bL0 = WSF(O_BL0);
  float* bL1 = WSF(O_BL1);
  float* bD0 = WSF(O_BD0);
  float* bD1 = WSF(O_BD1);
  float* w0c = WSF(O_W0C);
  half_t* h0b = WSH(O_H0B);
  half_t* h1b = WSH(O_H1B);
  float* c0 = WSF(O_C0);
  float* c1 = WSF(O_C1);
  float* inp = WSF(O_INP);
  int i = blockIdx.x * 256 + threadIdx.x, stride = gridDim.x * 256;
  for (int idx = i; idx < 262144; idx += stride) {
    if (idx < 2048) {
      int pn = gperm(idx);
      bL0[idx] = ebih0[pn] + ebhh0[pn];
      bL1[idx] = ebih1[pn] + ebhh1[pn];
      bD0[idx] = dbih0[pn] + dbhh0[pn];
      bD1[idx] = dbih1[pn] + dbhh1[pn];
      w0c[idx] = dWih0[(size_t)pn * 513];
      g_bar[idx] = 0;
    }
    if (idx < 256) inp[idx] = x[((size_t)idx * 512 + 511) * 64];
    h0b[idx] = (half_t)0.f;
    h1b[idx] = (half_t)0.f;
    if (idx < 131072) { c0[idx] = 0.f; c1[idx] = 0.f; }
  }
}

__global__ void kx16(const float* x) {
  half_t* dst = WSH(O_X16);   // (t, b, 128) zero-padded cols 64..127
  size_t i = (size_t)blockIdx.x * 256 + threadIdx.x;
  size_t stride = (size_t)gridDim.x * 256;
  for (size_t e = i; e < (size_t)512 * 256 * 128; e += stride) {
    int t = (int)(e >> 15);
    int b = (int)((e >> 7) & 255);
    int ii = (int)(e & 127);
    dst[e] = (ii < 64) ? (half_t)x[((size_t)b * 512 + t) * 64 + ii] : (half_t)0.f;
  }
}

// ---------------- launch ----------------
extern "C" void kernel_launch(void* const* d_in, const int* in_sizes, int n_in,
                              void* d_out, int out_size, void* d_ws, size_t ws_size,
                              hipStream_t stream) {
  const float* x     = (const float*)d_in[0];
  const float* eWih0 = (const float*)d_in[1];
  const float* eWhh0 = (const float*)d_in[2];
  const float* ebih0 = (const float*)d_in[3];
  const float* ebhh0 = (const float*)d_in[4];
  const float* eWih1 = (const float*)d_in[5];
  const float* eWhh1 = (const float*)d_in[6];
  const float* ebih1 = (const float*)d_in[7];
  const float* ebhh1 = (const float*)d_in[8];
  const float* dWih0 = (const float*)d_in[9];
  const float* dWhh0 = (const float*)d_in[10];
  const float* dbih0 = (const float*)d_in[11];
  const float* dbhh0 = (const float*)d_in[12];
  const float* dWih1 = (const float*)d_in[13];
  const float* dWhh1 = (const float*)d_in[14];
  const float* dbih1 = (const float*)d_in[15];
  const float* dbhh1 = (const float*)d_in[16];
  const float* attnW = (const float*)d_in[17];
  const float* attnv = (const float*)d_in[18];
  const float* outW  = (const float*)d_in[19];
  const float* outb  = (const float*)d_in[20];
  (void)in_sizes; (void)n_in; (void)out_size; (void)d_ws; (void)ws_size;

  kpackB<<<1024, 256, 0, stream>>>(O_WL0, 0, 32, 5, eWih0, eWhh0, nullptr, nullptr);
  kpackB<<<1024, 256, 0, stream>>>(O_WL1, 1, 32, 8, eWih1, eWhh1, nullptr, nullptr);
  kpackB<<<1024, 256, 0, stream>>>(O_WP1, 2, 73, 4, attnW, dWhh0, dWhh1, outW);
  kpackB<<<1024, 256, 0, stream>>>(O_WD0, 3, 32, 4, dWih0, nullptr, nullptr, nullptr);
  kpackB<<<1024, 256, 0, stream>>>(O_WD1, 4, 32, 4, dWih1, nullptr, nullptr, nullptr);
  kmisc<<<1024, 256, 0, stream>>>(ebih0, ebhh0, ebih1, ebhh1,
                                  dbih0, dbhh0, dbih1, dbhh1, dWih0, x);
  kx16<<<2048, 256, 0, stream>>>(x);

  float* outp = (float*)d_out;
  void* args[] = {(void*)&attnv, (void*)&outb, (void*)&outp};
  hipError_t e = hipLaunchCooperativeKernel((void*)kmain, dim3(256), dim3(512),
                                            args, 0, stream);
  if (e != hipSuccess) {
    // fallback: plain launch — per-group atomic barriers only; 256 blocks x
    // 512 thr (launch_bounds 512,2) are co-resident on 256 CUs
    kmain<<<dim3(256), dim3(512), 0, stream>>>(attnv, outb, outp);
  }
}

// Round 6
// 8504.759 us; speedup vs baseline: 2.3223x; 1.6228x over previous
//
#include <hip/hip_runtime.h>

// ---------------------------------------------------------------------------
// Seq2Seq LSTM + attention, persistent kernel for MI355X (gfx950)
// B=256, T=512, I=64, H=512, HORIZON=30, NQ=3
// R6: relaxed barriers (no per-step L2 writeback/invalidate). Cross-block data
// uses agent-coherent ops (atomic sc0|sc1 stores; global_load_lds aux=0x11).
// Read-only data (x16/weights/bias) stays L2-resident. c-state + bias in VGPRs
// during encoder. Burst-issue ring-4 K-loop. 2-sync LDS reduction.
// Heavy acq/rel barriers only at the two phase boundaries.
// ---------------------------------------------------------------------------

typedef _Float16 half_t;
typedef __attribute__((ext_vector_type(8)))  _Float16 f16x8;
typedef __attribute__((ext_vector_type(16))) float    f32x16;

#define MFMA(a,b,c) __builtin_amdgcn_mfma_f32_32x32x16_f16((a),(b),(c),0,0,0)
#define CBAR()      asm volatile("" ::: "memory")
#define AUXC 17   // CPol SC0|SC1: agent-coherent (bypass stale L1/L2)

template<int N> __device__ __forceinline__ void waitvm() {
  asm volatile("s_waitcnt vmcnt(%0)" :: "n"(N) : "memory");
}

__device__ __forceinline__ float fsig(float x)  { return 1.0f / (1.0f + __expf(-x)); }
__device__ __forceinline__ float ftanh(float x) { return 1.0f - 2.0f / (1.0f + __expf(2.0f * x)); }

// ---------------- coherent scalar ops (agent scope, relaxed) ----------------
union FU { float f; unsigned u; };
union HU { _Float16 h; unsigned short u; };
__device__ __forceinline__ float ldfa(const float* p) {
  unsigned v = __hip_atomic_load((const unsigned*)p, __ATOMIC_RELAXED, __HIP_MEMORY_SCOPE_AGENT);
  FU c; c.u = v; return c.f;
}
__device__ __forceinline__ void stfa(float* p, float v) {
  FU c; c.f = v;
  __hip_atomic_store((unsigned*)p, c.u, __ATOMIC_RELAXED, __HIP_MEMORY_SCOPE_AGENT);
}
__device__ __forceinline__ void stha(half_t* p, float v) {
  HU c; c.h = (half_t)v;
  __hip_atomic_store((unsigned short*)p, c.u, __ATOMIC_RELAXED, __HIP_MEMORY_SCOPE_AGENT);
}
__device__ __forceinline__ void st64(float* p, float a, float b) {
  FU x, y; x.f = a; y.f = b;
  unsigned long long v = (unsigned long long)x.u | ((unsigned long long)y.u << 32);
  __hip_atomic_store((unsigned long long*)p, v, __ATOMIC_RELAXED, __HIP_MEMORY_SCOPE_AGENT);
}
__device__ __forceinline__ void ld64(const float* p, float& a, float& b) {
  unsigned long long v = __hip_atomic_load((const unsigned long long*)p, __ATOMIC_RELAXED, __HIP_MEMORY_SCOPE_AGENT);
  FU x, y; x.u = (unsigned)v; y.u = (unsigned)(v >> 32); a = x.f; b = y.f;
}

// ---------------- workspace layout (bytes, inside g_ws) ----------------
static constexpr size_t O_X16 = 0;                             // (T,B,128) f16 x zero-padded
static constexpr size_t O_WL0 = O_X16 + (size_t)512*256*128*2; // 32t x 5c packed  (2048x640)
static constexpr size_t O_WL1 = O_WL0 + (size_t)2048*640*2;    // 32t x 8c packed  (2048x1024)
static constexpr size_t O_WP1 = O_WL1 + (size_t)2048*1024*2;   // 73t x 4c packed  (4672x512)
static constexpr size_t O_WD0 = O_WP1 + (size_t)4672*512*2;    // 32t x 4c packed
static constexpr size_t O_WD1 = O_WD0 + (size_t)2048*512*2;    // 32t x 4c packed
static constexpr size_t O_BL0 = O_WD1 + (size_t)2048*512*2;    // 2048 f32 biases (gate-permuted)
static constexpr size_t O_BL1 = O_BL0 + 8192;
static constexpr size_t O_BD0 = O_BL1 + 8192;
static constexpr size_t O_BD1 = O_BD0 + 8192;
static constexpr size_t O_W0C = O_BD1 + 8192;                  // 2048 f32 dec_Wih0[:,0] permuted
static constexpr size_t O_H0B = O_W0C + 8192;                  // 2 x (256,512) f16 L0 h ping-pong
static constexpr size_t O_H1B = O_H0B + (size_t)2*256*512*2;   // 2 x (256,512) f16 L1 h ping-pong
static constexpr size_t O_HD1 = O_H1B + (size_t)2*256*512*2;   // (256,512) f16 decoder h1
static constexpr size_t O_H0D = O_HD1 + (size_t)256*512*2;     // (256,512) f16 decoder h0
static constexpr size_t O_CTX = O_H0D + (size_t)256*512*2;     // (256,512) f16 context
static constexpr size_t O_C0  = O_CTX + (size_t)256*512*2;     // (256,512) f32 (unused scratch)
static constexpr size_t O_C1  = O_C0  + (size_t)256*512*4;     // (256,512) f32
static constexpr size_t O_INP = O_C1  + (size_t)256*512*4;     // 256 f32
static constexpr size_t O_GAT = O_INP + 1024;                  // (256,4672) f32 gate partials
static constexpr size_t O_EO  = O_GAT + (size_t)256*4672*4;    // (B*T,H) f16 encoder outputs
static constexpr size_t O_EP  = O_EO  + (size_t)256*512*512*2; // (B*T,512) f16 enc_proj
static constexpr size_t WS_NEED = O_EP + (size_t)256*512*512*2;

__device__ __align__(4096) unsigned char g_ws[WS_NEED];
__device__ int g_bar[2048];   // 128B-line-separated barrier state

#define WSH(o) ((half_t*)(g_ws + (o)))
#define WSCH(o) ((const half_t*)(g_ws + (o)))
#define WSF(o) ((float*)(g_ws + (o)))
#define WSCF(o) ((const float*)(g_ws + (o)))
#define BLINE(i) (g_bar + ((size_t)(i) << 5))

__device__ __forceinline__ int gperm(int n) { return (n & 3) * 512 + (n >> 2); }

// ------- per-group barriers: 64 blocks = 2 subgroups of 32 ------------------
// lines: cnt g*2+sub (0..7) | mst 8+g (8..11) | gen 12+g*2+sub (12..19)
// Relaxed: no cache maintenance. Cross-barrier data must be agent-coherent.
__device__ __forceinline__ void gbar_rel(int g, int sub) {
  __syncthreads();   // per-wave vmcnt(0) drain: sc0|sc1 stores are L3-visible
  if (threadIdx.x == 0) {
    int* cnt = BLINE(g * 2 + sub);
    int* mst = BLINE(8 + g);
    int* gs  = BLINE(12 + g * 2 + sub);
    int old = __hip_atomic_load(gs, __ATOMIC_RELAXED, __HIP_MEMORY_SCOPE_AGENT);
    int a = __hip_atomic_fetch_add(cnt, 1, __ATOMIC_RELAXED, __HIP_MEMORY_SCOPE_AGENT);
    if (a == 31) {
      __hip_atomic_store(cnt, 0, __ATOMIC_RELAXED, __HIP_MEMORY_SCOPE_AGENT);
      int m = __hip_atomic_fetch_add(mst, 1, __ATOMIC_RELAXED, __HIP_MEMORY_SCOPE_AGENT);
      if (m == 1) {
        __hip_atomic_store(mst, 0, __ATOMIC_RELAXED, __HIP_MEMORY_SCOPE_AGENT);
        __hip_atomic_fetch_add(BLINE(12 + g * 2), 1, __ATOMIC_RELAXED, __HIP_MEMORY_SCOPE_AGENT);
        __hip_atomic_fetch_add(BLINE(12 + g * 2 + 1), 1, __ATOMIC_RELAXED, __HIP_MEMORY_SCOPE_AGENT);
      }
    }
    while (__hip_atomic_load(gs, __ATOMIC_RELAXED, __HIP_MEMORY_SCOPE_AGENT) == old)
      __builtin_amdgcn_s_sleep(2);
  }
  __syncthreads();
}

// Heavy barrier: full release (L2 writeback) / acquire (L2 inv) — phase edges.
__device__ __forceinline__ void gbar_acq(int g, int sub) {
  __syncthreads();
  if (threadIdx.x == 0) {
    int* cnt = BLINE(g * 2 + sub);
    int* mst = BLINE(8 + g);
    int* gs  = BLINE(12 + g * 2 + sub);
    int old = __hip_atomic_load(gs, __ATOMIC_RELAXED, __HIP_MEMORY_SCOPE_AGENT);
    int a = __hip_atomic_fetch_add(cnt, 1, __ATOMIC_ACQ_REL, __HIP_MEMORY_SCOPE_AGENT);
    if (a == 31) {
      __hip_atomic_store(cnt, 0, __ATOMIC_RELAXED, __HIP_MEMORY_SCOPE_AGENT);
      int m = __hip_atomic_fetch_add(mst, 1, __ATOMIC_ACQ_REL, __HIP_MEMORY_SCOPE_AGENT);
      if (m == 1) {
        __hip_atomic_store(mst, 0, __ATOMIC_RELAXED, __HIP_MEMORY_SCOPE_AGENT);
        __hip_atomic_fetch_add(BLINE(12 + g * 2), 1, __ATOMIC_RELEASE, __HIP_MEMORY_SCOPE_AGENT);
        __hip_atomic_fetch_add(BLINE(12 + g * 2 + 1), 1, __ATOMIC_RELEASE, __HIP_MEMORY_SCOPE_AGENT);
      }
    }
    while (__hip_atomic_load(gs, __ATOMIC_RELAXED, __HIP_MEMORY_SCOPE_AGENT) == old)
      __builtin_amdgcn_s_sleep(2);
    (void)__hip_atomic_load(gs, __ATOMIC_ACQUIRE, __HIP_MEMORY_SCOPE_AGENT);
  }
  __syncthreads();
}

// ---------------- GEMM cores: 64x64 tile, K-split over 8 waves (chunk=128) ---
struct Seg { const half_t* p; int stride; int row0; };

// stage this wave's 64-row x 16-k fragment slice of chunk c into LDS slot dst
template<int AXA, int AXB>
__device__ __forceinline__ void stageA(Seg sa, Seg sb, int cSplit, int c,
                                       int lane, int wid, char* dst) {
  bool isA = c < cSplit;
  Seg s = isA ? sa : sb;
  int kb = (isA ? c : (c - cSplit)) * 128;
  const half_t* g = s.p + (size_t)(s.row0 + (lane & 31)) * s.stride
                        + kb + (wid << 4) + ((lane >> 5) << 3);
  if (isA) {
    __builtin_amdgcn_global_load_lds(
        (const __attribute__((address_space(1))) unsigned int*)g,
        (__attribute__((address_space(3))) unsigned int*)dst, 16, 0, AXA);
    __builtin_amdgcn_global_load_lds(
        (const __attribute__((address_space(1))) unsigned int*)(g + (size_t)32 * s.stride),
        (__attribute__((address_space(3))) unsigned int*)(dst + 1024), 16, 0, AXA);
  } else {
    __builtin_amdgcn_global_load_lds(
        (const __attribute__((address_space(1))) unsigned int*)g,
        (__attribute__((address_space(3))) unsigned int*)dst, 16, 0, AXB);
    __builtin_amdgcn_global_load_lds(
        (const __attribute__((address_space(1))) unsigned int*)(g + (size_t)32 * s.stride),
        (__attribute__((address_space(3))) unsigned int*)(dst + 1024), 16, 0, AXB);
  }
}

// ---- encoder K-body: B in registers, ring-4 staged A ----
template<int C, int NC, int CSPLIT, int AXA, int AXB>
__device__ __forceinline__ void kreg(Seg sa, Seg sb,
                                     const f16x8 (&B0)[8], const f16x8 (&B1)[8],
                                     int lane, int wid, char* asg, f32x16 acc[2][2]) {
  if constexpr (C < NC) {
    constexpr int rem = NC - 1 - C;
    waitvm<2 * (rem < 3 ? rem : 3)>();
    char* ab = asg + (size_t)(((C & 3) * 8 + wid)) * 2048 + lane * 16;
    f16x8 a0 = *(const f16x8*)ab;
    f16x8 a1 = *(const f16x8*)(ab + 1024);
    acc[0][0] = MFMA(a0, B0[C], acc[0][0]);
    acc[0][1] = MFMA(a0, B1[C], acc[0][1]);
    acc[1][0] = MFMA(a1, B0[C], acc[1][0]);
    acc[1][1] = MFMA(a1, B1[C], acc[1][1]);
    if constexpr (C + 4 < NC)
      stageA<AXA, AXB>(sa, sb, CSPLIT, C + 4, lane, wid,
                       asg + (size_t)((((C + 4) & 3) * 8 + wid)) * 2048);
    CBAR();
    kreg<C + 1, NC, CSPLIT, AXA, AXB>(sa, sb, B0, B1, lane, wid, asg, acc);
  }
}

template<int NC, int CSPLIT, int AXA, int AXB>
__device__ __forceinline__ void gemm_regB(Seg sa, Seg sb,
                                          const f16x8 (&B0)[8], const f16x8 (&B1)[8],
                                          int lane, int wid, char* asg, f32x16 acc[2][2]) {
  #pragma unroll
  for (int c = 0; c < (NC < 4 ? NC : 4); c++) {
    stageA<AXA, AXB>(sa, sb, CSPLIT, c, lane, wid, asg + (size_t)((c & 3) * 8 + wid) * 2048);
    CBAR();
  }
  kreg<0, NC, CSPLIT, AXA, AXB>(sa, sb, B0, B1, lane, wid, asg, acc);
}

// ---- streamed-B K-body (NC<=4): all chunks issued upfront ----
template<int C, int NC>
__device__ __forceinline__ void kks(int lane, int wid, char* asg, f32x16 acc[2][2],
                                    f16x8 (&b0)[4], f16x8 (&b1)[4]) {
  if constexpr (C < NC) {
    waitvm<4 * (NC - 1 - C)>();
    char* ab = asg + (size_t)(C * 8 + wid) * 2048 + lane * 16;
    f16x8 a0 = *(const f16x8*)ab;
    f16x8 a1 = *(const f16x8*)(ab + 1024);
    acc[0][0] = MFMA(a0, b0[C], acc[0][0]);
    acc[0][1] = MFMA(a0, b1[C], acc[0][1]);
    acc[1][0] = MFMA(a1, b0[C], acc[1][0]);
    acc[1][1] = MFMA(a1, b1[C], acc[1][1]);
    CBAR();
    kks<C + 1, NC>(lane, wid, asg, acc, b0, b1);
  }
}

template<int NC, int AXA, int AXB>
__device__ __forceinline__ void gemm_ks(Seg sa, Seg sb, int cSplit, const half_t* Wt,
                                        int lane, int wid, char* asg, f32x16 acc[2][2]) {
  const half_t* wb = Wt + (wid << 1) * 512 + lane * 8;
  f16x8 b0[4], b1[4];
  #pragma unroll
  for (int c = 0; c < NC; c++) {
    stageA<AXA, AXB>(sa, sb, cSplit, c, lane, wid, asg + (size_t)(c * 8 + wid) * 2048);
    CBAR();
    b0[c] = *(const f16x8*)(wb + (size_t)c * 8192);
    b1[c] = *(const f16x8*)(wb + (size_t)c * 8192 + 512);
    CBAR();
  }
  kks<0, NC>(lane, wid, asg, acc, b0, b1);
}

// ---------------- K-split reduction: 2 syncthreads, 4 partial buffers --------
__device__ __forceinline__ void acc_wr(float* dst, int lane, f32x16 acc[2][2]) {
  #pragma unroll
  for (int t = 0; t < 4; t++) {
    f32x16 a = acc[t >> 1][t & 1];
    #pragma unroll
    for (int r4 = 0; r4 < 4; r4++)
      *(float4*)(dst + ((t * 4 + r4) * 64 + lane) * 4) =
          make_float4(a[r4*4], a[r4*4+1], a[r4*4+2], a[r4*4+3]);
  }
}
__device__ __forceinline__ void acc_add(const float* src, int lane, f32x16 acc[2][2]) {
  #pragma unroll
  for (int t = 0; t < 4; t++) {
    #pragma unroll
    for (int r4 = 0; r4 < 4; r4++) {
      float4 v = *(const float4*)(src + ((t * 4 + r4) * 64 + lane) * 4);
      acc[t>>1][t&1][r4*4]   += v.x;
      acc[t>>1][t&1][r4*4+1] += v.y;
      acc[t>>1][t&1][r4*4+2] += v.z;
      acc[t>>1][t&1][r4*4+3] += v.w;
    }
  }
}
// waves 4-7 write bufs 0-3; waves 0-3 add own acc and write back. Epilogue
// threads then sum the 4 buffers directly via raddr().
__device__ __forceinline__ void reduce4(f32x16 acc[2][2], float* red, int lane, int wid) {
  if (wid >= 4) acc_wr(red + (size_t)(wid - 4) * 4096, lane, acc);
  __syncthreads();
  if (wid < 4) {
    acc_add(red + (size_t)wid * 4096, lane, acc);
    acc_wr(red + (size_t)wid * 4096, lane, acc);
  }
  __syncthreads();
}
__device__ __forceinline__ int raddr(int row, int col) {
  int ms = row >> 5, rr = row & 31;
  int q = rr & 3, hl = (rr >> 2) & 1, r4 = rr >> 3;
  int ns = col >> 5;
  int lane = (hl << 5) | (col & 31);
  int t = ms * 2 + ns;
  return ((t * 4 + r4) * 64 + lane) * 4 + q;
}
__device__ __forceinline__ float red_sum(const float* red, int row, int col) {
  int i = raddr(row, col);
  return red[i] + red[4096 + i] + red[8192 + i] + red[12288 + i];
}

// ---------------- main persistent kernel (4 independent groups) ----------------
__global__ void __launch_bounds__(512, 2) kmain(const float* __restrict__ attn_v,
                                                const float* __restrict__ out_b,
                                                float* __restrict__ out) {
  __shared__ __align__(16) char asg[65536];  // ring-4: 4 chunk-slots x 8 waves x 2KB
  __shared__ float red[16384];               // 4 x 16KB K-split partial buffers

  const half_t* x16 = WSCH(O_X16);
  const half_t* wL0 = WSCH(O_WL0);
  const half_t* wL1 = WSCH(O_WL1);
  const half_t* wP1 = WSCH(O_WP1);
  const half_t* wD0 = WSCH(O_WD0);
  const half_t* wD1 = WSCH(O_WD1);
  half_t* h0bB = WSH(O_H0B);
  half_t* h1bB = WSH(O_H1B);
  half_t* hd1  = WSH(O_HD1);
  half_t* h0d  = WSH(O_H0D);
  half_t* ctx  = WSH(O_CTX);
  half_t* eo   = WSH(O_EO);
  half_t* ep   = WSH(O_EP);
  float* c1 = WSF(O_C1);
  float* inp = WSF(O_INP);
  float* gates = WSF(O_GAT);

  const int tid = threadIdx.x;
  const int wid = tid >> 6;
  const int lane = tid & 63;
  const int g = blockIdx.x & 3;        // batch-slice group
  const int r = blockIdx.x >> 2;       // rank within group, 0..63
  const int sub = r & 1;
  const int m0 = g << 6;               // group's batch-row base
  const f32x16 zv = {0,0,0,0,0,0,0,0,0,0,0,0,0,0,0,0};

  // ================= encoder: 513 wavefront-pipelined steps =================
  {
    const bool isL1 = r >= 32;
    const int n0 = (r & 31) << 6;

    // B-weights in VGPRs for all 513 steps (read-only, plain cached loads)
    const half_t* wbase = isL1 ? (wL1 + (size_t)(n0 >> 6) * (8 * 8192))
                               : (wL0 + (size_t)(n0 >> 6) * (5 * 8192));
    const half_t* wb = wbase + (wid << 1) * 512 + lane * 8;
    const int ncB = isL1 ? 8 : 5;
    f16x8 B0[8], B1[8];
    #pragma unroll
    for (int c = 0; c < 8; c++) {
      if (c < ncB) {
        B0[c] = *(const f16x8*)(wb + (size_t)c * 8192);
        B1[c] = *(const f16x8*)(wb + (size_t)c * 8192 + 512);
      }
    }
    // bias quad + c-state in registers for the whole encoder
    const int eu = tid & 15;            // unit-quad index (same for both its)
    const int ebl = tid >> 4;           // batch row (it=0); it=1 adds 32
    const float* bias = isL1 ? WSCF(O_BL1) : WSCF(O_BL0);
    float4 breg = *(const float4*)&bias[n0 + eu * 4];
    float creg0 = 0.f, creg1 = 0.f;

    for (int s = 0; s <= 512; s++) {
      const bool active = isL1 ? (s > 0) : (s < 512);
      if (active) {
        const half_t* h0r = h0bB + (size_t)((s + 1) & 1) * (256 * 512);
        f32x16 acc[2][2] = {{zv, zv}, {zv, zv}};
        int t;
        if (!isL1) {
          t = s;
          gemm_regB<5, 1, 0, AUXC>(Seg{x16, 128, t * 256 + m0}, Seg{h0r, 512, m0},
                                   B0, B1, lane, wid, asg, acc);
        } else {
          t = s - 1;
          const half_t* h1r = h1bB + (size_t)(s & 1) * (256 * 512);
          gemm_regB<8, 4, AUXC, AUXC>(Seg{h0r, 512, m0}, Seg{h1r, 512, m0},
                                      B0, B1, lane, wid, asg, acc);
        }
        reduce4(acc, red, lane, wid);
        half_t* hb = isL1 ? (h1bB + (size_t)((s - 1) & 1) * (256 * 512))
                          : (h0bB + (size_t)(s & 1) * (256 * 512));
        #pragma unroll
        for (int it = 0; it < 2; it++) {
          int bl = ebl + it * 32;
          float gi = red_sum(red, bl, eu * 4 + 0) + breg.x;
          float gf = red_sum(red, bl, eu * 4 + 1) + breg.y;
          float gz = red_sum(red, bl, eu * 4 + 2) + breg.z;
          float go = red_sum(red, bl, eu * 4 + 3) + breg.w;
          float cold = it ? creg1 : creg0;
          float cn = fsig(gf) * cold + fsig(gi) * ftanh(gz);
          float hn = fsig(go) * ftanh(cn);
          if (it) creg1 = cn; else creg0 = cn;
          int bg = m0 + bl, ug = (n0 >> 2) + eu;
          stha(&hb[bg * 512 + ug], hn);                       // coherent publish
          if (isL1) eo[((size_t)bg * 512 + t) * 512 + ug] = (half_t)hn;  // plain
        }
      }
      gbar_rel(g, sub);
    }

    // flush c-state (plain; covered by heavy barrier below)
    if (isL1) {
      int ug = (n0 >> 2) + eu;
      c1[(m0 + ebl) * 512 + ug] = creg0;
      c1[(m0 + ebl + 32) * 512 + ug] = creg1;
    }
  }
  gbar_acq(g, sub);   // phase edge: flush eo + c1, invalidate stale L2

  // ====== enc_proj = enc_out @ attn_W^T (f16), group-local rows ======
  for (int j = 0; j < 64; j++) {
    const int jj = r * 64 + j;
    const int ml = jj >> 3;
    const int nt = jj & 7;
    const int row0 = (g << 15) + ml * 64;
    f32x16 acc[2][2] = {{zv, zv}, {zv, zv}};
    gemm_ks<4, 0, 0>(Seg{eo, 512, row0}, Seg{eo, 512, row0}, 4,
                     wP1 + (size_t)nt * (4 * 8192), lane, wid, asg, acc);
    reduce4(acc, red, lane, wid);
    {
      int row = tid >> 3, col = (tid & 7) * 8;
      f16x8 h8;
      #pragma unroll
      for (int q = 0; q < 8; q++) h8[q] = (half_t)red_sum(red, row, col + q);
      *(f16x8*)&ep[(size_t)(row0 + row) * 512 + nt * 64 + col] = h8;  // plain
    }
    __syncthreads();
  }
  gbar_acq(g, sub);   // phase edge: flush ep

  // ================= decoder: 30 steps (d=30 = final output-only pass) ======
  for (int d = 0; d <= 30; d++) {
    // ---- P1: h1 @ [attn_W | dWhh0 | dWhh1 | out_W]  (73 n-tiles / group) ----
    const half_t* hs = (d == 0) ? (h1bB + 256 * 512) : hd1;
    for (int jj = r; jj < 73; jj += 64) {
      const int n0p = jj * 64;
      f32x16 acc[2][2] = {{zv, zv}, {zv, zv}};
      gemm_ks<4, AUXC, AUXC>(Seg{hs, 512, m0}, Seg{hs, 512, m0}, 4,
                             wP1 + (size_t)jj * (4 * 8192), lane, wid, asg, acc);
      reduce4(acc, red, lane, wid);
      if (n0p < 4608) {
        #pragma unroll
        for (int it = 0; it < 2; it++) {
          int q = it * 512 + tid;
          int row = q >> 4, col = (q & 15) * 4;
          float v0 = red_sum(red, row, col + 0);
          float v1 = red_sum(red, row, col + 1);
          float v2 = red_sum(red, row, col + 2);
          float v3 = red_sum(red, row, col + 3);
          float* dst = &gates[(size_t)(m0 + row) * 4672 + n0p + col];
          st64(dst, v0, v1);
          st64(dst + 2, v2, v3);
        }
      } else if (d > 0) {
        if (tid < 64) {
          int bg = m0 + tid;
          float v0 = red_sum(red, tid, 0) + out_b[0];
          float v1 = red_sum(red, tid, 1) + out_b[1];
          float v2 = red_sum(red, tid, 2) + out_b[2];
          out[(size_t)bg * 90 + (d - 1) * 3 + 0] = v0;
          out[(size_t)bg * 90 + (d - 1) * 3 + 1] = v1;
          out[(size_t)bg * 90 + (d - 1) * 3 + 2] = v2;
          stfa(&inp[bg], v1);
        }
      }
      __syncthreads();
    }
    gbar_rel(g, sub);
    if (d == 30) break;

    // ---- P2: attention for batch row b = m0 + r ----
    {
      const int b = m0 + r;
      float* dpb = red;          // 512
      float* vb  = red + 512;    // 512
      float* eb  = red + 1024;   // 512
      float* ab2 = red + 2048;   // 512
      float* sc  = red + 2560;   // 16
      float* pm  = red + 4096;   // 8x512 ctx partials
      dpb[tid] = ldfa(&gates[(size_t)b * 4672 + tid]);
      vb[tid]  = attn_v[tid];
      __syncthreads();
      const half_t* eprow = ep + ((size_t)b << 18) + (size_t)(wid * 64) * 512 + lane * 8;
      for (int tt = 0; tt < 64; tt++) {
        f16x8 e8 = *(const f16x8*)(eprow + (size_t)tt * 512);   // plain (stable)
        float sum = 0.f;
        #pragma unroll
        for (int jq = 0; jq < 8; jq++)
          sum += vb[lane * 8 + jq] * ftanh((float)e8[jq] + dpb[lane * 8 + jq]);
        #pragma unroll
        for (int off = 32; off > 0; off >>= 1) sum += __shfl_down(sum, off, 64);
        if (lane == 0) eb[wid * 64 + tt] = sum;
      }
      __syncthreads();
      float e0 = eb[tid];
      float mx = e0;
      #pragma unroll
      for (int off = 32; off > 0; off >>= 1) mx = fmaxf(mx, __shfl_xor(mx, off, 64));
      if (lane == 0) sc[wid] = mx;
      __syncthreads();
      mx = sc[0];
      #pragma unroll
      for (int q = 1; q < 8; q++) mx = fmaxf(mx, sc[q]);
      float x0 = __expf(e0 - mx);
      float ssum = x0;
      #pragma unroll
      for (int off = 32; off > 0; off >>= 1) ssum += __shfl_xor(ssum, off, 64);
      __syncthreads();
      if (lane == 0) sc[8 + wid] = ssum;
      __syncthreads();
      float tot = sc[8];
      #pragma unroll
      for (int q = 1; q < 8; q++) tot += sc[8 + q];
      float inv = 1.f / tot;
      ab2[tid] = x0 * inv;
      __syncthreads();
      float pacc[8] = {0,0,0,0,0,0,0,0};
      const half_t* eow = eo + ((size_t)b << 18) + (size_t)(wid * 64) * 512 + lane * 8;
      for (int tt = 0; tt < 64; tt++) {
        f16x8 h8 = *(const f16x8*)(eow + (size_t)tt * 512);     // plain (stable)
        float at = ab2[wid * 64 + tt];
        #pragma unroll
        for (int jq = 0; jq < 8; jq++) pacc[jq] += at * (float)h8[jq];
      }
      #pragma unroll
      for (int jq = 0; jq < 8; jq++) pm[wid * 512 + lane * 8 + jq] = pacc[jq];
      __syncthreads();
      float sctx = 0.f;
      #pragma unroll
      for (int w = 0; w < 8; w++) sctx += pm[w * 512 + tid];
      stha(&ctx[(b << 9) + tid], sctx);                          // coherent
    }
    gbar_rel(g, sub);

    // ---- P3: gates0 = ctx @ dWih0[:,1:] + inp*w0col + partial + bias -> h0d ----
    if (r < 32) {
      const int n0 = r << 6;
      f32x16 acc[2][2] = {{zv, zv}, {zv, zv}};
      gemm_ks<4, AUXC, AUXC>(Seg{ctx, 512, m0}, Seg{ctx, 512, m0}, 4,
                             wD0 + (size_t)(n0 >> 6) * (4 * 8192), lane, wid, asg, acc);
      reduce4(acc, red, lane, wid);
      const float* bD0 = WSCF(O_BD0);
      const float* w0c = WSCF(O_W0C);
      #pragma unroll
      for (int it = 0; it < 2; it++) {
        int q = it * 512 + tid;
        int u = q & 15, bl = q >> 4;
        int bg = m0 + bl, ug = (n0 >> 2) + u, nl = n0 + u * 4;
        float p0, p1, p2, p3;
        ld64(&gates[(size_t)bg * 4672 + 512 + nl], p0, p1);
        ld64(&gates[(size_t)bg * 4672 + 512 + nl + 2], p2, p3);
        float4 b4 = *(const float4*)&bD0[nl];
        float4 w4 = *(const float4*)&w0c[nl];
        float iv = ldfa(&inp[bg]);
        float gi = red_sum(red, bl, u*4+0) + p0 + b4.x + iv * w4.x;
        float gf = red_sum(red, bl, u*4+1) + p1 + b4.y + iv * w4.y;
        float gz = red_sum(red, bl, u*4+2) + p2 + b4.z + iv * w4.z;
        float go = red_sum(red, bl, u*4+3) + p3 + b4.w + iv * w4.w;
        float cold = c1[bg * 512 + ug];
        float cn = fsig(gf) * cold + fsig(gi) * ftanh(gz);
        stha(&h0d[bg * 512 + ug], fsig(go) * ftanh(cn));        // coherent
      }
    }
    gbar_rel(g, sub);

    // ---- P4: gates1 = h0d @ dWih1 + partial + bias -> c1, hd1 ----
    if (r < 32) {
      const int n0 = r << 6;
      f32x16 acc[2][2] = {{zv, zv}, {zv, zv}};
      gemm_ks<4, AUXC, AUXC>(Seg{h0d, 512, m0}, Seg{h0d, 512, m0}, 4,
                             wD1 + (size_t)(n0 >> 6) * (4 * 8192), lane, wid, asg, acc);
      reduce4(acc, red, lane, wid);
      const float* bD1 = WSCF(O_BD1);
      #pragma unroll
      for (int it = 0; it < 2; it++) {
        int q = it * 512 + tid;
        int u = q & 15, bl = q >> 4;
        int bg = m0 + bl, ug = (n0 >> 2) + u, nl = n0 + u * 4;
        float p0, p1, p2, p3;
        ld64(&gates[(size_t)bg * 4672 + 2560 + nl], p0, p1);
        ld64(&gates[(size_t)bg * 4672 + 2560 + nl + 2], p2, p3);
        float4 b4 = *(const float4*)&bD1[nl];
        float gi = red_sum(red, bl, u*4+0) + p0 + b4.x;
        float gf = red_sum(red, bl, u*4+1) + p1 + b4.y;
        float gz = red_sum(red, bl, u*4+2) + p2 + b4.z;
        float go = red_sum(red, bl, u*4+3) + p3 + b4.w;
        float cold = c1[bg * 512 + ug];
        float cn = fsig(gf) * cold + fsig(gi) * ftanh(gz);
        float hn = fsig(go) * ftanh(cn);
        c1[bg * 512 + ug] = cn;                                  // self-read only
        stha(&hd1[bg * 512 + ug], hn);                           // coherent
      }
    }
    gbar_rel(g, sub);
  }
}

// ---------------- prep kernels ----------------
// packed-B layout (halves): e = (((tile*NC + c)*8 + w)*2 + bh)*512 + l*8 + j
// -> n = tile*64 + bh*32 + (l&31), k = c*128 + w*16 + (l>>5)*8 + j
__global__ void kpackB(size_t dstOff, int id, int Ntiles, int NC,
                       const float* s0, const float* s1,
                       const float* s2, const float* s3) {
  half_t* dst = (half_t*)(g_ws + dstOff);
  size_t total = (size_t)Ntiles * NC * 8192;
  size_t i = (size_t)blockIdx.x * 256 + threadIdx.x;
  size_t stride = (size_t)gridDim.x * 256;
  for (size_t e = i; e < total; e += stride) {
    int j = e & 7;
    int l = (e >> 3) & 63;
    int bh = (e >> 9) & 1;
    int w = (e >> 10) & 7;
    int tc = (int)(e >> 13);
    int c = tc % NC;
    int tile = tc / NC;
    int n = tile * 64 + bh * 32 + (l & 31);
    int k = c * 128 + w * 16 + ((l >> 5) << 3) + j;
    float v = 0.f;
    if (id == 0) {          // wL0: [Wih0(64) | pad(64) | Whh0(512)]
      int pn = gperm(n);
      if (k < 64) v = s0[(size_t)pn * 64 + k];
      else if (k >= 128) v = s1[(size_t)pn * 512 + (k - 128)];
    } else if (id == 1) {   // wL1: [Wih1(512) | Whh1(512)]
      int pn = gperm(n);
      v = (k < 512) ? s0[(size_t)pn * 512 + k] : s1[(size_t)pn * 512 + (k - 512)];
    } else if (id == 2) {   // wP1: [attnW | dWhh0 | dWhh1 | outW | pad]
      if (n < 512) v = s0[((size_t)n << 9) + k];
      else if (n < 2560) v = s1[((size_t)gperm(n - 512) << 9) + k];
      else if (n < 4608) v = s2[((size_t)gperm(n - 2560) << 9) + k];
      else if (n < 4611) v = s3[((size_t)(n - 4608) << 9) + k];
    } else if (id == 3) {   // wD0: dec_Wih0[:,1:]
      v = s0[(size_t)gperm(n) * 513 + 1 + k];
    } else {                // wD1
      v = s0[((size_t)gperm(n) << 9) + k];
    }
    dst[e] = (half_t)v;
  }
}

__global__ void kmisc(const float* ebih0, const float* ebhh0, const float* ebih1, const float* ebhh1,
                      const float* dbih0, const float* dbhh0, const float* dbih1, const float* dbhh1,
                      const float* dWih0, const float* x) {
  float* bL0 = WSF(O_BL0);
  float* bL1 = WSF(O_BL1);
  float* bD0 = WSF(O_BD0);
  float* bD1 = WSF(O_BD1);
  float* w0c = WSF(O_W0C);
  half_t* h0b = WSH(O_H0B);
  half_t* h1b = WSH(O_H1B);
  float* c1 = WSF(O_C1);
  float* inp = WSF(O_INP);
  int i = blockIdx.x * 256 + threadIdx.x, stride = gridDim.x * 256;
  for (int idx = i; idx < 262144; idx += stride) {
    if (idx < 2048) {
      int pn = gperm(idx);
      bL0[idx] = ebih0[pn] + ebhh0[pn];
      bL1[idx] = ebih1[pn] + ebhh1[pn];
      bD0[idx] = dbih0[pn] + dbhh0[pn];
      bD1[idx] = dbih1[pn] + dbhh1[pn];
      w0c[idx] = dWih0[(size_t)pn * 513];
      g_bar[idx] = 0;
    }
    if (idx < 256) inp[idx] = x[((size_t)idx * 512 + 511) * 64];
    h0b[idx] = (half_t)0.f;
    h1b[idx] = (half_t)0.f;
    if (idx < 131072) c1[idx] = 0.f;
  }
}

__global__ void kx16(const float* x) {
  half_t* dst = WSH(O_X16);   // (t, b, 128) zero-padded cols 64..127
  size_t i = (size_t)blockIdx.x * 256 + threadIdx.x;
  size_t stride = (size_t)gridDim.x * 256;
  for (size_t e = i; e < (size_t)512 * 256 * 128; e += stride) {
    int t = (int)(e >> 15);
    int b = (int)((e >> 7) & 255);
    int ii = (int)(e & 127);
    dst[e] = (ii < 64) ? (half_t)x[((size_t)b * 512 + t) * 64 + ii] : (half_t)0.f;
  }
}

// ---------------- launch ----------------
extern "C" void kernel_launch(void* const* d_in, const int* in_sizes, int n_in,
                              void* d_out, int out_size, void* d_ws, size_t ws_size,
                              hipStream_t stream) {
  const float* x     = (const float*)d_in[0];
  const float* eWih0 = (const float*)d_in[1];
  const float* eWhh0 = (const float*)d_in[2];
  const float* ebih0 = (const float*)d_in[3];
  const float* ebhh0 = (const float*)d_in[4];
  const float* eWih1 = (const float*)d_in[5];
  const float* eWhh1 = (const float*)d_in[6];
  const float* ebih1 = (const float*)d_in[7];
  const float* ebhh1 = (const float*)d_in[8];
  const float* dWih0 = (const float*)d_in[9];
  const float* dWhh0 = (const float*)d_in[10];
  const float* dbih0 = (const float*)d_in[11];
  const float* dbhh0 = (const float*)d_in[12];
  const float* dWih1 = (const float*)d_in[13];
  const float* dWhh1 = (const float*)d_in[14];
  const float* dbih1 = (const float*)d_in[15];
  const float* dbhh1 = (const float*)d_in[16];
  const float* attnW = (const float*)d_in[17];
  const float* attnv = (const float*)d_in[18];
  const float* outW  = (const float*)d_in[19];
  const float* outb  = (const float*)d_in[20];
  (void)in_sizes; (void)n_in; (void)out_size; (void)d_ws; (void)ws_size;

  kpackB<<<1024, 256, 0, stream>>>(O_WL0, 0, 32, 5, eWih0, eWhh0, nullptr, nullptr);
  kpackB<<<1024, 256, 0, stream>>>(O_WL1, 1, 32, 8, eWih1, eWhh1, nullptr, nullptr);
  kpackB<<<1024, 256, 0, stream>>>(O_WP1, 2, 73, 4, attnW, dWhh0, dWhh1, outW);
  kpackB<<<1024, 256, 0, stream>>>(O_WD0, 3, 32, 4, dWih0, nullptr, nullptr, nullptr);
  kpackB<<<1024, 256, 0, stream>>>(O_WD1, 4, 32, 4, dWih1, nullptr, nullptr, nullptr);
  kmisc<<<1024, 256, 0, stream>>>(ebih0, ebhh0, ebih1, ebhh1,
                                  dbih0, dbhh0, dbih1, dbhh1, dWih0, x);
  kx16<<<2048, 256, 0, stream>>>(x);

  float* outp = (float*)d_out;
  void* args[] = {(void*)&attnv, (void*)&outb, (void*)&outp};
  hipError_t e = hipLaunchCooperativeKernel((void*)kmain, dim3(256), dim3(512),
                                            args, 0, stream);
  if (e != hipSuccess) {
    kmain<<<dim3(256), dim3(512), 0, stream>>>(attnv, outb, outp);
  }
}

// Round 7
// 8494.956 us; speedup vs baseline: 2.3250x; 1.0012x over previous
//
#include <hip/hip_runtime.h>

// ---------------------------------------------------------------------------
// Seq2Seq LSTM + attention, persistent kernel for MI355X (gfx950)
// B=256, T=512, I=64, H=512, HORIZON=30, NQ=3
// R7: conflict-free 3-sync K-split reduction (zoned row*64+col half-sums,
// float4 epilogues); zero-contention flag-vote group barrier (per-block flag
// store + wave-0 ballot poll); P2 LDS reads hoisted to registers.
// Carried from R6: relaxed data-coherence scheme (sc0|sc1 stores + aux=0x11
// loads), L2-resident weights, c-state/bias in VGPRs, ring-4 K-loop.
// ---------------------------------------------------------------------------

typedef _Float16 half_t;
typedef __attribute__((ext_vector_type(8)))  _Float16 f16x8;
typedef __attribute__((ext_vector_type(16))) float    f32x16;

#define MFMA(a,b,c) __builtin_amdgcn_mfma_f32_32x32x16_f16((a),(b),(c),0,0,0)
#define CBAR()      asm volatile("" ::: "memory")
#define AUXC 17   // CPol SC0|SC1: agent-coherent (bypass stale L1/L2)

template<int N> __device__ __forceinline__ void waitvm() {
  asm volatile("s_waitcnt vmcnt(%0)" :: "n"(N) : "memory");
}

__device__ __forceinline__ float fsig(float x)  { return 1.0f / (1.0f + __expf(-x)); }
__device__ __forceinline__ float ftanh(float x) { return 1.0f - 2.0f / (1.0f + __expf(2.0f * x)); }

// ---------------- coherent scalar ops (agent scope, relaxed) ----------------
union FU { float f; unsigned u; };
union HU { _Float16 h; unsigned short u; };
__device__ __forceinline__ float ldfa(const float* p) {
  unsigned v = __hip_atomic_load((const unsigned*)p, __ATOMIC_RELAXED, __HIP_MEMORY_SCOPE_AGENT);
  FU c; c.u = v; return c.f;
}
__device__ __forceinline__ void stfa(float* p, float v) {
  FU c; c.f = v;
  __hip_atomic_store((unsigned*)p, c.u, __ATOMIC_RELAXED, __HIP_MEMORY_SCOPE_AGENT);
}
__device__ __forceinline__ void stha(half_t* p, float v) {
  HU c; c.h = (half_t)v;
  __hip_atomic_store((unsigned short*)p, c.u, __ATOMIC_RELAXED, __HIP_MEMORY_SCOPE_AGENT);
}
__device__ __forceinline__ void st64(float* p, float a, float b) {
  FU x, y; x.f = a; y.f = b;
  unsigned long long v = (unsigned long long)x.u | ((unsigned long long)y.u << 32);
  __hip_atomic_store((unsigned long long*)p, v, __ATOMIC_RELAXED, __HIP_MEMORY_SCOPE_AGENT);
}
__device__ __forceinline__ void ld64(const float* p, float& a, float& b) {
  unsigned long long v = __hip_atomic_load((const unsigned long long*)p, __ATOMIC_RELAXED, __HIP_MEMORY_SCOPE_AGENT);
  FU x, y; x.u = (unsigned)v; y.u = (unsigned)(v >> 32); a = x.f; b = y.f;
}

// ---------------- workspace layout (bytes, inside g_ws) ----------------
static constexpr size_t O_X16 = 0;                             // (T,B,128) f16 x zero-padded
static constexpr size_t O_WL0 = O_X16 + (size_t)512*256*128*2; // 32t x 5c packed  (2048x640)
static constexpr size_t O_WL1 = O_WL0 + (size_t)2048*640*2;    // 32t x 8c packed  (2048x1024)
static constexpr size_t O_WP1 = O_WL1 + (size_t)2048*1024*2;   // 73t x 4c packed  (4672x512)
static constexpr size_t O_WD0 = O_WP1 + (size_t)4672*512*2;    // 32t x 4c packed
static constexpr size_t O_WD1 = O_WD0 + (size_t)2048*512*2;    // 32t x 4c packed
static constexpr size_t O_BL0 = O_WD1 + (size_t)2048*512*2;    // 2048 f32 biases (gate-permuted)
static constexpr size_t O_BL1 = O_BL0 + 8192;
static constexpr size_t O_BD0 = O_BL1 + 8192;
static constexpr size_t O_BD1 = O_BD0 + 8192;
static constexpr size_t O_W0C = O_BD1 + 8192;                  // 2048 f32 dec_Wih0[:,0] permuted
static constexpr size_t O_H0B = O_W0C + 8192;                  // 2 x (256,512) f16 L0 h ping-pong
static constexpr size_t O_H1B = O_H0B + (size_t)2*256*512*2;   // 2 x (256,512) f16 L1 h ping-pong
static constexpr size_t O_HD1 = O_H1B + (size_t)2*256*512*2;   // (256,512) f16 decoder h1
static constexpr size_t O_H0D = O_HD1 + (size_t)256*512*2;     // (256,512) f16 decoder h0
static constexpr size_t O_CTX = O_H0D + (size_t)256*512*2;     // (256,512) f16 context
static constexpr size_t O_C0  = O_CTX + (size_t)256*512*2;     // (256,512) f32 (unused scratch)
static constexpr size_t O_C1  = O_C0  + (size_t)256*512*4;     // (256,512) f32
static constexpr size_t O_INP = O_C1  + (size_t)256*512*4;     // 256 f32
static constexpr size_t O_GAT = O_INP + 1024;                  // (256,4672) f32 gate partials
static constexpr size_t O_EO  = O_GAT + (size_t)256*4672*4;    // (B*T,H) f16 encoder outputs
static constexpr size_t O_EP  = O_EO  + (size_t)256*512*512*2; // (B*T,512) f16 enc_proj
static constexpr size_t WS_NEED = O_EP + (size_t)256*512*512*2;

__device__ __align__(4096) unsigned char g_ws[WS_NEED];
__device__ int g_bar[2048];    // acq/rel barrier lines (phase edges)
__device__ int g_flags[1024];  // 4 groups x 64 block flags

#define WSH(o) ((half_t*)(g_ws + (o)))
#define WSCH(o) ((const half_t*)(g_ws + (o)))
#define WSF(o) ((float*)(g_ws + (o)))
#define WSCF(o) ((const float*)(g_ws + (o)))
#define BLINE(i) (g_bar + ((size_t)(i) << 5))

__device__ __forceinline__ int gperm(int n) { return (n & 3) * 512 + (n >> 2); }

// ------- flag-vote group barrier: zero-contention arrive, ballot poll -------
// Block (g,r) stores flags[g*64+r]=step; wave 0 polls all 64 flags until all
// >= step. No RMWs, no master chain. Data coherence is carried by the sc0|sc1
// stores (drained at the syncthreads' vmcnt(0)) + AUXC loads, not the barrier.
__device__ __forceinline__ void gbarf(int g, int r, int step) {
  __syncthreads();   // drains vmcnt(0): all coherent stores are L3-visible
  if (threadIdx.x < 64) {
    if (threadIdx.x == 0)
      __hip_atomic_store(&g_flags[(g << 6) + r], step,
                         __ATOMIC_RELAXED, __HIP_MEMORY_SCOPE_AGENT);
    const int* fp = &g_flags[(g << 6) + threadIdx.x];
    for (;;) {
      int v = __hip_atomic_load(fp, __ATOMIC_RELAXED, __HIP_MEMORY_SCOPE_AGENT);
      if (__all(v >= step)) break;
      __builtin_amdgcn_s_sleep(1);
    }
  }
  __syncthreads();
}

// Heavy barrier: full release (L2 writeback) / acquire (L2 inv) — phase edges.
__device__ __forceinline__ void gbar_acq(int g, int sub) {
  __syncthreads();
  if (threadIdx.x == 0) {
    int* cnt = BLINE(g * 2 + sub);
    int* mst = BLINE(8 + g);
    int* gs  = BLINE(12 + g * 2 + sub);
    int old = __hip_atomic_load(gs, __ATOMIC_RELAXED, __HIP_MEMORY_SCOPE_AGENT);
    int a = __hip_atomic_fetch_add(cnt, 1, __ATOMIC_ACQ_REL, __HIP_MEMORY_SCOPE_AGENT);
    if (a == 31) {
      __hip_atomic_store(cnt, 0, __ATOMIC_RELAXED, __HIP_MEMORY_SCOPE_AGENT);
      int m = __hip_atomic_fetch_add(mst, 1, __ATOMIC_ACQ_REL, __HIP_MEMORY_SCOPE_AGENT);
      if (m == 1) {
        __hip_atomic_store(mst, 0, __ATOMIC_RELAXED, __HIP_MEMORY_SCOPE_AGENT);
        __hip_atomic_fetch_add(BLINE(12 + g * 2), 1, __ATOMIC_RELEASE, __HIP_MEMORY_SCOPE_AGENT);
        __hip_atomic_fetch_add(BLINE(12 + g * 2 + 1), 1, __ATOMIC_RELEASE, __HIP_MEMORY_SCOPE_AGENT);
      }
    }
    while (__hip_atomic_load(gs, __ATOMIC_RELAXED, __HIP_MEMORY_SCOPE_AGENT) == old)
      __builtin_amdgcn_s_sleep(2);
    (void)__hip_atomic_load(gs, __ATOMIC_ACQUIRE, __HIP_MEMORY_SCOPE_AGENT);
  }
  __syncthreads();
}

// ---------------- GEMM cores: 64x64 tile, K-split over 8 waves (chunk=128) ---
struct Seg { const half_t* p; int stride; int row0; };

template<int AXA, int AXB>
__device__ __forceinline__ void stageA(Seg sa, Seg sb, int cSplit, int c,
                                       int lane, int wid, char* dst) {
  bool isA = c < cSplit;
  Seg s = isA ? sa : sb;
  int kb = (isA ? c : (c - cSplit)) * 128;
  const half_t* g = s.p + (size_t)(s.row0 + (lane & 31)) * s.stride
                        + kb + (wid << 4) + ((lane >> 5) << 3);
  if (isA) {
    __builtin_amdgcn_global_load_lds(
        (const __attribute__((address_space(1))) unsigned int*)g,
        (__attribute__((address_space(3))) unsigned int*)dst, 16, 0, AXA);
    __builtin_amdgcn_global_load_lds(
        (const __attribute__((address_space(1))) unsigned int*)(g + (size_t)32 * s.stride),
        (__attribute__((address_space(3))) unsigned int*)(dst + 1024), 16, 0, AXA);
  } else {
    __builtin_amdgcn_global_load_lds(
        (const __attribute__((address_space(1))) unsigned int*)g,
        (__attribute__((address_space(3))) unsigned int*)dst, 16, 0, AXB);
    __builtin_amdgcn_global_load_lds(
        (const __attribute__((address_space(1))) unsigned int*)(g + (size_t)32 * s.stride),
        (__attribute__((address_space(3))) unsigned int*)(dst + 1024), 16, 0, AXB);
  }
}

// ---- encoder K-body: B in registers, ring-4 staged A ----
template<int C, int NC, int CSPLIT, int AXA, int AXB>
__device__ __forceinline__ void kreg(Seg sa, Seg sb,
                                     const f16x8 (&B0)[8], const f16x8 (&B1)[8],
                                     int lane, int wid, char* asg, f32x16 acc[2][2]) {
  if constexpr (C < NC) {
    constexpr int rem = NC - 1 - C;
    waitvm<2 * (rem < 3 ? rem : 3)>();
    char* ab = asg + (size_t)(((C & 3) * 8 + wid)) * 2048 + lane * 16;
    f16x8 a0 = *(const f16x8*)ab;
    f16x8 a1 = *(const f16x8*)(ab + 1024);
    acc[0][0] = MFMA(a0, B0[C], acc[0][0]);
    acc[0][1] = MFMA(a0, B1[C], acc[0][1]);
    acc[1][0] = MFMA(a1, B0[C], acc[1][0]);
    acc[1][1] = MFMA(a1, B1[C], acc[1][1]);
    if constexpr (C + 4 < NC)
      stageA<AXA, AXB>(sa, sb, CSPLIT, C + 4, lane, wid,
                       asg + (size_t)((((C + 4) & 3) * 8 + wid)) * 2048);
    CBAR();
    kreg<C + 1, NC, CSPLIT, AXA, AXB>(sa, sb, B0, B1, lane, wid, asg, acc);
  }
}

template<int NC, int CSPLIT, int AXA, int AXB>
__device__ __forceinline__ void gemm_regB(Seg sa, Seg sb,
                                          const f16x8 (&B0)[8], const f16x8 (&B1)[8],
                                          int lane, int wid, char* asg, f32x16 acc[2][2]) {
  #pragma unroll
  for (int c = 0; c < (NC < 4 ? NC : 4); c++) {
    stageA<AXA, AXB>(sa, sb, CSPLIT, c, lane, wid, asg + (size_t)((c & 3) * 8 + wid) * 2048);
    CBAR();
  }
  kreg<0, NC, CSPLIT, AXA, AXB>(sa, sb, B0, B1, lane, wid, asg, acc);
}

// ---- streamed-B K-body (NC<=4): all chunks issued upfront ----
template<int C, int NC>
__device__ __forceinline__ void kks(int lane, int wid, char* asg, f32x16 acc[2][2],
                                    f16x8 (&b0)[4], f16x8 (&b1)[4]) {
  if constexpr (C < NC) {
    waitvm<4 * (NC - 1 - C)>();
    char* ab = asg + (size_t)(C * 8 + wid) * 2048 + lane * 16;
    f16x8 a0 = *(const f16x8*)ab;
    f16x8 a1 = *(const f16x8*)(ab + 1024);
    acc[0][0] = MFMA(a0, b0[C], acc[0][0]);
    acc[0][1] = MFMA(a0, b1[C], acc[0][1]);
    acc[1][0] = MFMA(a1, b0[C], acc[1][0]);
    acc[1][1] = MFMA(a1, b1[C], acc[1][1]);
    CBAR();
    kks<C + 1, NC>(lane, wid, asg, acc, b0, b1);
  }
}

template<int NC, int AXA, int AXB>
__device__ __forceinline__ void gemm_ks(Seg sa, Seg sb, int cSplit, const half_t* Wt,
                                        int lane, int wid, char* asg, f32x16 acc[2][2]) {
  const half_t* wb = Wt + (wid << 1) * 512 + lane * 8;
  f16x8 b0[4], b1[4];
  #pragma unroll
  for (int c = 0; c < NC; c++) {
    stageA<AXA, AXB>(sa, sb, cSplit, c, lane, wid, asg + (size_t)(c * 8 + wid) * 2048);
    CBAR();
    b0[c] = *(const f16x8*)(wb + (size_t)c * 8192);
    b1[c] = *(const f16x8*)(wb + (size_t)c * 8192 + 512);
    CBAR();
  }
  kks<0, NC>(lane, wid, asg, acc, b0, b1);
}

// ---------------- K-split reduction: 3 syncs, conflict-free ------------------
__device__ __forceinline__ void acc_wr(float* dst, int lane, f32x16 acc[2][2]) {
  #pragma unroll
  for (int t = 0; t < 4; t++) {
    f32x16 a = acc[t >> 1][t & 1];
    #pragma unroll
    for (int r4 = 0; r4 < 4; r4++)
      *(float4*)(dst + ((t * 4 + r4) * 64 + lane) * 4) =
          make_float4(a[r4*4], a[r4*4+1], a[r4*4+2], a[r4*4+3]);
  }
}
__device__ __forceinline__ void acc_add(const float* src, int lane, f32x16 acc[2][2]) {
  #pragma unroll
  for (int t = 0; t < 4; t++) {
    #pragma unroll
    for (int r4 = 0; r4 < 4; r4++) {
      float4 v = *(const float4*)(src + ((t * 4 + r4) * 64 + lane) * 4);
      acc[t>>1][t&1][r4*4]   += v.x;
      acc[t>>1][t&1][r4*4+1] += v.y;
      acc[t>>1][t&1][r4*4+2] += v.z;
      acc[t>>1][t&1][r4*4+3] += v.w;
    }
  }
}
// 8 waves -> 2 half-sums scattered as row*64+col into zone0 (red+8192) and
// zone1 (red+12288). All epilogues read two float4s and add (conflict-free).
__device__ __forceinline__ void reduce8(f32x16 acc[2][2], float* red, int lane, int wid) {
  if (wid >= 4) acc_wr(red + (size_t)(wid - 4) * 4096, lane, acc);
  __syncthreads();
  if (wid < 4) acc_add(red + (size_t)wid * 4096, lane, acc);
  if (wid == 2 || wid == 3) acc_wr(red + (size_t)wid * 4096, lane, acc);
  __syncthreads();
  if (wid < 2) {
    acc_add(red + (size_t)(wid + 2) * 4096, lane, acc);
    float* zone = red + 8192 + (size_t)wid * 4096;   // overwrites bufs 2,3 (safe: in-wave RAW order)
    #pragma unroll
    for (int ms = 0; ms < 2; ms++)
      #pragma unroll
      for (int ns = 0; ns < 2; ns++)
        #pragma unroll
        for (int rr = 0; rr < 16; rr++) {
          int row = ms * 32 + (rr & 3) + ((rr >> 2) << 3) + ((lane >> 5) << 2);
          zone[row * 64 + ns * 32 + (lane & 31)] = acc[ms][ns][rr];
        }
  }
  __syncthreads();
}
__device__ __forceinline__ float4 rsum4(const float* red, int row, int col) {
  float4 a = *(const float4*)&red[8192 + row * 64 + col];
  float4 b = *(const float4*)&red[12288 + row * 64 + col];
  return make_float4(a.x + b.x, a.y + b.y, a.z + b.z, a.w + b.w);
}

// ---------------- main persistent kernel (4 independent groups) ----------------
__global__ void __launch_bounds__(512, 2) kmain(const float* __restrict__ attn_v,
                                                const float* __restrict__ out_b,
                                                float* __restrict__ out) {
  __shared__ __align__(16) char asg[65536];  // ring-4: 4 chunk-slots x 8 waves x 2KB
  __shared__ float red[16384];               // 4 partial bufs / 2 result zones

  const half_t* x16 = WSCH(O_X16);
  const half_t* wL0 = WSCH(O_WL0);
  const half_t* wL1 = WSCH(O_WL1);
  const half_t* wP1 = WSCH(O_WP1);
  const half_t* wD0 = WSCH(O_WD0);
  const half_t* wD1 = WSCH(O_WD1);
  half_t* h0bB = WSH(O_H0B);
  half_t* h1bB = WSH(O_H1B);
  half_t* hd1  = WSH(O_HD1);
  half_t* h0d  = WSH(O_H0D);
  half_t* ctx  = WSH(O_CTX);
  half_t* eo   = WSH(O_EO);
  half_t* ep   = WSH(O_EP);
  float* c1 = WSF(O_C1);
  float* inp = WSF(O_INP);
  float* gates = WSF(O_GAT);

  const int tid = threadIdx.x;
  const int wid = tid >> 6;
  const int lane = tid & 63;
  const int g = blockIdx.x & 3;        // batch-slice group
  const int r = blockIdx.x >> 2;       // rank within group, 0..63
  const int sub = r & 1;
  const int m0 = g << 6;               // group's batch-row base
  const f32x16 zv = {0,0,0,0,0,0,0,0,0,0,0,0,0,0,0,0};
  int bstep = 0;

  // ================= encoder: 513 wavefront-pipelined steps =================
  {
    const bool isL1 = r >= 32;
    const int n0 = (r & 31) << 6;

    const half_t* wbase = isL1 ? (wL1 + (size_t)(n0 >> 6) * (8 * 8192))
                               : (wL0 + (size_t)(n0 >> 6) * (5 * 8192));
    const half_t* wb = wbase + (wid << 1) * 512 + lane * 8;
    const int ncB = isL1 ? 8 : 5;
    f16x8 B0[8], B1[8];
    #pragma unroll
    for (int c = 0; c < 8; c++) {
      if (c < ncB) {
        B0[c] = *(const f16x8*)(wb + (size_t)c * 8192);
        B1[c] = *(const f16x8*)(wb + (size_t)c * 8192 + 512);
      }
    }
    const int eu = tid & 15;
    const int ebl = tid >> 4;
    const float* bias = isL1 ? WSCF(O_BL1) : WSCF(O_BL0);
    float4 breg = *(const float4*)&bias[n0 + eu * 4];
    float creg0 = 0.f, creg1 = 0.f;

    for (int s = 0; s <= 512; s++) {
      const bool active = isL1 ? (s > 0) : (s < 512);
      if (active) {
        const half_t* h0r = h0bB + (size_t)((s + 1) & 1) * (256 * 512);
        f32x16 acc[2][2] = {{zv, zv}, {zv, zv}};
        int t;
        if (!isL1) {
          t = s;
          gemm_regB<5, 1, 0, AUXC>(Seg{x16, 128, t * 256 + m0}, Seg{h0r, 512, m0},
                                   B0, B1, lane, wid, asg, acc);
        } else {
          t = s - 1;
          const half_t* h1r = h1bB + (size_t)(s & 1) * (256 * 512);
          gemm_regB<8, 4, AUXC, AUXC>(Seg{h0r, 512, m0}, Seg{h1r, 512, m0},
                                      B0, B1, lane, wid, asg, acc);
        }
        reduce8(acc, red, lane, wid);
        half_t* hb = isL1 ? (h1bB + (size_t)((s - 1) & 1) * (256 * 512))
                          : (h0bB + (size_t)(s & 1) * (256 * 512));
        #pragma unroll
        for (int it = 0; it < 2; it++) {
          int bl = ebl + it * 32;
          float4 g4 = rsum4(red, bl, eu * 4);
          float gi = g4.x + breg.x, gf = g4.y + breg.y;
          float gz = g4.z + breg.z, go = g4.w + breg.w;
          float cold = it ? creg1 : creg0;
          float cn = fsig(gf) * cold + fsig(gi) * ftanh(gz);
          float hn = fsig(go) * ftanh(cn);
          if (it) creg1 = cn; else creg0 = cn;
          int bg = m0 + bl, ug = (n0 >> 2) + eu;
          stha(&hb[bg * 512 + ug], hn);                       // coherent publish
          if (isL1) eo[((size_t)bg * 512 + t) * 512 + ug] = (half_t)hn;  // plain
        }
      }
      gbarf(g, r, ++bstep);
    }

    if (isL1) {   // flush c-state (plain; covered by heavy barrier below)
      int ug = (n0 >> 2) + eu;
      c1[(m0 + ebl) * 512 + ug] = creg0;
      c1[(m0 + ebl + 32) * 512 + ug] = creg1;
    }
  }
  gbar_acq(g, sub);   // phase edge: flush eo + c1, invalidate stale L2

  // ====== enc_proj = enc_out @ attn_W^T (f16), group-local rows ======
  for (int j = 0; j < 64; j++) {
    const int jj = r * 64 + j;
    const int ml = jj >> 3;
    const int nt = jj & 7;
    const int row0 = (g << 15) + ml * 64;
    f32x16 acc[2][2] = {{zv, zv}, {zv, zv}};
    gemm_ks<4, 0, 0>(Seg{eo, 512, row0}, Seg{eo, 512, row0}, 4,
                     wP1 + (size_t)nt * (4 * 8192), lane, wid, asg, acc);
    reduce8(acc, red, lane, wid);
    {
      int row = tid >> 3, col = (tid & 7) * 8;
      float4 a0 = rsum4(red, row, col);
      float4 a1 = rsum4(red, row, col + 4);
      f16x8 h8;
      h8[0] = (half_t)a0.x; h8[1] = (half_t)a0.y; h8[2] = (half_t)a0.z; h8[3] = (half_t)a0.w;
      h8[4] = (half_t)a1.x; h8[5] = (half_t)a1.y; h8[6] = (half_t)a1.z; h8[7] = (half_t)a1.w;
      *(f16x8*)&ep[(size_t)(row0 + row) * 512 + nt * 64 + col] = h8;  // plain
    }
    __syncthreads();
  }
  gbar_acq(g, sub);   // phase edge: flush ep

  // ================= decoder: 30 steps (d=30 = final output-only pass) ======
  for (int d = 0; d <= 30; d++) {
    // ---- P1: h1 @ [attn_W | dWhh0 | dWhh1 | out_W]  (73 n-tiles / group) ----
    const half_t* hs = (d == 0) ? (h1bB + 256 * 512) : hd1;
    for (int jj = r; jj < 73; jj += 64) {
      const int n0p = jj * 64;
      f32x16 acc[2][2] = {{zv, zv}, {zv, zv}};
      gemm_ks<4, AUXC, AUXC>(Seg{hs, 512, m0}, Seg{hs, 512, m0}, 4,
                             wP1 + (size_t)jj * (4 * 8192), lane, wid, asg, acc);
      reduce8(acc, red, lane, wid);
      if (n0p < 4608) {
        #pragma unroll
        for (int it = 0; it < 2; it++) {
          int q = it * 512 + tid;
          int row = q >> 4, col = (q & 15) * 4;
          float4 v4 = rsum4(red, row, col);
          float* dst = &gates[(size_t)(m0 + row) * 4672 + n0p + col];
          st64(dst, v4.x, v4.y);
          st64(dst + 2, v4.z, v4.w);
        }
      } else if (d > 0) {
        if (tid < 64) {
          int bg = m0 + tid;
          float v0 = red[8192 + tid * 64 + 0] + red[12288 + tid * 64 + 0] + out_b[0];
          float v1 = red[8192 + tid * 64 + 1] + red[12288 + tid * 64 + 1] + out_b[1];
          float v2 = red[8192 + tid * 64 + 2] + red[12288 + tid * 64 + 2] + out_b[2];
          out[(size_t)bg * 90 + (d - 1) * 3 + 0] = v0;
          out[(size_t)bg * 90 + (d - 1) * 3 + 1] = v1;
          out[(size_t)bg * 90 + (d - 1) * 3 + 2] = v2;
          stfa(&inp[bg], v1);
        }
      }
      __syncthreads();
    }
    gbarf(g, r, ++bstep);
    if (d == 30) break;

    // ---- P2: attention for batch row b = m0 + r ----
    {
      const int b = m0 + r;
      float* dpb = red;          // 512
      float* vb  = red + 512;    // 512
      float* eb  = red + 1024;   // 512
      float* ab2 = red + 2048;   // 512
      float* sc  = red + 2560;   // 16
      float* pm  = red + 4096;   // 8x512 ctx partials
      dpb[tid] = ldfa(&gates[(size_t)b * 4672 + tid]);
      vb[tid]  = attn_v[tid];
      __syncthreads();
      // hoist tt-invariant LDS reads into registers (were 16-way conflicted)
      float va[8], da[8];
      {
        float4 t0 = *(const float4*)&vb[lane * 8];
        float4 t1 = *(const float4*)&vb[lane * 8 + 4];
        float4 t2 = *(const float4*)&dpb[lane * 8];
        float4 t3 = *(const float4*)&dpb[lane * 8 + 4];
        va[0]=t0.x; va[1]=t0.y; va[2]=t0.z; va[3]=t0.w;
        va[4]=t1.x; va[5]=t1.y; va[6]=t1.z; va[7]=t1.w;
        da[0]=t2.x; da[1]=t2.y; da[2]=t2.z; da[3]=t2.w;
        da[4]=t3.x; da[5]=t3.y; da[6]=t3.z; da[7]=t3.w;
      }
      const half_t* eprow = ep + ((size_t)b << 18) + (size_t)(wid * 64) * 512 + lane * 8;
      for (int tt = 0; tt < 64; tt++) {
        f16x8 e8 = *(const f16x8*)(eprow + (size_t)tt * 512);
        float sum = 0.f;
        #pragma unroll
        for (int jq = 0; jq < 8; jq++)
          sum += va[jq] * ftanh((float)e8[jq] + da[jq]);
        #pragma unroll
        for (int off = 32; off > 0; off >>= 1) sum += __shfl_down(sum, off, 64);
        if (lane == 0) eb[wid * 64 + tt] = sum;
      }
      __syncthreads();
      float e0 = eb[tid];
      float mx = e0;
      #pragma unroll
      for (int off = 32; off > 0; off >>= 1) mx = fmaxf(mx, __shfl_xor(mx, off, 64));
      if (lane == 0) sc[wid] = mx;
      __syncthreads();
      mx = sc[0];
      #pragma unroll
      for (int q = 1; q < 8; q++) mx = fmaxf(mx, sc[q]);
      float x0 = __expf(e0 - mx);
      float ssum = x0;
      #pragma unroll
      for (int off = 32; off > 0; off >>= 1) ssum += __shfl_xor(ssum, off, 64);
      __syncthreads();
      if (lane == 0) sc[8 + wid] = ssum;
      __syncthreads();
      float tot = sc[8];
      #pragma unroll
      for (int q = 1; q < 8; q++) tot += sc[8 + q];
      float inv = 1.f / tot;
      ab2[tid] = x0 * inv;
      __syncthreads();
      float pacc[8] = {0,0,0,0,0,0,0,0};
      const half_t* eow = eo + ((size_t)b << 18) + (size_t)(wid * 64) * 512 + lane * 8;
      for (int tt = 0; tt < 64; tt++) {
        f16x8 h8 = *(const f16x8*)(eow + (size_t)tt * 512);
        float at = ab2[wid * 64 + tt];
        #pragma unroll
        for (int jq = 0; jq < 8; jq++) pacc[jq] += at * (float)h8[jq];
      }
      #pragma unroll
      for (int jq = 0; jq < 8; jq++) pm[wid * 512 + lane * 8 + jq] = pacc[jq];
      __syncthreads();
      float sctx = 0.f;
      #pragma unroll
      for (int w = 0; w < 8; w++) sctx += pm[w * 512 + tid];
      stha(&ctx[(b << 9) + tid], sctx);                          // coherent
    }
    gbarf(g, r, ++bstep);

    // ---- P3: gates0 = ctx @ dWih0[:,1:] + inp*w0col + partial + bias -> h0d ----
    if (r < 32) {
      const int n0 = r << 6;
      f32x16 acc[2][2] = {{zv, zv}, {zv, zv}};
      gemm_ks<4, AUXC, AUXC>(Seg{ctx, 512, m0}, Seg{ctx, 512, m0}, 4,
                             wD0 + (size_t)(n0 >> 6) * (4 * 8192), lane, wid, asg, acc);
      reduce8(acc, red, lane, wid);
      const float* bD0 = WSCF(O_BD0);
      const float* w0c = WSCF(O_W0C);
      #pragma unroll
      for (int it = 0; it < 2; it++) {
        int q = it * 512 + tid;
        int u = q & 15, bl = q >> 4;
        int bg = m0 + bl, ug = (n0 >> 2) + u, nl = n0 + u * 4;
        float4 g4 = rsum4(red, bl, u * 4);
        float p0, p1, p2, p3;
        ld64(&gates[(size_t)bg * 4672 + 512 + nl], p0, p1);
        ld64(&gates[(size_t)bg * 4672 + 512 + nl + 2], p2, p3);
        float4 b4 = *(const float4*)&bD0[nl];
        float4 w4 = *(const float4*)&w0c[nl];
        float iv = ldfa(&inp[bg]);
        float gi = g4.x + p0 + b4.x + iv * w4.x;
        float gf = g4.y + p1 + b4.y + iv * w4.y;
        float gz = g4.z + p2 + b4.z + iv * w4.z;
        float go = g4.w + p3 + b4.w + iv * w4.w;
        float cold = c1[bg * 512 + ug];
        float cn = fsig(gf) * cold + fsig(gi) * ftanh(gz);
        stha(&h0d[bg * 512 + ug], fsig(go) * ftanh(cn));        // coherent
      }
    }
    gbarf(g, r, ++bstep);

    // ---- P4: gates1 = h0d @ dWih1 + partial + bias -> c1, hd1 ----
    if (r < 32) {
      const int n0 = r << 6;
      f32x16 acc[2][2] = {{zv, zv}, {zv, zv}};
      gemm_ks<4, AUXC, AUXC>(Seg{h0d, 512, m0}, Seg{h0d, 512, m0}, 4,
                             wD1 + (size_t)(n0 >> 6) * (4 * 8192), lane, wid, asg, acc);
      reduce8(acc, red, lane, wid);
      const float* bD1 = WSCF(O_BD1);
      #pragma unroll
      for (int it = 0; it < 2; it++) {
        int q = it * 512 + tid;
        int u = q & 15, bl = q >> 4;
        int bg = m0 + bl, ug = (n0 >> 2) + u, nl = n0 + u * 4;
        float4 g4 = rsum4(red, bl, u * 4);
        float p0, p1, p2, p3;
        ld64(&gates[(size_t)bg * 4672 + 2560 + nl], p0, p1);
        ld64(&gates[(size_t)bg * 4672 + 2560 + nl + 2], p2, p3);
        float4 b4 = *(const float4*)&bD1[nl];
        float gi = g4.x + p0 + b4.x;
        float gf = g4.y + p1 + b4.y;
        float gz = g4.z + p2 + b4.z;
        float go = g4.w + p3 + b4.w;
        float cold = c1[bg * 512 + ug];
        float cn = fsig(gf) * cold + fsig(gi) * ftanh(gz);
        float hn = fsig(go) * ftanh(cn);
        c1[bg * 512 + ug] = cn;                                  // self-read only
        stha(&hd1[bg * 512 + ug], hn);                           // coherent
      }
    }
    gbarf(g, r, ++bstep);
  }
}

// ---------------- prep kernels ----------------
__global__ void kpackB(size_t dstOff, int id, int Ntiles, int NC,
                       const float* s0, const float* s1,
                       const float* s2, const float* s3) {
  half_t* dst = (half_t*)(g_ws + dstOff);
  size_t total = (size_t)Ntiles * NC * 8192;
  size_t i = (size_t)blockIdx.x * 256 + threadIdx.x;
  size_t stride = (size_t)gridDim.x * 256;
  for (size_t e = i; e < total; e += stride) {
    int j = e & 7;
    int l = (e >> 3) & 63;
    int bh = (e >> 9) & 1;
    int w = (e >> 10) & 7;
    int tc = (int)(e >> 13);
    int c = tc % NC;
    int tile = tc / NC;
    int n = tile * 64 + bh * 32 + (l & 31);
    int k = c * 128 + w * 16 + ((l >> 5) << 3) + j;
    float v = 0.f;
    if (id == 0) {          // wL0: [Wih0(64) | pad(64) | Whh0(512)]
      int pn = gperm(n);
      if (k < 64) v = s0[(size_t)pn * 64 + k];
      else if (k >= 128) v = s1[(size_t)pn * 512 + (k - 128)];
    } else if (id == 1) {   // wL1: [Wih1(512) | Whh1(512)]
      int pn = gperm(n);
      v = (k < 512) ? s0[(size_t)pn * 512 + k] : s1[(size_t)pn * 512 + (k - 512)];
    } else if (id == 2) {   // wP1: [attnW | dWhh0 | dWhh1 | outW | pad]
      if (n < 512) v = s0[((size_t)n << 9) + k];
      else if (n < 2560) v = s1[((size_t)gperm(n - 512) << 9) + k];
      else if (n < 4608) v = s2[((size_t)gperm(n - 2560) << 9) + k];
      else if (n < 4611) v = s3[((size_t)(n - 4608) << 9) + k];
    } else if (id == 3) {   // wD0: dec_Wih0[:,1:]
      v = s0[(size_t)gperm(n) * 513 + 1 + k];
    } else {                // wD1
      v = s0[((size_t)gperm(n) << 9) + k];
    }
    dst[e] = (half_t)v;
  }
}

__global__ void kmisc(const float* ebih0, const float* ebhh0, const float* ebih1, const float* ebhh1,
                      const float* dbih0, const float* dbhh0, const float* dbih1, const float* dbhh1,
                      const float* dWih0, const float* x) {
  float* bL0 = WSF(O_BL0);
  float* bL1 = WSF(O_BL1);
  float* bD0 = WSF(O_BD0);
  float* bD1 = WSF(O_BD1);
  float* w0c = WSF(O_W0C);
  half_t* h0b = WSH(O_H0B);
  half_t* h1b = WSH(O_H1B);
  float* c1 = WSF(O_C1);
  float* inp = WSF(O_INP);
  int i = blockIdx.x * 256 + threadIdx.x, stride = gridDim.x * 256;
  for (int idx = i; idx < 262144; idx += stride) {
    if (idx < 2048) {
      int pn = gperm(idx);
      bL0[idx] = ebih0[pn] + ebhh0[pn];
      bL1[idx] = ebih1[pn] + ebhh1[pn];
      bD0[idx] = dbih0[pn] + dbhh0[pn];
      bD1[idx] = dbih1[pn] + dbhh1[pn];
      w0c[idx] = dWih0[(size_t)pn * 513];
      g_bar[idx] = 0;
    }
    if (idx < 1024) g_flags[idx] = 0;
    if (idx < 256) inp[idx] = x[((size_t)idx * 512 + 511) * 64];
    h0b[idx] = (half_t)0.f;
    h1b[idx] = (half_t)0.f;
    if (idx < 131072) c1[idx] = 0.f;
  }
}

__global__ void kx16(const float* x) {
  half_t* dst = WSH(O_X16);   // (t, b, 128) zero-padded cols 64..127
  size_t i = (size_t)blockIdx.x * 256 + threadIdx.x;
  size_t stride = (size_t)gridDim.x * 256;
  for (size_t e = i; e < (size_t)512 * 256 * 128; e += stride) {
    int t = (int)(e >> 15);
    int b = (int)((e >> 7) & 255);
    int ii = (int)(e & 127);
    dst[e] = (ii < 64) ? (half_t)x[((size_t)b * 512 + t) * 64 + ii] : (half_t)0.f;
  }
}

// ---------------- launch ----------------
extern "C" void kernel_launch(void* const* d_in, const int* in_sizes, int n_in,
                              void* d_out, int out_size, void* d_ws, size_t ws_size,
                              hipStream_t stream) {
  const float* x     = (const float*)d_in[0];
  const float* eWih0 = (const float*)d_in[1];
  const float* eWhh0 = (const float*)d_in[2];
  const float* ebih0 = (const float*)d_in[3];
  const float* ebhh0 = (const float*)d_in[4];
  const float* eWih1 = (const float*)d_in[5];
  const float* eWhh1 = (const float*)d_in[6];
  const float* ebih1 = (const float*)d_in[7];
  const float* ebhh1 = (const float*)d_in[8];
  const float* dWih0 = (const float*)d_in[9];
  const float* dWhh0 = (const float*)d_in[10];
  const float* dbih0 = (const float*)d_in[11];
  const float* dbhh0 = (const float*)d_in[12];
  const float* dWih1 = (const float*)d_in[13];
  const float* dWhh1 = (const float*)d_in[14];
  const float* dbih1 = (const float*)d_in[15];
  const float* dbhh1 = (const float*)d_in[16];
  const float* attnW = (const float*)d_in[17];
  const float* attnv = (const float*)d_in[18];
  const float* outW  = (const float*)d_in[19];
  const float* outb  = (const float*)d_in[20];
  (void)in_sizes; (void)n_in; (void)out_size; (void)d_ws; (void)ws_size;

  kpackB<<<1024, 256, 0, stream>>>(O_WL0, 0, 32, 5, eWih0, eWhh0, nullptr, nullptr);
  kpackB<<<1024, 256, 0, stream>>>(O_WL1, 1, 32, 8, eWih1, eWhh1, nullptr, nullptr);
  kpackB<<<1024, 256, 0, stream>>>(O_WP1, 2, 73, 4, attnW, dWhh0, dWhh1, outW);
  kpackB<<<1024, 256, 0, stream>>>(O_WD0, 3, 32, 4, dWih0, nullptr, nullptr, nullptr);
  kpackB<<<1024, 256, 0, stream>>>(O_WD1, 4, 32, 4, dWih1, nullptr, nullptr, nullptr);
  kmisc<<<1024, 256, 0, stream>>>(ebih0, ebhh0, ebih1, ebhh1,
                                  dbih0, dbhh0, dbih1, dbhh1, dWih0, x);
  kx16<<<2048, 256, 0, stream>>>(x);

  float* outp = (float*)d_out;
  void* args[] = {(void*)&attnv, (void*)&outb, (void*)&outp};
  hipError_t e = hipLaunchCooperativeKernel((void*)kmain, dim3(256), dim3(512),
                                            args, 0, stream);
  if (e != hipSuccess) {
    kmain<<<dim3(256), dim3(512), 0, stream>>>(attnv, outb, outp);
  }
}